// Round 20
// baseline (147.014 us; speedup 1.0000x reference)
//
#include <hip/hip_runtime.h>

// HolographicBlock: B=2, S=2048, D=1024, R=64, H=8, HD=128
// Pre-swizzled weight images + global_load_lds everywhere; bf16 t-partials.
// Attention = R19 with K-only LDS staging (48KB -> 3 blocks/CU); V fragments
// read directly from the swizzled Vimg (byte-identical offsets, L2-resident).

#define Bn 2
#define Sn 2048
#define Dn 1024
#define Rn 64
#define Hn 8
#define HDn 128
#define Mn (Bn*Sn)   // 4096 rows
#define TSTRIDE ((size_t)Mn * Rn)

typedef __bf16 bf16x8 __attribute__((ext_vector_type(8)));
typedef float f32x4 __attribute__((ext_vector_type(4)));
typedef __attribute__((address_space(1))) const unsigned int g_u32;
typedef __attribute__((address_space(3))) unsigned int l_u32;

__device__ __forceinline__ float bf2f(unsigned short u){
    union { unsigned int i; float f; } x; x.i = ((unsigned int)u) << 16; return x.f;
}
__device__ __forceinline__ unsigned short f2bf(float f){
    union { float f; unsigned int i; } x; x.f = f;
    unsigned int r = x.i + 0x7fffu + ((x.i >> 16) & 1u);
    return (unsigned short)(r >> 16);
}
__device__ __forceinline__ unsigned int pk2(float a, float b){
    unsigned int r;
    asm("v_cvt_pk_bf16_f32 %0, %1, %2" : "=v"(r) : "v"(a), "v"(b));
    return r;
}
__device__ __forceinline__ float vexp2(float x){
    float r;
    asm("v_exp_f32 %0, %1" : "=v"(r) : "v"(x));
    return r;
}
__device__ __forceinline__ void gld16(const void* g, void* l){
    __builtin_amdgcn_global_load_lds((g_u32*)g, (l_u32*)l, 16, 0, 0);
}
__device__ __forceinline__ void dma32k(const char* src, char* dst, int tid){
    #pragma unroll
    for (int p = 0; p < 8; ++p)
        gld16(src + p * 4096 + tid * 16, dst + p * 4096 + tid * 16);
}
__device__ __forceinline__ float bflo(unsigned int u){
    union { unsigned int i; float f; } x; x.i = u << 16; return x.f;
}
__device__ __forceinline__ float bfhi(unsigned int u){
    union { unsigned int i; float f; } x; x.i = u & 0xffff0000u; return x.f;
}
__device__ __forceinline__ uint4 comb8(uint4 A, uint4 C, float Wc){
    uint4 r;
    unsigned int* a = (unsigned int*)&A;
    unsigned int* c = (unsigned int*)&C;
    unsigned int* o = (unsigned int*)&r;
    #pragma unroll
    for (int e = 0; e < 4; ++e){
        float lo = (bflo(a[e]) + bflo(c[e])) * Wc;
        float hi = (bfhi(a[e]) + bfhi(c[e])) * Wc;
        o[e] = pk2(lo, hi);
    }
    return r;
}

// ---------------- prep: PRE-SWIZZLED weight images + rope table
__global__ __launch_bounds__(256) void prep_g(const float* __restrict__ A,
                                              const float* __restrict__ Bsrc,
                                              const float* __restrict__ Cq, const float* __restrict__ Ck,
                                              const float* __restrict__ Cv, const float* __restrict__ Co,
                                              const float* __restrict__ Cfc, const float* __restrict__ Cpr,
                                              const float* __restrict__ s1, const float* __restrict__ s2,
                                              char* __restrict__ AtI1c, char* __restrict__ AtI0c,
                                              char* __restrict__ AtI2u, char* __restrict__ AtI0u,
                                              char* __restrict__ BIq, char* __restrict__ BIk,
                                              char* __restrict__ BIv, char* __restrict__ BIo,
                                              char* __restrict__ BIfc, char* __restrict__ BIpr,
                                              float2* __restrict__ rt){
    int idx = blockIdx.x * 256 + threadIdx.x;
    if (idx < 4 * 65536){
        int v = idx >> 16, e = idx & 65535;
        int r = e & 63, d = e >> 6;
        float sc = (v == 0) ? s1[d] : (v == 2) ? s2[d] : 1.f;
        unsigned short val = f2bf(A[d * 64 + r] * sc);
        if (v < 2){
            int us = (d >> 6) * 4096 + r * 64 + (((((d >> 3) & 7) << 4) ^ ((r & 7) << 4)) >> 1) + (d & 7);
            ((unsigned short*)(v == 0 ? AtI1c : AtI0c))[us] = val;
        } else {
            int us = (d >> 8) * 16384 + r * 256 + (((((d >> 3) & 31) << 4) ^ ((r & 7) << 4)) >> 1) + (d & 7);
            ((unsigned short*)(v == 2 ? AtI2u : AtI0u))[us] = val;
        }
    } else if (idx < 10 * 65536){
        int v = (idx >> 16) - 4, e = idx & 65535;
        int d = e & 1023, r = e >> 10;
        const float* C = v==0?Cq : v==1?Ck : v==2?Cv : v==3?Co : v==4?Cfc : Cpr;
        float extra = (v == 0) ? (0.08838834764831845f * 1.4426950408889634f) : 1.f;
        unsigned short val = f2bf(Bsrc[r * 1024 + d] * C[r] * extra);
        int us = (d >> 8) * 16384 + (d & 255) * 64 + ((((r >> 3) << 4) ^ ((d & 7) << 4)) >> 1) + (r & 7);
        ((unsigned short*)(v==0?BIq : v==1?BIk : v==2?BIv : v==3?BIo : v==4?BIfc : BIpr))[us] = val;
    } else if (idx < 10 * 65536 + Sn * 64){
        int e = idx - 10 * 65536;
        int s = e >> 6, f = e & 63;
        float inv = exp2f(-(float)f * (13.287712379549449f / 64.0f));
        float fr = (float)s * inv;
        float sn, cs; sincosf(fr, &sn, &cs);
        rt[e] = make_float2(cs, sn);
    }
}

// ---------------- down GEMM (f32 input + sumsq): DMA At image, bf16 t-partials out
__global__ __launch_bounds__(256) void down_g(const float* __restrict__ inp,
                                              const char* __restrict__ AtImg,
                                              unsigned short* __restrict__ tpart,
                                              float* __restrict__ sspart){
    __shared__ char xt[32768];
    __shared__ char at[32768];
    int tid = threadIdx.x;
    int m0 = blockIdx.x * 64, sp = blockIdx.y;
    int row = tid >> 2, q4 = tid & 3;
    int w = tid >> 6, lane = tid & 63, l4 = lane >> 4, lm = lane & 15;
    int swz = (row & 7) << 4;
    dma32k(AtImg + (size_t)sp * 32768, at, tid);
    float ss = 0.f;
    f32x4 acc[4];
    #pragma unroll
    for (int nt = 0; nt < 4; ++nt) acc[nt] = (f32x4){0.f,0.f,0.f,0.f};

    float4 xr[4];
    #define LOADX(c) { int k0 = sp * 256 + (c) * 64; \
        const float4* s = (const float4*)(inp + (size_t)(m0+row)*1024 + k0 + q4*16); \
        xr[0]=s[0]; xr[1]=s[1]; xr[2]=s[2]; xr[3]=s[3]; }

    LOADX(0);
    for (int c = 0; c < 4; ++c){
        char* xc = xt + c * 8192;
        #pragma unroll
        for (int i = 0; i < 4; ++i)
            ss += xr[i].x*xr[i].x + xr[i].y*xr[i].y + xr[i].z*xr[i].z + xr[i].w*xr[i].w;
        uint4 p0 = {pk2(xr[0].x,xr[0].y), pk2(xr[0].z,xr[0].w), pk2(xr[1].x,xr[1].y), pk2(xr[1].z,xr[1].w)};
        uint4 p1 = {pk2(xr[2].x,xr[2].y), pk2(xr[2].z,xr[2].w), pk2(xr[3].x,xr[3].y), pk2(xr[3].z,xr[3].w)};
        *(uint4*)(xc + row * 128 + ((q4 * 32) ^ swz)) = p0;
        *(uint4*)(xc + row * 128 + ((q4 * 32 + 16) ^ swz)) = p1;
        __syncthreads();            // c==0 also drains the At DMA
        if (c < 3) LOADX(c + 1);
        #pragma unroll
        for (int ks = 0; ks < 2; ++ks){
            int arow = 16 * w + lm;
            bf16x8 af = *(const bf16x8*)(xc + arow * 128 + ((ks*64 + l4*16) ^ ((arow & 7) << 4)));
            #pragma unroll
            for (int nt = 0; nt < 4; ++nt){
                int brow = nt * 16 + lm;
                bf16x8 bf = *(const bf16x8*)(at + c * 8192 + brow * 128 + ((ks*64 + l4*16) ^ ((brow & 7) << 4)));
                acc[nt] = __builtin_amdgcn_mfma_f32_16x16x32_bf16(af, bf, acc[nt], 0, 0, 0);
            }
        }
    }
    #undef LOADX
    ss += __shfl_xor(ss, 1); ss += __shfl_xor(ss, 2);
    if (q4 == 0) sspart[sp * Mn + m0 + row] = ss;
    #pragma unroll
    for (int nt = 0; nt < 4; ++nt)
        #pragma unroll
        for (int r = 0; r < 4; ++r){
            int ml = 16 * w + 4 * l4 + r;
            tpart[(size_t)sp * TSTRIDE + (size_t)(m0 + ml) * 64 + nt * 16 + lm] = f2bf(acc[nt][r]);
        }
}

// ---------------- down GEMM for y (fused slice-combine), bf16 t-partials out
__global__ __launch_bounds__(256) void downy_g(const unsigned short* __restrict__ ybf,
                                               const unsigned short* __restrict__ pab,
                                               const float* __restrict__ pl,
                                               const char* __restrict__ AtImg,
                                               unsigned short* __restrict__ tpart){
    __shared__ char xt[32768];
    __shared__ char at[32768];
    int tid = threadIdx.x;
    int m0 = blockIdx.x * 64, sp = blockIdx.y;
    int row = tid >> 2, q4 = tid & 3;
    int w = tid >> 6, lane = tid & 63, l4 = lane >> 4, lm = lane & 15;
    int swz = (row & 7) << 4;
    int jq = (m0 & (Sn - 1)) >> 7;
    int bpos = m0 >> 11;
    int srow = (m0 & 127) + row;
    dma32k(AtImg + (size_t)sp * 32768, at, tid);
    f32x4 acc[4];
    #pragma unroll
    for (int nt = 0; nt < 4; ++nt) acc[nt] = (f32x4){0.f,0.f,0.f,0.f};

    #define MFMAC(c) { \
        _Pragma("unroll") \
        for (int ks = 0; ks < 2; ++ks){ \
            int arow = 16 * w + lm; \
            bf16x8 af = *(const bf16x8*)(xt + (c) * 8192 + arow * 128 + ((ks*64 + l4*16) ^ ((arow & 7) << 4))); \
            _Pragma("unroll") \
            for (int nt = 0; nt < 4; ++nt){ \
                int brow = nt * 16 + lm; \
                bf16x8 bf = *(const bf16x8*)(at + (c) * 8192 + brow * 128 + ((ks*64 + l4*16) ^ ((brow & 7) << 4))); \
                acc[nt] = __builtin_amdgcn_mfma_f32_16x16x32_bf16(af, bf, acc[nt], 0, 0, 0); \
            } \
        } }

    if (jq < 8){
        const char* yb = (const char*)ybf;
        #pragma unroll
        for (int p = 0; p < 8; ++p){
            int c = p >> 1;
            int rw = (p & 1) * 32 + (tid >> 3);
            int gp = (tid & 7) ^ (rw & 7);
            gld16(yb + (size_t)(m0 + rw) * 2048 + sp * 512 + c * 128 + gp * 16,
                  xt + p * 4096 + tid * 16);
        }
        __syncthreads();
        for (int c = 0; c < 4; ++c) MFMAC(c);
    } else {
        uint4 xrb[2];
        #define LOADCMB(c) { int k0 = sp * 256 + (c) * 64; \
            int h = k0 >> 7; int d0 = k0 & 127; \
            int s0sl = (((bpos * 8 + h) * 8) + (jq - 8)) * 2; \
            const unsigned short* p0 = pab + (size_t)s0sl * 16384 + srow * 128 + d0 + q4 * 16; \
            const unsigned short* p1 = p0 + 16384; \
            float Wc = 1.f / (pl[s0sl * 128 + srow] + pl[(s0sl + 1) * 128 + srow]); \
            uint4 A0 = ((const uint4*)p0)[0], A1 = ((const uint4*)p0)[1]; \
            uint4 C0 = ((const uint4*)p1)[0], C1 = ((const uint4*)p1)[1]; \
            xrb[0] = comb8(A0, C0, Wc); xrb[1] = comb8(A1, C1, Wc); }
        LOADCMB(0);
        for (int c = 0; c < 4; ++c){
            char* xc = xt + c * 8192;
            *(uint4*)(xc + row * 128 + ((q4 * 32) ^ swz)) = xrb[0];
            *(uint4*)(xc + row * 128 + ((q4 * 32 + 16) ^ swz)) = xrb[1];
            __syncthreads();
            if (c < 3) LOADCMB(c + 1);
            MFMAC(c);
        }
        #undef LOADCMB
    }
    #undef MFMAC
    #pragma unroll
    for (int nt = 0; nt < 4; ++nt)
        #pragma unroll
        for (int r = 0; r < 4; ++r){
            int ml = 16 * w + 4 * l4 + r;
            tpart[(size_t)sp * TSTRIDE + (size_t)(m0 + ml) * 64 + nt * 16 + lm] = f2bf(acc[nt][r]);
        }
}

// ---------------- stage t tile (sum 4 bf16 K-split partials, optional rms) into swizzled LDS
template<int DORMS>
__device__ __forceinline__ void stage_t(char* tt, const unsigned short* __restrict__ tpart,
                                        const float* __restrict__ sspart, int m0, int tid){
    int row = tid >> 2, q4 = tid & 3;
    const unsigned short* bp = tpart + (size_t)(m0 + row) * 64 + q4 * 16;
    float s[16];
    #pragma unroll
    for (int half = 0; half < 2; ++half){
        uint4 u0 = ((const uint4*)(bp + 0 * TSTRIDE))[half];
        uint4 u1 = ((const uint4*)(bp + 1 * TSTRIDE))[half];
        uint4 u2 = ((const uint4*)(bp + 2 * TSTRIDE))[half];
        uint4 u3 = ((const uint4*)(bp + 3 * TSTRIDE))[half];
        const unsigned int* a0 = (const unsigned int*)&u0;
        const unsigned int* a1 = (const unsigned int*)&u1;
        const unsigned int* a2 = (const unsigned int*)&u2;
        const unsigned int* a3 = (const unsigned int*)&u3;
        #pragma unroll
        for (int e = 0; e < 4; ++e){
            s[half*8 + 2*e]     = bflo(a0[e]) + bflo(a1[e]) + bflo(a2[e]) + bflo(a3[e]);
            s[half*8 + 2*e + 1] = bfhi(a0[e]) + bfhi(a1[e]) + bfhi(a2[e]) + bfhi(a3[e]);
        }
    }
    float rr = 1.f;
    if (DORMS){
        int m = m0 + row;
        float ssum = sspart[m] + sspart[Mn + m] + sspart[2*Mn + m] + sspart[3*Mn + m];
        rr = rsqrtf(ssum * (1.f / 1024.f) + 1.1920929e-07f);
    }
    #pragma unroll
    for (int i = 0; i < 16; ++i) s[i] *= rr;
    int swz = (row & 7) << 4;
    uint4 p0 = {pk2(s[0],s[1]), pk2(s[2],s[3]), pk2(s[4],s[5]), pk2(s[6],s[7])};
    uint4 p1 = {pk2(s[8],s[9]), pk2(s[10],s[11]), pk2(s[12],s[13]), pk2(s[14],s[15])};
    *(uint4*)(tt + row * 128 + ((q4 * 32) ^ swz)) = p0;
    *(uint4*)(tt + row * 128 + ((q4 * 32 + 16) ^ swz)) = p1;
}

// ---------------- up GEMM (final projection): DMA Bt image
template<int SILU, int HASBASE, int OUT_BF16, int DORMS>
__global__ __launch_bounds__(256) void up_g(const unsigned short* __restrict__ tpart,
                                            const float* __restrict__ sspart,
                                            const char* __restrict__ BtImg,
                                            const float* base,
                                            void* __restrict__ outp){
    __shared__ char tt[4096];
    __shared__ char bb[32768];
    int tid = threadIdx.x;
    int m0 = blockIdx.x * 32, n0 = blockIdx.y * 256;
    int w = tid >> 6, lane = tid & 63, l4 = lane >> 4, lm = lane & 15;
    int wm = w & 1, wn = w >> 1;
    dma32k(BtImg + (size_t)blockIdx.y * 32768, bb, tid);
    if (tid < 128) stage_t<DORMS>(tt, tpart, sspart, m0, tid);
    __syncthreads();
    bf16x8 af[2];
    #pragma unroll
    for (int ks = 0; ks < 2; ++ks){
        int arow = 16 * wm + lm;
        af[ks] = *(const bf16x8*)(tt + arow * 128 + ((ks*64 + l4*16) ^ ((arow & 7) << 4)));
    }
    f32x4 acc[8];
    #pragma unroll
    for (int nt = 0; nt < 8; ++nt) acc[nt] = (f32x4){0.f,0.f,0.f,0.f};
    #pragma unroll
    for (int nt = 0; nt < 8; ++nt){
        int brow = wn * 128 + nt * 16 + lm;
        #pragma unroll
        for (int ks = 0; ks < 2; ++ks){
            bf16x8 bf = *(const bf16x8*)(bb + brow * 128 + ((ks*64 + l4*16) ^ ((brow & 7) << 4)));
            acc[nt] = __builtin_amdgcn_mfma_f32_16x16x32_bf16(af[ks], bf, acc[nt], 0, 0, 0);
        }
    }
    #pragma unroll
    for (int nt = 0; nt < 8; ++nt)
        #pragma unroll
        for (int r = 0; r < 4; ++r){
            int m = m0 + 16 * wm + 4 * l4 + r;
            int n = n0 + wn * 128 + nt * 16 + lm;
            float v = acc[nt][r];
            if (SILU) v = v / (1.f + __expf(-v));
            if (HASBASE) v += base[(size_t)m * 1024 + n];
            if (OUT_BF16) ((unsigned short*)outp)[(size_t)m * 1024 + n] = f2bf(v);
            else          ((float*)outp)[(size_t)m * 1024 + n] = v;
        }
}

// ---------------- FUSED up->down: DMA BtU image, DMA AtD ud-image; bf16 tpout
template<int SILU, int HASBASE, int STOREOUT, int SUMSQ, int DORMS_IN>
__global__ __launch_bounds__(256) void updown_g(const unsigned short* __restrict__ tpin,
                                                const float* __restrict__ sspin,
                                                const char* __restrict__ BtUimg,
                                                const char* __restrict__ AtDimg,
                                                const float* base,
                                                float* outp,
                                                unsigned short* __restrict__ tpout,
                                                float* __restrict__ sspout){
    __shared__ char tt[4096];
    __shared__ char bb[32768];     // BtU image, later AtD image
    __shared__ char xb[16384];     // bounced up-output tile [32][256] bf16
    __shared__ float ssl[2][32];
    int tid = threadIdx.x;
    int m0 = blockIdx.x * 32, n0 = blockIdx.y * 256, sp = blockIdx.y;
    int w = tid >> 6, lane = tid & 63, l4 = lane >> 4, lm = lane & 15;
    int wm = w & 1, wn = w >> 1;
    dma32k(BtUimg + (size_t)sp * 32768, bb, tid);
    if (tid < 128) stage_t<DORMS_IN>(tt, tpin, sspin, m0, tid);
    __syncthreads();
    // ---- up MFMA
    bf16x8 af[2];
    #pragma unroll
    for (int ks = 0; ks < 2; ++ks){
        int arow = 16 * wm + lm;
        af[ks] = *(const bf16x8*)(tt + arow * 128 + ((ks*64 + l4*16) ^ ((arow & 7) << 4)));
    }
    f32x4 acc[8];
    #pragma unroll
    for (int nt = 0; nt < 8; ++nt) acc[nt] = (f32x4){0.f,0.f,0.f,0.f};
    #pragma unroll
    for (int nt = 0; nt < 8; ++nt){
        int brow = wn * 128 + nt * 16 + lm;
        #pragma unroll
        for (int ks = 0; ks < 2; ++ks){
            bf16x8 bf = *(const bf16x8*)(bb + brow * 128 + ((ks*64 + l4*16) ^ ((brow & 7) << 4)));
            acc[nt] = __builtin_amdgcn_mfma_f32_16x16x32_bf16(af[ks], bf, acc[nt], 0, 0, 0);
        }
    }
    // ---- epilogue
    float val[8][4];
    float sq[4] = {0.f, 0.f, 0.f, 0.f};
    #pragma unroll
    for (int nt = 0; nt < 8; ++nt)
        #pragma unroll
        for (int r = 0; r < 4; ++r){
            int m = m0 + 16 * wm + 4 * l4 + r;
            int n = n0 + wn * 128 + nt * 16 + lm;
            float v = acc[nt][r];
            if (SILU) v = v / (1.f + __expf(-v));
            if (HASBASE) v += base[(size_t)m * 1024 + n];
            val[nt][r] = v;
            if (STOREOUT) outp[(size_t)m * 1024 + n] = v;
            if (SUMSQ) sq[r] += v * v;
        }
    if (SUMSQ){
        #pragma unroll
        for (int r = 0; r < 4; ++r){
            float s_ = sq[r];
            s_ += __shfl_xor(s_, 1);
            s_ += __shfl_xor(s_, 2);
            s_ += __shfl_xor(s_, 4);
            s_ += __shfl_xor(s_, 8);
            if (lm == 0) ssl[wn][16 * wm + 4 * l4 + r] = s_;
        }
    }
    __syncthreads();   // bb reads done, ssl visible
    // ---- DMA AtD ud-image into bb; bounce val -> xb
    dma32k(AtDimg + (size_t)sp * 32768, bb, tid);
    #pragma unroll
    for (int nt = 0; nt < 8; ++nt)
        #pragma unroll
        for (int r = 0; r < 4; ++r){
            int mrow = 16 * wm + 4 * l4 + r;
            int cn = wn * 128 + nt * 16 + lm;
            *(unsigned short*)(xb + mrow * 512 + ((cn * 2) ^ ((mrow & 7) << 4))) = f2bf(val[nt][r]);
        }
    __syncthreads();
    if (SUMSQ && tid < 32)
        sspout[sp * Mn + m0 + tid] = ssl[0][tid] + ssl[1][tid];
    // ---- down MFMA
    f32x4 acc2[2];
    acc2[0] = (f32x4){0.f,0.f,0.f,0.f};
    acc2[1] = (f32x4){0.f,0.f,0.f,0.f};
    #pragma unroll
    for (int kk = 0; kk < 8; ++kk){
        int arow = 16 * (w & 1) + lm;
        bf16x8 a2 = *(const bf16x8*)(xb + arow * 512 + ((kk * 64 + l4 * 16) ^ ((arow & 7) << 4)));
        #pragma unroll
        for (int j = 0; j < 2; ++j){
            int brow = (2 * (w >> 1) + j) * 16 + lm;
            bf16x8 b2 = *(const bf16x8*)(bb + brow * 512 + ((kk * 64 + l4 * 16) ^ ((brow & 7) << 4)));
            acc2[j] = __builtin_amdgcn_mfma_f32_16x16x32_bf16(a2, b2, acc2[j], 0, 0, 0);
        }
    }
    #pragma unroll
    for (int j = 0; j < 2; ++j)
        #pragma unroll
        for (int r = 0; r < 4; ++r){
            int ml = 16 * (w & 1) + 4 * l4 + r;
            int nc = (2 * (w >> 1) + j) * 16 + lm;
            tpout[(size_t)sp * TSTRIDE + (size_t)(m0 + ml) * 64 + nc] = f2bf(acc2[j][r]);
        }
}

// ---------------- fused QKV up-proj + RoPE; DMA Bt images; K,V pre-swizzled tile images out
__global__ __launch_bounds__(256) void qkv_g(const unsigned short* __restrict__ tpart,
                                             const float* __restrict__ sspart,
                                             const char* __restrict__ BIq,
                                             const char* __restrict__ BIk,
                                             const char* __restrict__ BIv,
                                             const float2* __restrict__ rt,
                                             unsigned short* __restrict__ qout,
                                             char* __restrict__ Kimg,
                                             char* __restrict__ Vimg){
    __shared__ char tt[8192];
    __shared__ char bb[32768];
    int tid = threadIdx.x;
    int m0 = blockIdx.x * 64, n0 = blockIdx.y * 256;
    int b = m0 >> 11, s0 = m0 & (Sn - 1);
    int h0 = n0 >> 7;
    int w = tid >> 6, lane = tid & 63, l4 = lane >> 4, lm = lane & 15;
    dma32k(BIq + (size_t)blockIdx.y * 32768, bb, tid);
    stage_t<1>(tt, tpart, sspart, m0, tid);
    __syncthreads();
    bf16x8 af[2];
    #pragma unroll
    for (int ks = 0; ks < 2; ++ks){
        int arow = 16 * w + lm;
        af[ks] = *(const bf16x8*)(tt + arow * 128 + ((ks*64 + l4*16) ^ ((arow & 7) << 4)));
    }
    f32x4 acc[16];
    float2 cs[4][4];
    #pragma unroll
    for (int ntb = 0; ntb < 4; ++ntb)
        #pragma unroll
        for (int r = 0; r < 4; ++r)
            cs[ntb][r] = rt[(size_t)(s0 + 16*w + 4*l4 + r) * 64 + ntb * 16 + lm];

    #define MMUL() { _Pragma("unroll") for (int nt = 0; nt < 16; ++nt) acc[nt] = (f32x4){0.f,0.f,0.f,0.f}; \
        _Pragma("unroll") for (int nt = 0; nt < 16; ++nt){ int brow = nt * 16 + lm; \
            _Pragma("unroll") for (int ks = 0; ks < 2; ++ks){ \
                bf16x8 bf = *(const bf16x8*)(bb + brow * 128 + ((ks*64 + l4*16) ^ ((brow & 7) << 4))); \
                acc[nt] = __builtin_amdgcn_mfma_f32_16x16x32_bf16(af[ks], bf, acc[nt], 0, 0, 0); } } }

    #define ROPE() { _Pragma("unroll") for (int g = 0; g < 2; ++g) \
        _Pragma("unroll") for (int ntb = 0; ntb < 4; ++ntb){ int lo = g*8 + ntb, hi = lo + 4; \
            _Pragma("unroll") for (int r = 0; r < 4; ++r){ float2 c = cs[ntb][r]; \
                float a = acc[lo][r], bq = acc[hi][r]; \
                acc[lo][r] = a * c.x + bq * c.y; acc[hi][r] = -a * c.y + bq * c.x; } } }

    #define BOUNCE() { \
        _Pragma("unroll") for (int nt = 0; nt < 16; ++nt) \
            _Pragma("unroll") for (int r = 0; r < 4; ++r){ \
                int nl = nt * 16 + lm, ml2 = 16 * w + 4 * l4 + r; \
                *(unsigned short*)(bb + ml2 * 512 + ((nl * 2) ^ ((ml2 & 7) << 4))) = f2bf(acc[nt][r]); } \
        __syncthreads(); }

    // ---- Q (pre-scaled by 1/sqrt(128)*log2e via BIq)
    MMUL(); ROPE();
    __syncthreads();
    BOUNCE();
    {
        int ml = tid >> 2, seg = tid & 3;
        int head = h0 + (seg >> 1), hd0q = (seg & 1) * 64;
        size_t dstbase = (((size_t)(b * 8 + head) * Sn + (s0 + ml)) * 128 + hd0q);
        #pragma unroll
        for (int j = 0; j < 8; ++j){
            uint4 v = *(const uint4*)(bb + ml * 512 + ((seg * 128 + j * 16) ^ ((ml & 7) << 4)));
            *(uint4*)(qout + dstbase + j * 8) = v;
        }
    }
    __syncthreads();
    // ---- K -> permuted swizzled tile image
    dma32k(BIk + (size_t)blockIdx.y * 32768, bb, tid);
    __syncthreads();
    MMUL(); ROPE();
    __syncthreads();
    BOUNCE();
    {
        int ml = tid >> 2, seg = tid & 3;
        int hd0q = (seg & 1) * 64;
        int head = h0 + (seg >> 1);
        int pr = 16 * (ml & 3) + (ml >> 2);
        size_t rowb = (((size_t)(b * 8 + head) * 32 + (s0 >> 6)) * 64 + pr) * 256;
        #pragma unroll
        for (int j = 0; j < 8; ++j){
            uint4 v = *(const uint4*)(bb + ml * 512 + ((seg * 128 + j * 16) ^ ((ml & 7) << 4)));
            int cb = hd0q * 2 + j * 16;
            *(uint4*)(Kimg + rowb + (cb ^ ((pr & 7) << 4))) = v;
        }
    }
    __syncthreads();
    // ---- V -> transposed swizzled tile image
    dma32k(BIv + (size_t)blockIdx.y * 32768, bb, tid);
    __syncthreads();
    MMUL();
    __syncthreads();
    #pragma unroll
    for (int nt = 0; nt < 16; ++nt)
        #pragma unroll
        for (int r = 0; r < 4; ++r){
            int nl = nt * 16 + lm, ml2 = 16 * w + 4 * l4 + r;
            *(unsigned short*)(bb + nl * 128 + ((ml2 * 2) ^ ((nl & 7) << 4))) = f2bf(acc[nt][r]);
        }
    __syncthreads();
    {
        int head = h0 + (tid >> 7), d = tid & 127;
        size_t rowb = (((size_t)(b * 8 + head) * 32 + (s0 >> 6)) * 128 + d) * 128;
        #pragma unroll
        for (int j = 0; j < 8; ++j){
            uint4 v = *(const uint4*)(bb + tid * 128 + ((j * 16) ^ ((tid & 7) << 4)));
            *(uint4*)(Vimg + rowb + ((j * 16) ^ ((d & 7) << 4))) = v;
        }
    }
    #undef MMUL
    #undef ROPE
    #undef BOUNCE
}

// ---------------- K-split flash attention: K-only LDS dbuf (48KB, 3 blocks/CU),
// V fragments direct from swizzled Vimg (L2-resident, byte-identical offsets)
__global__ __launch_bounds__(256, 3) void attn2_kernel(const unsigned short* __restrict__ qb,
                                                       const char* __restrict__ Kimg,
                                                       const char* __restrict__ Vimg,
                                                       unsigned short* __restrict__ ybf,
                                                       unsigned short* __restrict__ pab,
                                                       float* __restrict__ pl){
    __shared__ uint4 smem4[49152 / 16];
    char* smem = (char*)smem4;
    int tid = threadIdx.x;
    int w = tid >> 6, lane = tid & 63, l4 = lane >> 4, lm = lane & 15;
    int i = blockIdx.x;
    int xg = i & 7, j5 = i >> 3;
    int bh = 2 * xg + (j5 & 1);
    int slot = j5 >> 1;
    int grp = slot >> 3, g = slot & 7;
    int J, t0, niters, direct, slice;
    if (grp == 0){ J = 8 + g;  t0 = 0;  niters = 16;         direct = 0; slice = (bh * 8 + g) * 2; }
    else if (grp == 1){ J = 15 - g; t0 = 16; niters = 2 * J - 14; direct = 0; slice = (bh * 8 + (J - 8)) * 2 + 1; }
    else { J = 7 - g;  t0 = 0;  niters = 2 * J + 2;  direct = 1; slice = 0; }
    int b = bh >> 3, h = bh & 7;
    int qrow0w = 128 * J + 32 * w;
    int wqmax = qrow0w + 31;

    bf16x8 qf[2][4];
    #pragma unroll
    for (int f = 0; f < 2; ++f){
        const unsigned short* qg = qb + ((size_t)bh * Sn + qrow0w + 16 * f + lm) * HDn;
        #pragma unroll
        for (int df = 0; df < 4; ++df)
            qf[f][df] = *(const bf16x8*)(qg + df * 32 + l4 * 8);
    }
    f32x4 acc[2][8];
    #pragma unroll
    for (int f = 0; f < 2; ++f)
        #pragma unroll
        for (int dg = 0; dg < 8; ++dg) acc[f][dg] = (f32x4){0.f,0.f,0.f,0.f};
    float lp[2][4];
    #pragma unroll
    for (int f = 0; f < 2; ++f)
        #pragma unroll
        for (int r = 0; r < 4; ++r) lp[f][r] = 0.f;

    const float OFF = 11.541560327111708f;   // 8 * log2(e)
    size_t imgbase = (size_t)bh * 32 * 16384;

    // K-only DMA stage: tile T -> LDS buffer at BUFB (16KB)
    #define STAGE_DMA(T, BUFB) { size_t tb = imgbase + (size_t)(T) * 16384; \
        _Pragma("unroll") for (int i2 = 0; i2 < 4; ++i2) \
            gld16(Kimg + tb + i2 * 4096 + tid * 16, smem + (BUFB) + i2 * 4096 + tid * 16); }

    STAGE_DMA(t0, 0);
    __syncthreads();

    for (int it = 0; it < niters; ++it){
        int t = t0 + it;
        int bsel = (it & 1) << 14;
        if (it + 1 < niters)
            STAGE_DMA(t + 1, bsel ^ 16384);
        if (64 * t <= wqmax){
            char* KL = smem + bsel;
            const char* VG = Vimg + imgbase + (size_t)t * 16384;
            char* pb = smem + 32768 + (w << 12);
            __builtin_amdgcn_s_setprio(1);
            f32x4 sf[2][4];
            #pragma unroll
            for (int kc = 0; kc < 4; ++kc){ sf[0][kc] = (f32x4){0.f,0.f,0.f,0.f}; sf[1][kc] = (f32x4){0.f,0.f,0.f,0.f}; }
            #pragma unroll
            for (int kc = 0; kc < 4; ++kc){
                int krow = 16 * kc + lm;
                int ksw = (krow & 7) << 4;
                #pragma unroll
                for (int df = 0; df < 4; ++df){
                    bf16x8 kf = *(const bf16x8*)(KL + krow * 256 + ((df * 64 + l4 * 16) ^ ksw));
                    sf[0][kc] = __builtin_amdgcn_mfma_f32_16x16x32_bf16(qf[0][df], kf, sf[0][kc], 0, 0, 0);
                    sf[1][kc] = __builtin_amdgcn_mfma_f32_16x16x32_bf16(qf[1][df], kf, sf[1][kc], 0, 0, 0);
                }
            }
            bool needmask = (64 * t + 63 > qrow0w);
            #pragma unroll
            for (int f = 0; f < 2; ++f){
                #pragma unroll
                for (int r = 0; r < 4; ++r){
                    float s0v = sf[f][0][r], s1v = sf[f][1][r],
                          s2v = sf[f][2][r], s3v = sf[f][3][r];
                    if (needmask){
                        int qr = qrow0w + 16 * f + 4 * l4 + r;
                        int j0k = 64 * t + 4 * lm;
                        s0v = (j0k     > qr) ? -1e30f : s0v;
                        s1v = (j0k + 1 > qr) ? -1e30f : s1v;
                        s2v = (j0k + 2 > qr) ? -1e30f : s2v;
                        s3v = (j0k + 3 > qr) ? -1e30f : s3v;
                    }
                    float p0 = vexp2(s0v - OFF), p1 = vexp2(s1v - OFF),
                          p2 = vexp2(s2v - OFF), p3 = vexp2(s3v - OFF);
                    lp[f][r] += p0 + p1 + p2 + p3;
                    int prow = 16 * f + 4 * l4 + r;
                    uint2 pkd = {pk2(p0, p1), pk2(p2, p3)};
                    *(uint2*)(pb + prow * 128 + ((lm * 8) ^ ((prow & 7) << 4))) = pkd;
                }
            }
            #pragma unroll
            for (int ks = 0; ks < 2; ++ks){
                int pcol = (ks * 64 + l4 * 16) ^ ((lm & 7) << 4);
                bf16x8 pa0 = *(const bf16x8*)(pb + lm * 128 + pcol);
                bf16x8 pa1 = *(const bf16x8*)(pb + (16 + lm) * 128 + pcol);
                #pragma unroll
                for (int dg = 0; dg < 8; ++dg){
                    int vrow = 16 * dg + lm;
                    bf16x8 vf = *(const bf16x8*)(VG + vrow * 128 + ((ks * 64 + l4 * 16) ^ ((vrow & 7) << 4)));
                    acc[0][dg] = __builtin_amdgcn_mfma_f32_16x16x32_bf16(pa0, vf, acc[0][dg], 0, 0, 0);
                    acc[1][dg] = __builtin_amdgcn_mfma_f32_16x16x32_bf16(pa1, vf, acc[1][dg], 0, 0, 0);
                }
            }
            __builtin_amdgcn_s_setprio(0);
        }
        __syncthreads();
    }
    #undef STAGE_DMA
    float lsum[2][4];
    #pragma unroll
    for (int f = 0; f < 2; ++f)
        #pragma unroll
        for (int r = 0; r < 4; ++r){
            float l_ = lp[f][r];
            l_ += __shfl_xor(l_, 1);
            l_ += __shfl_xor(l_, 2);
            l_ += __shfl_xor(l_, 4);
            l_ += __shfl_xor(l_, 8);
            lsum[f][r] = l_;
        }
    if (direct){
        #pragma unroll
        for (int f = 0; f < 2; ++f)
            #pragma unroll
            for (int r = 0; r < 4; ++r){
                float inv = 1.f / lsum[f][r];
                int row = qrow0w + 16 * f + 4 * l4 + r;
                unsigned short* yr = ybf + ((size_t)b * Sn + row) * Dn + h * HDn;
                #pragma unroll
                for (int dg = 0; dg < 8; ++dg)
                    yr[16 * dg + lm] = f2bf(acc[f][dg][r] * inv);
            }
    } else {
        unsigned short* pa_ = pab + (size_t)slice * 16384;
        #pragma unroll
        for (int f = 0; f < 2; ++f)
            #pragma unroll
            for (int r = 0; r < 4; ++r){
                int row = 32 * w + 16 * f + 4 * l4 + r;
                #pragma unroll
                for (int dg = 0; dg < 8; ++dg)
                    pa_[row * 128 + 16 * dg + lm] = f2bf(acc[f][dg][r]);
                if (lm == 0)
                    pl[slice * 128 + row] = lsum[f][r];
            }
    }
}

extern "C" void kernel_launch(void* const* d_in, const int* in_sizes, int n_in,
                              void* d_out, int out_size, void* d_ws, size_t ws_size,
                              hipStream_t stream){
    const float* x      = (const float*)d_in[0];
    const float* A      = (const float*)d_in[1];
    const float* Bm     = (const float*)d_in[2];
    const float* C_q    = (const float*)d_in[3];
    const float* C_k    = (const float*)d_in[4];
    const float* C_v    = (const float*)d_in[5];
    const float* C_o    = (const float*)d_in[6];
    const float* C_fc   = (const float*)d_in[7];
    const float* C_proj = (const float*)d_in[8];
    const float* scale1 = (const float*)d_in[9];
    const float* scale2 = (const float*)d_in[10];
    float* out = (float*)d_out;

    char* ws = (char*)d_ws;
    size_t off = 0;
    auto alloc = [&](size_t bytes)->char*{ char* p = ws + off; off += (bytes + 255) & ~(size_t)255; return p; };
    unsigned short* qb   = (unsigned short*)alloc((size_t)Mn * Dn * 2);   // 8MB
    char*           Kimg = alloc((size_t)16 * 32 * 16384);                // 8MB
    char*           Vimg = alloc((size_t)16 * 32 * 16384);                // 8MB
    unsigned short* ybf  = (unsigned short*)alloc((size_t)Mn * Dn * 2);   // 8MB
    unsigned short* pab  = (unsigned short*)alloc((size_t)256 * 16384 * 2); // 8MB
    float*          pl   = (float*)alloc((size_t)256 * 128 * 4);          // 128KB
    unsigned short* tpA  = (unsigned short*)alloc(4 * TSTRIDE * 2);       // 2MB (bf16)
    unsigned short* tpB  = (unsigned short*)alloc(4 * TSTRIDE * 2);       // 2MB (bf16)
    float*          sspA = (float*)alloc(4 * (size_t)Mn * 4);             // 64KB
    float*          sspB = (float*)alloc(4 * (size_t)Mn * 4);             // 64KB
    char*           AtI1c = alloc(131072);
    char*           AtI0c = alloc(131072);
    char*           AtI2u = alloc(131072);
    char*           AtI0u = alloc(131072);
    char*           BIq   = alloc(131072);
    char*           BIk   = alloc(131072);
    char*           BIv   = alloc(131072);
    char*           BIo   = alloc(131072);
    char*           BIfc  = alloc(131072);
    char*           BIpr  = alloc(131072);
    float2*         rt    = (float2*)alloc((size_t)Sn * 64 * 8);          // 1MB

    prep_g<<<3072, 256, 0, stream>>>(A, Bm, C_q, C_k, C_v, C_o, C_fc, C_proj,
                                     scale1, scale2,
                                     AtI1c, AtI0c, AtI2u, AtI0u,
                                     BIq, BIk, BIv, BIo, BIfc, BIpr, rt);
    // t1 partials = x @ At1 (s1 folded), ss = rowwise sumsq(x)
    down_g<<<dim3(Mn / 64, 4), 256, 0, stream>>>(x, AtI1c, tpA, sspA);
    // q (scaled+roped), K-image, V-image (rms fused in staging)
    qkv_g<<<dim3(Mn / 64, 4), 256, 0, stream>>>(tpA, sspA, BIq, BIk, BIv, rt, qb, Kimg, Vimg);
    // attention (direct y for j<8; bf16 partials for j>=8)
    attn2_kernel<<<384, 256, 0, stream>>>(qb, Kimg, Vimg, ybf, pab, pl);
    // t2 partials = y @ At0 with slice-combine fused into staging
    downy_g<<<dim3(Mn / 64, 4), 256, 0, stream>>>(ybf, pab, pl, AtI0c, tpA);
    // FUSED: x1 = x + t2@Bto -> out; sumsq(x1) -> sspB; t3 = x1@At2 -> tpB
    updown_g<0, 1, 1, 1, 0><<<dim3(Mn / 32, 4), 256, 0, stream>>>(
        tpA, nullptr, BIo, AtI2u, x, out, tpB, sspB);
    // FUSED: m = silu(rms(t3)@Btfc) (never stored); t4 = m@At0 -> tpA
    updown_g<1, 0, 0, 0, 1><<<dim3(Mn / 32, 4), 256, 0, stream>>>(
        tpB, sspB, BIfc, AtI0u, nullptr, nullptr, tpA, nullptr);
    // out = x1 + t4 @ Btpr
    up_g<0, 1, 0, 0><<<dim3(Mn / 32, 4), 256, 0, stream>>>(tpA, nullptr, BIpr, out, out);
}

// Round 21
// 109.298 us; speedup vs baseline: 1.3451x; 1.3451x over previous
//
#include <hip/hip_runtime.h>

// HolographicBlock: B=2, S=2048, D=1024, R=64, H=8, HD=128
// Pre-swizzled weight images + global_load_lds everywhere; bf16 t-partials.
// Attention = R17/R18 (DMA staging K+V 80KB dbuf, bf16 attention partials).
// (R19 configuration — best verified: 109.3 us)

#define Bn 2
#define Sn 2048
#define Dn 1024
#define Rn 64
#define Hn 8
#define HDn 128
#define Mn (Bn*Sn)   // 4096 rows
#define TSTRIDE ((size_t)Mn * Rn)

typedef __bf16 bf16x8 __attribute__((ext_vector_type(8)));
typedef float f32x4 __attribute__((ext_vector_type(4)));
typedef __attribute__((address_space(1))) const unsigned int g_u32;
typedef __attribute__((address_space(3))) unsigned int l_u32;

__device__ __forceinline__ float bf2f(unsigned short u){
    union { unsigned int i; float f; } x; x.i = ((unsigned int)u) << 16; return x.f;
}
__device__ __forceinline__ unsigned short f2bf(float f){
    union { float f; unsigned int i; } x; x.f = f;
    unsigned int r = x.i + 0x7fffu + ((x.i >> 16) & 1u);
    return (unsigned short)(r >> 16);
}
__device__ __forceinline__ unsigned int pk2(float a, float b){
    unsigned int r;
    asm("v_cvt_pk_bf16_f32 %0, %1, %2" : "=v"(r) : "v"(a), "v"(b));
    return r;
}
__device__ __forceinline__ float vexp2(float x){
    float r;
    asm("v_exp_f32 %0, %1" : "=v"(r) : "v"(x));
    return r;
}
__device__ __forceinline__ void gld16(const void* g, void* l){
    __builtin_amdgcn_global_load_lds((g_u32*)g, (l_u32*)l, 16, 0, 0);
}
__device__ __forceinline__ void dma32k(const char* src, char* dst, int tid){
    #pragma unroll
    for (int p = 0; p < 8; ++p)
        gld16(src + p * 4096 + tid * 16, dst + p * 4096 + tid * 16);
}
__device__ __forceinline__ float bflo(unsigned int u){
    union { unsigned int i; float f; } x; x.i = u << 16; return x.f;
}
__device__ __forceinline__ float bfhi(unsigned int u){
    union { unsigned int i; float f; } x; x.i = u & 0xffff0000u; return x.f;
}
__device__ __forceinline__ uint4 comb8(uint4 A, uint4 C, float Wc){
    uint4 r;
    unsigned int* a = (unsigned int*)&A;
    unsigned int* c = (unsigned int*)&C;
    unsigned int* o = (unsigned int*)&r;
    #pragma unroll
    for (int e = 0; e < 4; ++e){
        float lo = (bflo(a[e]) + bflo(c[e])) * Wc;
        float hi = (bfhi(a[e]) + bfhi(c[e])) * Wc;
        o[e] = pk2(lo, hi);
    }
    return r;
}

// ---------------- prep: PRE-SWIZZLED weight images + rope table
__global__ __launch_bounds__(256) void prep_g(const float* __restrict__ A,
                                              const float* __restrict__ Bsrc,
                                              const float* __restrict__ Cq, const float* __restrict__ Ck,
                                              const float* __restrict__ Cv, const float* __restrict__ Co,
                                              const float* __restrict__ Cfc, const float* __restrict__ Cpr,
                                              const float* __restrict__ s1, const float* __restrict__ s2,
                                              char* __restrict__ AtI1c, char* __restrict__ AtI0c,
                                              char* __restrict__ AtI2u, char* __restrict__ AtI0u,
                                              char* __restrict__ BIq, char* __restrict__ BIk,
                                              char* __restrict__ BIv, char* __restrict__ BIo,
                                              char* __restrict__ BIfc, char* __restrict__ BIpr,
                                              float2* __restrict__ rt){
    int idx = blockIdx.x * 256 + threadIdx.x;
    if (idx < 4 * 65536){
        int v = idx >> 16, e = idx & 65535;
        int r = e & 63, d = e >> 6;
        float sc = (v == 0) ? s1[d] : (v == 2) ? s2[d] : 1.f;
        unsigned short val = f2bf(A[d * 64 + r] * sc);
        if (v < 2){
            int us = (d >> 6) * 4096 + r * 64 + (((((d >> 3) & 7) << 4) ^ ((r & 7) << 4)) >> 1) + (d & 7);
            ((unsigned short*)(v == 0 ? AtI1c : AtI0c))[us] = val;
        } else {
            int us = (d >> 8) * 16384 + r * 256 + (((((d >> 3) & 31) << 4) ^ ((r & 7) << 4)) >> 1) + (d & 7);
            ((unsigned short*)(v == 2 ? AtI2u : AtI0u))[us] = val;
        }
    } else if (idx < 10 * 65536){
        int v = (idx >> 16) - 4, e = idx & 65535;
        int d = e & 1023, r = e >> 10;
        const float* C = v==0?Cq : v==1?Ck : v==2?Cv : v==3?Co : v==4?Cfc : Cpr;
        float extra = (v == 0) ? (0.08838834764831845f * 1.4426950408889634f) : 1.f;
        unsigned short val = f2bf(Bsrc[r * 1024 + d] * C[r] * extra);
        int us = (d >> 8) * 16384 + (d & 255) * 64 + ((((r >> 3) << 4) ^ ((d & 7) << 4)) >> 1) + (r & 7);
        ((unsigned short*)(v==0?BIq : v==1?BIk : v==2?BIv : v==3?BIo : v==4?BIfc : BIpr))[us] = val;
    } else if (idx < 10 * 65536 + Sn * 64){
        int e = idx - 10 * 65536;
        int s = e >> 6, f = e & 63;
        float inv = exp2f(-(float)f * (13.287712379549449f / 64.0f));
        float fr = (float)s * inv;
        float sn, cs; sincosf(fr, &sn, &cs);
        rt[e] = make_float2(cs, sn);
    }
}

// ---------------- down GEMM (f32 input + sumsq): DMA At image, bf16 t-partials out
__global__ __launch_bounds__(256) void down_g(const float* __restrict__ inp,
                                              const char* __restrict__ AtImg,
                                              unsigned short* __restrict__ tpart,
                                              float* __restrict__ sspart){
    __shared__ char xt[32768];
    __shared__ char at[32768];
    int tid = threadIdx.x;
    int m0 = blockIdx.x * 64, sp = blockIdx.y;
    int row = tid >> 2, q4 = tid & 3;
    int w = tid >> 6, lane = tid & 63, l4 = lane >> 4, lm = lane & 15;
    int swz = (row & 7) << 4;
    dma32k(AtImg + (size_t)sp * 32768, at, tid);
    float ss = 0.f;
    f32x4 acc[4];
    #pragma unroll
    for (int nt = 0; nt < 4; ++nt) acc[nt] = (f32x4){0.f,0.f,0.f,0.f};

    float4 xr[4];
    #define LOADX(c) { int k0 = sp * 256 + (c) * 64; \
        const float4* s = (const float4*)(inp + (size_t)(m0+row)*1024 + k0 + q4*16); \
        xr[0]=s[0]; xr[1]=s[1]; xr[2]=s[2]; xr[3]=s[3]; }

    LOADX(0);
    for (int c = 0; c < 4; ++c){
        char* xc = xt + c * 8192;
        #pragma unroll
        for (int i = 0; i < 4; ++i)
            ss += xr[i].x*xr[i].x + xr[i].y*xr[i].y + xr[i].z*xr[i].z + xr[i].w*xr[i].w;
        uint4 p0 = {pk2(xr[0].x,xr[0].y), pk2(xr[0].z,xr[0].w), pk2(xr[1].x,xr[1].y), pk2(xr[1].z,xr[1].w)};
        uint4 p1 = {pk2(xr[2].x,xr[2].y), pk2(xr[2].z,xr[2].w), pk2(xr[3].x,xr[3].y), pk2(xr[3].z,xr[3].w)};
        *(uint4*)(xc + row * 128 + ((q4 * 32) ^ swz)) = p0;
        *(uint4*)(xc + row * 128 + ((q4 * 32 + 16) ^ swz)) = p1;
        __syncthreads();            // c==0 also drains the At DMA
        if (c < 3) LOADX(c + 1);
        #pragma unroll
        for (int ks = 0; ks < 2; ++ks){
            int arow = 16 * w + lm;
            bf16x8 af = *(const bf16x8*)(xc + arow * 128 + ((ks*64 + l4*16) ^ ((arow & 7) << 4)));
            #pragma unroll
            for (int nt = 0; nt < 4; ++nt){
                int brow = nt * 16 + lm;
                bf16x8 bf = *(const bf16x8*)(at + c * 8192 + brow * 128 + ((ks*64 + l4*16) ^ ((brow & 7) << 4)));
                acc[nt] = __builtin_amdgcn_mfma_f32_16x16x32_bf16(af, bf, acc[nt], 0, 0, 0);
            }
        }
    }
    #undef LOADX
    ss += __shfl_xor(ss, 1); ss += __shfl_xor(ss, 2);
    if (q4 == 0) sspart[sp * Mn + m0 + row] = ss;
    #pragma unroll
    for (int nt = 0; nt < 4; ++nt)
        #pragma unroll
        for (int r = 0; r < 4; ++r){
            int ml = 16 * w + 4 * l4 + r;
            tpart[(size_t)sp * TSTRIDE + (size_t)(m0 + ml) * 64 + nt * 16 + lm] = f2bf(acc[nt][r]);
        }
}

// ---------------- down GEMM for y (fused slice-combine), bf16 t-partials out
__global__ __launch_bounds__(256) void downy_g(const unsigned short* __restrict__ ybf,
                                               const unsigned short* __restrict__ pab,
                                               const float* __restrict__ pl,
                                               const char* __restrict__ AtImg,
                                               unsigned short* __restrict__ tpart){
    __shared__ char xt[32768];
    __shared__ char at[32768];
    int tid = threadIdx.x;
    int m0 = blockIdx.x * 64, sp = blockIdx.y;
    int row = tid >> 2, q4 = tid & 3;
    int w = tid >> 6, lane = tid & 63, l4 = lane >> 4, lm = lane & 15;
    int swz = (row & 7) << 4;
    int jq = (m0 & (Sn - 1)) >> 7;
    int bpos = m0 >> 11;
    int srow = (m0 & 127) + row;
    dma32k(AtImg + (size_t)sp * 32768, at, tid);
    f32x4 acc[4];
    #pragma unroll
    for (int nt = 0; nt < 4; ++nt) acc[nt] = (f32x4){0.f,0.f,0.f,0.f};

    #define MFMAC(c) { \
        _Pragma("unroll") \
        for (int ks = 0; ks < 2; ++ks){ \
            int arow = 16 * w + lm; \
            bf16x8 af = *(const bf16x8*)(xt + (c) * 8192 + arow * 128 + ((ks*64 + l4*16) ^ ((arow & 7) << 4))); \
            _Pragma("unroll") \
            for (int nt = 0; nt < 4; ++nt){ \
                int brow = nt * 16 + lm; \
                bf16x8 bf = *(const bf16x8*)(at + (c) * 8192 + brow * 128 + ((ks*64 + l4*16) ^ ((brow & 7) << 4))); \
                acc[nt] = __builtin_amdgcn_mfma_f32_16x16x32_bf16(af, bf, acc[nt], 0, 0, 0); \
            } \
        } }

    if (jq < 8){
        const char* yb = (const char*)ybf;
        #pragma unroll
        for (int p = 0; p < 8; ++p){
            int c = p >> 1;
            int rw = (p & 1) * 32 + (tid >> 3);
            int gp = (tid & 7) ^ (rw & 7);
            gld16(yb + (size_t)(m0 + rw) * 2048 + sp * 512 + c * 128 + gp * 16,
                  xt + p * 4096 + tid * 16);
        }
        __syncthreads();
        for (int c = 0; c < 4; ++c) MFMAC(c);
    } else {
        uint4 xrb[2];
        #define LOADCMB(c) { int k0 = sp * 256 + (c) * 64; \
            int h = k0 >> 7; int d0 = k0 & 127; \
            int s0sl = (((bpos * 8 + h) * 8) + (jq - 8)) * 2; \
            const unsigned short* p0 = pab + (size_t)s0sl * 16384 + srow * 128 + d0 + q4 * 16; \
            const unsigned short* p1 = p0 + 16384; \
            float Wc = 1.f / (pl[s0sl * 128 + srow] + pl[(s0sl + 1) * 128 + srow]); \
            uint4 A0 = ((const uint4*)p0)[0], A1 = ((const uint4*)p0)[1]; \
            uint4 C0 = ((const uint4*)p1)[0], C1 = ((const uint4*)p1)[1]; \
            xrb[0] = comb8(A0, C0, Wc); xrb[1] = comb8(A1, C1, Wc); }
        LOADCMB(0);
        for (int c = 0; c < 4; ++c){
            char* xc = xt + c * 8192;
            *(uint4*)(xc + row * 128 + ((q4 * 32) ^ swz)) = xrb[0];
            *(uint4*)(xc + row * 128 + ((q4 * 32 + 16) ^ swz)) = xrb[1];
            __syncthreads();
            if (c < 3) LOADCMB(c + 1);
            MFMAC(c);
        }
        #undef LOADCMB
    }
    #undef MFMAC
    #pragma unroll
    for (int nt = 0; nt < 4; ++nt)
        #pragma unroll
        for (int r = 0; r < 4; ++r){
            int ml = 16 * w + 4 * l4 + r;
            tpart[(size_t)sp * TSTRIDE + (size_t)(m0 + ml) * 64 + nt * 16 + lm] = f2bf(acc[nt][r]);
        }
}

// ---------------- stage t tile (sum 4 bf16 K-split partials, optional rms) into swizzled LDS
template<int DORMS>
__device__ __forceinline__ void stage_t(char* tt, const unsigned short* __restrict__ tpart,
                                        const float* __restrict__ sspart, int m0, int tid){
    int row = tid >> 2, q4 = tid & 3;
    const unsigned short* bp = tpart + (size_t)(m0 + row) * 64 + q4 * 16;
    float s[16];
    #pragma unroll
    for (int half = 0; half < 2; ++half){
        uint4 u0 = ((const uint4*)(bp + 0 * TSTRIDE))[half];
        uint4 u1 = ((const uint4*)(bp + 1 * TSTRIDE))[half];
        uint4 u2 = ((const uint4*)(bp + 2 * TSTRIDE))[half];
        uint4 u3 = ((const uint4*)(bp + 3 * TSTRIDE))[half];
        const unsigned int* a0 = (const unsigned int*)&u0;
        const unsigned int* a1 = (const unsigned int*)&u1;
        const unsigned int* a2 = (const unsigned int*)&u2;
        const unsigned int* a3 = (const unsigned int*)&u3;
        #pragma unroll
        for (int e = 0; e < 4; ++e){
            s[half*8 + 2*e]     = bflo(a0[e]) + bflo(a1[e]) + bflo(a2[e]) + bflo(a3[e]);
            s[half*8 + 2*e + 1] = bfhi(a0[e]) + bfhi(a1[e]) + bfhi(a2[e]) + bfhi(a3[e]);
        }
    }
    float rr = 1.f;
    if (DORMS){
        int m = m0 + row;
        float ssum = sspart[m] + sspart[Mn + m] + sspart[2*Mn + m] + sspart[3*Mn + m];
        rr = rsqrtf(ssum * (1.f / 1024.f) + 1.1920929e-07f);
    }
    #pragma unroll
    for (int i = 0; i < 16; ++i) s[i] *= rr;
    int swz = (row & 7) << 4;
    uint4 p0 = {pk2(s[0],s[1]), pk2(s[2],s[3]), pk2(s[4],s[5]), pk2(s[6],s[7])};
    uint4 p1 = {pk2(s[8],s[9]), pk2(s[10],s[11]), pk2(s[12],s[13]), pk2(s[14],s[15])};
    *(uint4*)(tt + row * 128 + ((q4 * 32) ^ swz)) = p0;
    *(uint4*)(tt + row * 128 + ((q4 * 32 + 16) ^ swz)) = p1;
}

// ---------------- up GEMM (final projection): DMA Bt image
template<int SILU, int HASBASE, int OUT_BF16, int DORMS>
__global__ __launch_bounds__(256) void up_g(const unsigned short* __restrict__ tpart,
                                            const float* __restrict__ sspart,
                                            const char* __restrict__ BtImg,
                                            const float* base,
                                            void* __restrict__ outp){
    __shared__ char tt[4096];
    __shared__ char bb[32768];
    int tid = threadIdx.x;
    int m0 = blockIdx.x * 32, n0 = blockIdx.y * 256;
    int w = tid >> 6, lane = tid & 63, l4 = lane >> 4, lm = lane & 15;
    int wm = w & 1, wn = w >> 1;
    dma32k(BtImg + (size_t)blockIdx.y * 32768, bb, tid);
    if (tid < 128) stage_t<DORMS>(tt, tpart, sspart, m0, tid);
    __syncthreads();
    bf16x8 af[2];
    #pragma unroll
    for (int ks = 0; ks < 2; ++ks){
        int arow = 16 * wm + lm;
        af[ks] = *(const bf16x8*)(tt + arow * 128 + ((ks*64 + l4*16) ^ ((arow & 7) << 4)));
    }
    f32x4 acc[8];
    #pragma unroll
    for (int nt = 0; nt < 8; ++nt) acc[nt] = (f32x4){0.f,0.f,0.f,0.f};
    #pragma unroll
    for (int nt = 0; nt < 8; ++nt){
        int brow = wn * 128 + nt * 16 + lm;
        #pragma unroll
        for (int ks = 0; ks < 2; ++ks){
            bf16x8 bf = *(const bf16x8*)(bb + brow * 128 + ((ks*64 + l4*16) ^ ((brow & 7) << 4)));
            acc[nt] = __builtin_amdgcn_mfma_f32_16x16x32_bf16(af[ks], bf, acc[nt], 0, 0, 0);
        }
    }
    #pragma unroll
    for (int nt = 0; nt < 8; ++nt)
        #pragma unroll
        for (int r = 0; r < 4; ++r){
            int m = m0 + 16 * wm + 4 * l4 + r;
            int n = n0 + wn * 128 + nt * 16 + lm;
            float v = acc[nt][r];
            if (SILU) v = v / (1.f + __expf(-v));
            if (HASBASE) v += base[(size_t)m * 1024 + n];
            if (OUT_BF16) ((unsigned short*)outp)[(size_t)m * 1024 + n] = f2bf(v);
            else          ((float*)outp)[(size_t)m * 1024 + n] = v;
        }
}

// ---------------- FUSED up->down: DMA BtU image, DMA AtD ud-image; bf16 tpout
template<int SILU, int HASBASE, int STOREOUT, int SUMSQ, int DORMS_IN>
__global__ __launch_bounds__(256) void updown_g(const unsigned short* __restrict__ tpin,
                                                const float* __restrict__ sspin,
                                                const char* __restrict__ BtUimg,
                                                const char* __restrict__ AtDimg,
                                                const float* base,
                                                float* outp,
                                                unsigned short* __restrict__ tpout,
                                                float* __restrict__ sspout){
    __shared__ char tt[4096];
    __shared__ char bb[32768];     // BtU image, later AtD image
    __shared__ char xb[16384];     // bounced up-output tile [32][256] bf16
    __shared__ float ssl[2][32];
    int tid = threadIdx.x;
    int m0 = blockIdx.x * 32, n0 = blockIdx.y * 256, sp = blockIdx.y;
    int w = tid >> 6, lane = tid & 63, l4 = lane >> 4, lm = lane & 15;
    int wm = w & 1, wn = w >> 1;
    dma32k(BtUimg + (size_t)sp * 32768, bb, tid);
    if (tid < 128) stage_t<DORMS_IN>(tt, tpin, sspin, m0, tid);
    __syncthreads();
    // ---- up MFMA
    bf16x8 af[2];
    #pragma unroll
    for (int ks = 0; ks < 2; ++ks){
        int arow = 16 * wm + lm;
        af[ks] = *(const bf16x8*)(tt + arow * 128 + ((ks*64 + l4*16) ^ ((arow & 7) << 4)));
    }
    f32x4 acc[8];
    #pragma unroll
    for (int nt = 0; nt < 8; ++nt) acc[nt] = (f32x4){0.f,0.f,0.f,0.f};
    #pragma unroll
    for (int nt = 0; nt < 8; ++nt){
        int brow = wn * 128 + nt * 16 + lm;
        #pragma unroll
        for (int ks = 0; ks < 2; ++ks){
            bf16x8 bf = *(const bf16x8*)(bb + brow * 128 + ((ks*64 + l4*16) ^ ((brow & 7) << 4)));
            acc[nt] = __builtin_amdgcn_mfma_f32_16x16x32_bf16(af[ks], bf, acc[nt], 0, 0, 0);
        }
    }
    // ---- epilogue
    float val[8][4];
    float sq[4] = {0.f, 0.f, 0.f, 0.f};
    #pragma unroll
    for (int nt = 0; nt < 8; ++nt)
        #pragma unroll
        for (int r = 0; r < 4; ++r){
            int m = m0 + 16 * wm + 4 * l4 + r;
            int n = n0 + wn * 128 + nt * 16 + lm;
            float v = acc[nt][r];
            if (SILU) v = v / (1.f + __expf(-v));
            if (HASBASE) v += base[(size_t)m * 1024 + n];
            val[nt][r] = v;
            if (STOREOUT) outp[(size_t)m * 1024 + n] = v;
            if (SUMSQ) sq[r] += v * v;
        }
    if (SUMSQ){
        #pragma unroll
        for (int r = 0; r < 4; ++r){
            float s_ = sq[r];
            s_ += __shfl_xor(s_, 1);
            s_ += __shfl_xor(s_, 2);
            s_ += __shfl_xor(s_, 4);
            s_ += __shfl_xor(s_, 8);
            if (lm == 0) ssl[wn][16 * wm + 4 * l4 + r] = s_;
        }
    }
    __syncthreads();   // bb reads done, ssl visible
    // ---- DMA AtD ud-image into bb; bounce val -> xb
    dma32k(AtDimg + (size_t)sp * 32768, bb, tid);
    #pragma unroll
    for (int nt = 0; nt < 8; ++nt)
        #pragma unroll
        for (int r = 0; r < 4; ++r){
            int mrow = 16 * wm + 4 * l4 + r;
            int cn = wn * 128 + nt * 16 + lm;
            *(unsigned short*)(xb + mrow * 512 + ((cn * 2) ^ ((mrow & 7) << 4))) = f2bf(val[nt][r]);
        }
    __syncthreads();
    if (SUMSQ && tid < 32)
        sspout[sp * Mn + m0 + tid] = ssl[0][tid] + ssl[1][tid];
    // ---- down MFMA
    f32x4 acc2[2];
    acc2[0] = (f32x4){0.f,0.f,0.f,0.f};
    acc2[1] = (f32x4){0.f,0.f,0.f,0.f};
    #pragma unroll
    for (int kk = 0; kk < 8; ++kk){
        int arow = 16 * (w & 1) + lm;
        bf16x8 a2 = *(const bf16x8*)(xb + arow * 512 + ((kk * 64 + l4 * 16) ^ ((arow & 7) << 4)));
        #pragma unroll
        for (int j = 0; j < 2; ++j){
            int brow = (2 * (w >> 1) + j) * 16 + lm;
            bf16x8 b2 = *(const bf16x8*)(bb + brow * 512 + ((kk * 64 + l4 * 16) ^ ((brow & 7) << 4)));
            acc2[j] = __builtin_amdgcn_mfma_f32_16x16x32_bf16(a2, b2, acc2[j], 0, 0, 0);
        }
    }
    #pragma unroll
    for (int j = 0; j < 2; ++j)
        #pragma unroll
        for (int r = 0; r < 4; ++r){
            int ml = 16 * (w & 1) + 4 * l4 + r;
            int nc = (2 * (w >> 1) + j) * 16 + lm;
            tpout[(size_t)sp * TSTRIDE + (size_t)(m0 + ml) * 64 + nc] = f2bf(acc2[j][r]);
        }
}

// ---------------- fused QKV up-proj + RoPE; DMA Bt images; K,V pre-swizzled tile images out
__global__ __launch_bounds__(256) void qkv_g(const unsigned short* __restrict__ tpart,
                                             const float* __restrict__ sspart,
                                             const char* __restrict__ BIq,
                                             const char* __restrict__ BIk,
                                             const char* __restrict__ BIv,
                                             const float2* __restrict__ rt,
                                             unsigned short* __restrict__ qout,
                                             char* __restrict__ Kimg,
                                             char* __restrict__ Vimg){
    __shared__ char tt[8192];
    __shared__ char bb[32768];
    int tid = threadIdx.x;
    int m0 = blockIdx.x * 64, n0 = blockIdx.y * 256;
    int b = m0 >> 11, s0 = m0 & (Sn - 1);
    int h0 = n0 >> 7;
    int w = tid >> 6, lane = tid & 63, l4 = lane >> 4, lm = lane & 15;
    dma32k(BIq + (size_t)blockIdx.y * 32768, bb, tid);
    stage_t<1>(tt, tpart, sspart, m0, tid);
    __syncthreads();
    bf16x8 af[2];
    #pragma unroll
    for (int ks = 0; ks < 2; ++ks){
        int arow = 16 * w + lm;
        af[ks] = *(const bf16x8*)(tt + arow * 128 + ((ks*64 + l4*16) ^ ((arow & 7) << 4)));
    }
    f32x4 acc[16];
    float2 cs[4][4];
    #pragma unroll
    for (int ntb = 0; ntb < 4; ++ntb)
        #pragma unroll
        for (int r = 0; r < 4; ++r)
            cs[ntb][r] = rt[(size_t)(s0 + 16*w + 4*l4 + r) * 64 + ntb * 16 + lm];

    #define MMUL() { _Pragma("unroll") for (int nt = 0; nt < 16; ++nt) acc[nt] = (f32x4){0.f,0.f,0.f,0.f}; \
        _Pragma("unroll") for (int nt = 0; nt < 16; ++nt){ int brow = nt * 16 + lm; \
            _Pragma("unroll") for (int ks = 0; ks < 2; ++ks){ \
                bf16x8 bf = *(const bf16x8*)(bb + brow * 128 + ((ks*64 + l4*16) ^ ((brow & 7) << 4))); \
                acc[nt] = __builtin_amdgcn_mfma_f32_16x16x32_bf16(af[ks], bf, acc[nt], 0, 0, 0); } } }

    #define ROPE() { _Pragma("unroll") for (int g = 0; g < 2; ++g) \
        _Pragma("unroll") for (int ntb = 0; ntb < 4; ++ntb){ int lo = g*8 + ntb, hi = lo + 4; \
            _Pragma("unroll") for (int r = 0; r < 4; ++r){ float2 c = cs[ntb][r]; \
                float a = acc[lo][r], bq = acc[hi][r]; \
                acc[lo][r] = a * c.x + bq * c.y; acc[hi][r] = -a * c.y + bq * c.x; } } }

    #define BOUNCE() { \
        _Pragma("unroll") for (int nt = 0; nt < 16; ++nt) \
            _Pragma("unroll") for (int r = 0; r < 4; ++r){ \
                int nl = nt * 16 + lm, ml2 = 16 * w + 4 * l4 + r; \
                *(unsigned short*)(bb + ml2 * 512 + ((nl * 2) ^ ((ml2 & 7) << 4))) = f2bf(acc[nt][r]); } \
        __syncthreads(); }

    // ---- Q (pre-scaled by 1/sqrt(128)*log2e via BIq)
    MMUL(); ROPE();
    __syncthreads();
    BOUNCE();
    {
        int ml = tid >> 2, seg = tid & 3;
        int head = h0 + (seg >> 1), hd0q = (seg & 1) * 64;
        size_t dstbase = (((size_t)(b * 8 + head) * Sn + (s0 + ml)) * 128 + hd0q);
        #pragma unroll
        for (int j = 0; j < 8; ++j){
            uint4 v = *(const uint4*)(bb + ml * 512 + ((seg * 128 + j * 16) ^ ((ml & 7) << 4)));
            *(uint4*)(qout + dstbase + j * 8) = v;
        }
    }
    __syncthreads();
    // ---- K -> permuted swizzled tile image
    dma32k(BIk + (size_t)blockIdx.y * 32768, bb, tid);
    __syncthreads();
    MMUL(); ROPE();
    __syncthreads();
    BOUNCE();
    {
        int ml = tid >> 2, seg = tid & 3;
        int hd0q = (seg & 1) * 64;
        int head = h0 + (seg >> 1);
        int pr = 16 * (ml & 3) + (ml >> 2);
        size_t rowb = (((size_t)(b * 8 + head) * 32 + (s0 >> 6)) * 64 + pr) * 256;
        #pragma unroll
        for (int j = 0; j < 8; ++j){
            uint4 v = *(const uint4*)(bb + ml * 512 + ((seg * 128 + j * 16) ^ ((ml & 7) << 4)));
            int cb = hd0q * 2 + j * 16;
            *(uint4*)(Kimg + rowb + (cb ^ ((pr & 7) << 4))) = v;
        }
    }
    __syncthreads();
    // ---- V -> transposed swizzled tile image
    dma32k(BIv + (size_t)blockIdx.y * 32768, bb, tid);
    __syncthreads();
    MMUL();
    __syncthreads();
    #pragma unroll
    for (int nt = 0; nt < 16; ++nt)
        #pragma unroll
        for (int r = 0; r < 4; ++r){
            int nl = nt * 16 + lm, ml2 = 16 * w + 4 * l4 + r;
            *(unsigned short*)(bb + nl * 128 + ((ml2 * 2) ^ ((nl & 7) << 4))) = f2bf(acc[nt][r]);
        }
    __syncthreads();
    {
        int head = h0 + (tid >> 7), d = tid & 127;
        size_t rowb = (((size_t)(b * 8 + head) * 32 + (s0 >> 6)) * 128 + d) * 128;
        #pragma unroll
        for (int j = 0; j < 8; ++j){
            uint4 v = *(const uint4*)(bb + tid * 128 + ((j * 16) ^ ((tid & 7) << 4)));
            *(uint4*)(Vimg + rowb + ((j * 16) ^ ((d & 7) << 4))) = v;
        }
    }
    #undef MMUL
    #undef ROPE
    #undef BOUNCE
}

// ---------------- K-split flash attention (R17/R18): DMA staging K+V, bf16 partials
__global__ __launch_bounds__(256, 2) void attn2_kernel(const unsigned short* __restrict__ qb,
                                                       const char* __restrict__ Kimg,
                                                       const char* __restrict__ Vimg,
                                                       unsigned short* __restrict__ ybf,
                                                       unsigned short* __restrict__ pab,
                                                       float* __restrict__ pl){
    __shared__ uint4 smem4[81920 / 16];
    char* smem = (char*)smem4;
    int tid = threadIdx.x;
    int w = tid >> 6, lane = tid & 63, l4 = lane >> 4, lm = lane & 15;
    int i = blockIdx.x;
    int xg = i & 7, j5 = i >> 3;
    int bh = 2 * xg + (j5 & 1);
    int slot = j5 >> 1;
    int grp = slot >> 3, g = slot & 7;
    int J, t0, niters, direct, slice;
    if (grp == 0){ J = 8 + g;  t0 = 0;  niters = 16;         direct = 0; slice = (bh * 8 + g) * 2; }
    else if (grp == 1){ J = 15 - g; t0 = 16; niters = 2 * J - 14; direct = 0; slice = (bh * 8 + (J - 8)) * 2 + 1; }
    else { J = 7 - g;  t0 = 0;  niters = 2 * J + 2;  direct = 1; slice = 0; }
    int b = bh >> 3, h = bh & 7;
    int qrow0w = 128 * J + 32 * w;
    int wqmax = qrow0w + 31;

    bf16x8 qf[2][4];
    #pragma unroll
    for (int f = 0; f < 2; ++f){
        const unsigned short* qg = qb + ((size_t)bh * Sn + qrow0w + 16 * f + lm) * HDn;
        #pragma unroll
        for (int df = 0; df < 4; ++df)
            qf[f][df] = *(const bf16x8*)(qg + df * 32 + l4 * 8);
    }
    f32x4 acc[2][8];
    #pragma unroll
    for (int f = 0; f < 2; ++f)
        #pragma unroll
        for (int dg = 0; dg < 8; ++dg) acc[f][dg] = (f32x4){0.f,0.f,0.f,0.f};
    float lp[2][4];
    #pragma unroll
    for (int f = 0; f < 2; ++f)
        #pragma unroll
        for (int r = 0; r < 4; ++r) lp[f][r] = 0.f;

    const float OFF = 11.541560327111708f;   // 8 * log2(e)
    size_t imgbase = (size_t)bh * 32 * 16384;

    #define STAGE_DMA(T, BUFB) { size_t tb = imgbase + (size_t)(T) * 16384; \
        _Pragma("unroll") for (int i2 = 0; i2 < 4; ++i2){ \
            gld16(Kimg + tb + i2 * 4096 + tid * 16, smem + (BUFB) + i2 * 4096 + tid * 16); \
            gld16(Vimg + tb + i2 * 4096 + tid * 16, smem + (BUFB) + 16384 + i2 * 4096 + tid * 16); } }

    STAGE_DMA(t0, 0);
    __syncthreads();

    for (int it = 0; it < niters; ++it){
        int t = t0 + it;
        int bsel = (it & 1) << 15;
        if (it + 1 < niters)
            STAGE_DMA(t + 1, bsel ^ 32768);
        if (64 * t <= wqmax){
            char* KL = smem + bsel;
            char* VL = smem + bsel + 16384;
            char* pb = smem + 65536 + (w << 12);
            __builtin_amdgcn_s_setprio(1);
            f32x4 sf[2][4];
            #pragma unroll
            for (int kc = 0; kc < 4; ++kc){ sf[0][kc] = (f32x4){0.f,0.f,0.f,0.f}; sf[1][kc] = (f32x4){0.f,0.f,0.f,0.f}; }
            #pragma unroll
            for (int kc = 0; kc < 4; ++kc){
                int krow = 16 * kc + lm;
                int ksw = (krow & 7) << 4;
                #pragma unroll
                for (int df = 0; df < 4; ++df){
                    bf16x8 kf = *(const bf16x8*)(KL + krow * 256 + ((df * 64 + l4 * 16) ^ ksw));
                    sf[0][kc] = __builtin_amdgcn_mfma_f32_16x16x32_bf16(qf[0][df], kf, sf[0][kc], 0, 0, 0);
                    sf[1][kc] = __builtin_amdgcn_mfma_f32_16x16x32_bf16(qf[1][df], kf, sf[1][kc], 0, 0, 0);
                }
            }
            bool needmask = (64 * t + 63 > qrow0w);
            #pragma unroll
            for (int f = 0; f < 2; ++f){
                #pragma unroll
                for (int r = 0; r < 4; ++r){
                    float s0v = sf[f][0][r], s1v = sf[f][1][r],
                          s2v = sf[f][2][r], s3v = sf[f][3][r];
                    if (needmask){
                        int qr = qrow0w + 16 * f + 4 * l4 + r;
                        int j0k = 64 * t + 4 * lm;
                        s0v = (j0k     > qr) ? -1e30f : s0v;
                        s1v = (j0k + 1 > qr) ? -1e30f : s1v;
                        s2v = (j0k + 2 > qr) ? -1e30f : s2v;
                        s3v = (j0k + 3 > qr) ? -1e30f : s3v;
                    }
                    float p0 = vexp2(s0v - OFF), p1 = vexp2(s1v - OFF),
                          p2 = vexp2(s2v - OFF), p3 = vexp2(s3v - OFF);
                    lp[f][r] += p0 + p1 + p2 + p3;
                    int prow = 16 * f + 4 * l4 + r;
                    uint2 pkd = {pk2(p0, p1), pk2(p2, p3)};
                    *(uint2*)(pb + prow * 128 + ((lm * 8) ^ ((prow & 7) << 4))) = pkd;
                }
            }
            #pragma unroll
            for (int ks = 0; ks < 2; ++ks){
                int pcol = (ks * 64 + l4 * 16) ^ ((lm & 7) << 4);
                bf16x8 pa0 = *(const bf16x8*)(pb + lm * 128 + pcol);
                bf16x8 pa1 = *(const bf16x8*)(pb + (16 + lm) * 128 + pcol);
                #pragma unroll
                for (int dg = 0; dg < 8; ++dg){
                    int vrow = 16 * dg + lm;
                    bf16x8 vf = *(const bf16x8*)(VL + vrow * 128 + ((ks * 64 + l4 * 16) ^ ((vrow & 7) << 4)));
                    acc[0][dg] = __builtin_amdgcn_mfma_f32_16x16x32_bf16(pa0, vf, acc[0][dg], 0, 0, 0);
                    acc[1][dg] = __builtin_amdgcn_mfma_f32_16x16x32_bf16(pa1, vf, acc[1][dg], 0, 0, 0);
                }
            }
            __builtin_amdgcn_s_setprio(0);
        }
        __syncthreads();
    }
    #undef STAGE_DMA
    float lsum[2][4];
    #pragma unroll
    for (int f = 0; f < 2; ++f)
        #pragma unroll
        for (int r = 0; r < 4; ++r){
            float l_ = lp[f][r];
            l_ += __shfl_xor(l_, 1);
            l_ += __shfl_xor(l_, 2);
            l_ += __shfl_xor(l_, 4);
            l_ += __shfl_xor(l_, 8);
            lsum[f][r] = l_;
        }
    if (direct){
        #pragma unroll
        for (int f = 0; f < 2; ++f)
            #pragma unroll
            for (int r = 0; r < 4; ++r){
                float inv = 1.f / lsum[f][r];
                int row = qrow0w + 16 * f + 4 * l4 + r;
                unsigned short* yr = ybf + ((size_t)b * Sn + row) * Dn + h * HDn;
                #pragma unroll
                for (int dg = 0; dg < 8; ++dg)
                    yr[16 * dg + lm] = f2bf(acc[f][dg][r] * inv);
            }
    } else {
        unsigned short* pa_ = pab + (size_t)slice * 16384;
        #pragma unroll
        for (int f = 0; f < 2; ++f)
            #pragma unroll
            for (int r = 0; r < 4; ++r){
                int row = 32 * w + 16 * f + 4 * l4 + r;
                #pragma unroll
                for (int dg = 0; dg < 8; ++dg)
                    pa_[row * 128 + 16 * dg + lm] = f2bf(acc[f][dg][r]);
                if (lm == 0)
                    pl[slice * 128 + row] = lsum[f][r];
            }
    }
}

extern "C" void kernel_launch(void* const* d_in, const int* in_sizes, int n_in,
                              void* d_out, int out_size, void* d_ws, size_t ws_size,
                              hipStream_t stream){
    const float* x      = (const float*)d_in[0];
    const float* A      = (const float*)d_in[1];
    const float* Bm     = (const float*)d_in[2];
    const float* C_q    = (const float*)d_in[3];
    const float* C_k    = (const float*)d_in[4];
    const float* C_v    = (const float*)d_in[5];
    const float* C_o    = (const float*)d_in[6];
    const float* C_fc   = (const float*)d_in[7];
    const float* C_proj = (const float*)d_in[8];
    const float* scale1 = (const float*)d_in[9];
    const float* scale2 = (const float*)d_in[10];
    float* out = (float*)d_out;

    char* ws = (char*)d_ws;
    size_t off = 0;
    auto alloc = [&](size_t bytes)->char*{ char* p = ws + off; off += (bytes + 255) & ~(size_t)255; return p; };
    unsigned short* qb   = (unsigned short*)alloc((size_t)Mn * Dn * 2);   // 8MB
    char*           Kimg = alloc((size_t)16 * 32 * 16384);                // 8MB
    char*           Vimg = alloc((size_t)16 * 32 * 16384);                // 8MB
    unsigned short* ybf  = (unsigned short*)alloc((size_t)Mn * Dn * 2);   // 8MB
    unsigned short* pab  = (unsigned short*)alloc((size_t)256 * 16384 * 2); // 8MB
    float*          pl   = (float*)alloc((size_t)256 * 128 * 4);          // 128KB
    unsigned short* tpA  = (unsigned short*)alloc(4 * TSTRIDE * 2);       // 2MB (bf16)
    unsigned short* tpB  = (unsigned short*)alloc(4 * TSTRIDE * 2);       // 2MB (bf16)
    float*          sspA = (float*)alloc(4 * (size_t)Mn * 4);             // 64KB
    float*          sspB = (float*)alloc(4 * (size_t)Mn * 4);             // 64KB
    char*           AtI1c = alloc(131072);
    char*           AtI0c = alloc(131072);
    char*           AtI2u = alloc(131072);
    char*           AtI0u = alloc(131072);
    char*           BIq   = alloc(131072);
    char*           BIk   = alloc(131072);
    char*           BIv   = alloc(131072);
    char*           BIo   = alloc(131072);
    char*           BIfc  = alloc(131072);
    char*           BIpr  = alloc(131072);
    float2*         rt    = (float2*)alloc((size_t)Sn * 64 * 8);          // 1MB

    prep_g<<<3072, 256, 0, stream>>>(A, Bm, C_q, C_k, C_v, C_o, C_fc, C_proj,
                                     scale1, scale2,
                                     AtI1c, AtI0c, AtI2u, AtI0u,
                                     BIq, BIk, BIv, BIo, BIfc, BIpr, rt);
    // t1 partials = x @ At1 (s1 folded), ss = rowwise sumsq(x)
    down_g<<<dim3(Mn / 64, 4), 256, 0, stream>>>(x, AtI1c, tpA, sspA);
    // q (scaled+roped), K-image, V-image (rms fused in staging)
    qkv_g<<<dim3(Mn / 64, 4), 256, 0, stream>>>(tpA, sspA, BIq, BIk, BIv, rt, qb, Kimg, Vimg);
    // attention (direct y for j<8; bf16 partials for j>=8)
    attn2_kernel<<<384, 256, 0, stream>>>(qb, Kimg, Vimg, ybf, pab, pl);
    // t2 partials = y @ At0 with slice-combine fused into staging
    downy_g<<<dim3(Mn / 64, 4), 256, 0, stream>>>(ybf, pab, pl, AtI0c, tpA);
    // FUSED: x1 = x + t2@Bto -> out; sumsq(x1) -> sspB; t3 = x1@At2 -> tpB
    updown_g<0, 1, 1, 1, 0><<<dim3(Mn / 32, 4), 256, 0, stream>>>(
        tpA, nullptr, BIo, AtI2u, x, out, tpB, sspB);
    // FUSED: m = silu(rms(t3)@Btfc) (never stored); t4 = m@At0 -> tpA
    updown_g<1, 0, 0, 0, 1><<<dim3(Mn / 32, 4), 256, 0, stream>>>(
        tpB, sspB, BIfc, AtI0u, nullptr, nullptr, tpA, nullptr);
    // out = x1 + t4 @ Btpr
    up_g<0, 1, 0, 0><<<dim3(Mn / 32, 4), 256, 0, stream>>>(tpA, nullptr, BIpr, out, out);
}

// Round 22
// 106.283 us; speedup vs baseline: 1.3832x; 1.0284x over previous
//
#include <hip/hip_runtime.h>

// HolographicBlock: B=2, S=2048, D=1024, R=64, H=8, HD=128
// Pre-swizzled weight images + global_load_lds everywhere; bf16 t-partials.
// Attention = R19 (DMA staging K+V 80KB dbuf, bf16 attention partials).
// NEW: qkv_g split across blockIdx.z (Q/K/V as parallel blocks, 768 total).

#define Bn 2
#define Sn 2048
#define Dn 1024
#define Rn 64
#define Hn 8
#define HDn 128
#define Mn (Bn*Sn)   // 4096 rows
#define TSTRIDE ((size_t)Mn * Rn)

typedef __bf16 bf16x8 __attribute__((ext_vector_type(8)));
typedef float f32x4 __attribute__((ext_vector_type(4)));
typedef __attribute__((address_space(1))) const unsigned int g_u32;
typedef __attribute__((address_space(3))) unsigned int l_u32;

__device__ __forceinline__ float bf2f(unsigned short u){
    union { unsigned int i; float f; } x; x.i = ((unsigned int)u) << 16; return x.f;
}
__device__ __forceinline__ unsigned short f2bf(float f){
    union { float f; unsigned int i; } x; x.f = f;
    unsigned int r = x.i + 0x7fffu + ((x.i >> 16) & 1u);
    return (unsigned short)(r >> 16);
}
__device__ __forceinline__ unsigned int pk2(float a, float b){
    unsigned int r;
    asm("v_cvt_pk_bf16_f32 %0, %1, %2" : "=v"(r) : "v"(a), "v"(b));
    return r;
}
__device__ __forceinline__ float vexp2(float x){
    float r;
    asm("v_exp_f32 %0, %1" : "=v"(r) : "v"(x));
    return r;
}
__device__ __forceinline__ void gld16(const void* g, void* l){
    __builtin_amdgcn_global_load_lds((g_u32*)g, (l_u32*)l, 16, 0, 0);
}
__device__ __forceinline__ void dma32k(const char* src, char* dst, int tid){
    #pragma unroll
    for (int p = 0; p < 8; ++p)
        gld16(src + p * 4096 + tid * 16, dst + p * 4096 + tid * 16);
}
__device__ __forceinline__ float bflo(unsigned int u){
    union { unsigned int i; float f; } x; x.i = u << 16; return x.f;
}
__device__ __forceinline__ float bfhi(unsigned int u){
    union { unsigned int i; float f; } x; x.i = u & 0xffff0000u; return x.f;
}
__device__ __forceinline__ uint4 comb8(uint4 A, uint4 C, float Wc){
    uint4 r;
    unsigned int* a = (unsigned int*)&A;
    unsigned int* c = (unsigned int*)&C;
    unsigned int* o = (unsigned int*)&r;
    #pragma unroll
    for (int e = 0; e < 4; ++e){
        float lo = (bflo(a[e]) + bflo(c[e])) * Wc;
        float hi = (bfhi(a[e]) + bfhi(c[e])) * Wc;
        o[e] = pk2(lo, hi);
    }
    return r;
}

// ---------------- prep: PRE-SWIZZLED weight images + rope table
__global__ __launch_bounds__(256) void prep_g(const float* __restrict__ A,
                                              const float* __restrict__ Bsrc,
                                              const float* __restrict__ Cq, const float* __restrict__ Ck,
                                              const float* __restrict__ Cv, const float* __restrict__ Co,
                                              const float* __restrict__ Cfc, const float* __restrict__ Cpr,
                                              const float* __restrict__ s1, const float* __restrict__ s2,
                                              char* __restrict__ AtI1c, char* __restrict__ AtI0c,
                                              char* __restrict__ AtI2u, char* __restrict__ AtI0u,
                                              char* __restrict__ BIq, char* __restrict__ BIk,
                                              char* __restrict__ BIv, char* __restrict__ BIo,
                                              char* __restrict__ BIfc, char* __restrict__ BIpr,
                                              float2* __restrict__ rt){
    int idx = blockIdx.x * 256 + threadIdx.x;
    if (idx < 4 * 65536){
        int v = idx >> 16, e = idx & 65535;
        int r = e & 63, d = e >> 6;
        float sc = (v == 0) ? s1[d] : (v == 2) ? s2[d] : 1.f;
        unsigned short val = f2bf(A[d * 64 + r] * sc);
        if (v < 2){
            int us = (d >> 6) * 4096 + r * 64 + (((((d >> 3) & 7) << 4) ^ ((r & 7) << 4)) >> 1) + (d & 7);
            ((unsigned short*)(v == 0 ? AtI1c : AtI0c))[us] = val;
        } else {
            int us = (d >> 8) * 16384 + r * 256 + (((((d >> 3) & 31) << 4) ^ ((r & 7) << 4)) >> 1) + (d & 7);
            ((unsigned short*)(v == 2 ? AtI2u : AtI0u))[us] = val;
        }
    } else if (idx < 10 * 65536){
        int v = (idx >> 16) - 4, e = idx & 65535;
        int d = e & 1023, r = e >> 10;
        const float* C = v==0?Cq : v==1?Ck : v==2?Cv : v==3?Co : v==4?Cfc : Cpr;
        float extra = (v == 0) ? (0.08838834764831845f * 1.4426950408889634f) : 1.f;
        unsigned short val = f2bf(Bsrc[r * 1024 + d] * C[r] * extra);
        int us = (d >> 8) * 16384 + (d & 255) * 64 + ((((r >> 3) << 4) ^ ((d & 7) << 4)) >> 1) + (r & 7);
        ((unsigned short*)(v==0?BIq : v==1?BIk : v==2?BIv : v==3?BIo : v==4?BIfc : BIpr))[us] = val;
    } else if (idx < 10 * 65536 + Sn * 64){
        int e = idx - 10 * 65536;
        int s = e >> 6, f = e & 63;
        float inv = exp2f(-(float)f * (13.287712379549449f / 64.0f));
        float fr = (float)s * inv;
        float sn, cs; sincosf(fr, &sn, &cs);
        rt[e] = make_float2(cs, sn);
    }
}

// ---------------- down GEMM (f32 input + sumsq): DMA At image, bf16 t-partials out
__global__ __launch_bounds__(256) void down_g(const float* __restrict__ inp,
                                              const char* __restrict__ AtImg,
                                              unsigned short* __restrict__ tpart,
                                              float* __restrict__ sspart){
    __shared__ char xt[32768];
    __shared__ char at[32768];
    int tid = threadIdx.x;
    int m0 = blockIdx.x * 64, sp = blockIdx.y;
    int row = tid >> 2, q4 = tid & 3;
    int w = tid >> 6, lane = tid & 63, l4 = lane >> 4, lm = lane & 15;
    int swz = (row & 7) << 4;
    dma32k(AtImg + (size_t)sp * 32768, at, tid);
    float ss = 0.f;
    f32x4 acc[4];
    #pragma unroll
    for (int nt = 0; nt < 4; ++nt) acc[nt] = (f32x4){0.f,0.f,0.f,0.f};

    float4 xr[4];
    #define LOADX(c) { int k0 = sp * 256 + (c) * 64; \
        const float4* s = (const float4*)(inp + (size_t)(m0+row)*1024 + k0 + q4*16); \
        xr[0]=s[0]; xr[1]=s[1]; xr[2]=s[2]; xr[3]=s[3]; }

    LOADX(0);
    for (int c = 0; c < 4; ++c){
        char* xc = xt + c * 8192;
        #pragma unroll
        for (int i = 0; i < 4; ++i)
            ss += xr[i].x*xr[i].x + xr[i].y*xr[i].y + xr[i].z*xr[i].z + xr[i].w*xr[i].w;
        uint4 p0 = {pk2(xr[0].x,xr[0].y), pk2(xr[0].z,xr[0].w), pk2(xr[1].x,xr[1].y), pk2(xr[1].z,xr[1].w)};
        uint4 p1 = {pk2(xr[2].x,xr[2].y), pk2(xr[2].z,xr[2].w), pk2(xr[3].x,xr[3].y), pk2(xr[3].z,xr[3].w)};
        *(uint4*)(xc + row * 128 + ((q4 * 32) ^ swz)) = p0;
        *(uint4*)(xc + row * 128 + ((q4 * 32 + 16) ^ swz)) = p1;
        __syncthreads();            // c==0 also drains the At DMA
        if (c < 3) LOADX(c + 1);
        #pragma unroll
        for (int ks = 0; ks < 2; ++ks){
            int arow = 16 * w + lm;
            bf16x8 af = *(const bf16x8*)(xc + arow * 128 + ((ks*64 + l4*16) ^ ((arow & 7) << 4)));
            #pragma unroll
            for (int nt = 0; nt < 4; ++nt){
                int brow = nt * 16 + lm;
                bf16x8 bf = *(const bf16x8*)(at + c * 8192 + brow * 128 + ((ks*64 + l4*16) ^ ((brow & 7) << 4)));
                acc[nt] = __builtin_amdgcn_mfma_f32_16x16x32_bf16(af, bf, acc[nt], 0, 0, 0);
            }
        }
    }
    #undef LOADX
    ss += __shfl_xor(ss, 1); ss += __shfl_xor(ss, 2);
    if (q4 == 0) sspart[sp * Mn + m0 + row] = ss;
    #pragma unroll
    for (int nt = 0; nt < 4; ++nt)
        #pragma unroll
        for (int r = 0; r < 4; ++r){
            int ml = 16 * w + 4 * l4 + r;
            tpart[(size_t)sp * TSTRIDE + (size_t)(m0 + ml) * 64 + nt * 16 + lm] = f2bf(acc[nt][r]);
        }
}

// ---------------- down GEMM for y (fused slice-combine), bf16 t-partials out
__global__ __launch_bounds__(256) void downy_g(const unsigned short* __restrict__ ybf,
                                               const unsigned short* __restrict__ pab,
                                               const float* __restrict__ pl,
                                               const char* __restrict__ AtImg,
                                               unsigned short* __restrict__ tpart){
    __shared__ char xt[32768];
    __shared__ char at[32768];
    int tid = threadIdx.x;
    int m0 = blockIdx.x * 64, sp = blockIdx.y;
    int row = tid >> 2, q4 = tid & 3;
    int w = tid >> 6, lane = tid & 63, l4 = lane >> 4, lm = lane & 15;
    int swz = (row & 7) << 4;
    int jq = (m0 & (Sn - 1)) >> 7;
    int bpos = m0 >> 11;
    int srow = (m0 & 127) + row;
    dma32k(AtImg + (size_t)sp * 32768, at, tid);
    f32x4 acc[4];
    #pragma unroll
    for (int nt = 0; nt < 4; ++nt) acc[nt] = (f32x4){0.f,0.f,0.f,0.f};

    #define MFMAC(c) { \
        _Pragma("unroll") \
        for (int ks = 0; ks < 2; ++ks){ \
            int arow = 16 * w + lm; \
            bf16x8 af = *(const bf16x8*)(xt + (c) * 8192 + arow * 128 + ((ks*64 + l4*16) ^ ((arow & 7) << 4))); \
            _Pragma("unroll") \
            for (int nt = 0; nt < 4; ++nt){ \
                int brow = nt * 16 + lm; \
                bf16x8 bf = *(const bf16x8*)(at + (c) * 8192 + brow * 128 + ((ks*64 + l4*16) ^ ((brow & 7) << 4))); \
                acc[nt] = __builtin_amdgcn_mfma_f32_16x16x32_bf16(af, bf, acc[nt], 0, 0, 0); \
            } \
        } }

    if (jq < 8){
        const char* yb = (const char*)ybf;
        #pragma unroll
        for (int p = 0; p < 8; ++p){
            int c = p >> 1;
            int rw = (p & 1) * 32 + (tid >> 3);
            int gp = (tid & 7) ^ (rw & 7);
            gld16(yb + (size_t)(m0 + rw) * 2048 + sp * 512 + c * 128 + gp * 16,
                  xt + p * 4096 + tid * 16);
        }
        __syncthreads();
        for (int c = 0; c < 4; ++c) MFMAC(c);
    } else {
        uint4 xrb[2];
        #define LOADCMB(c) { int k0 = sp * 256 + (c) * 64; \
            int h = k0 >> 7; int d0 = k0 & 127; \
            int s0sl = (((bpos * 8 + h) * 8) + (jq - 8)) * 2; \
            const unsigned short* p0 = pab + (size_t)s0sl * 16384 + srow * 128 + d0 + q4 * 16; \
            const unsigned short* p1 = p0 + 16384; \
            float Wc = 1.f / (pl[s0sl * 128 + srow] + pl[(s0sl + 1) * 128 + srow]); \
            uint4 A0 = ((const uint4*)p0)[0], A1 = ((const uint4*)p0)[1]; \
            uint4 C0 = ((const uint4*)p1)[0], C1 = ((const uint4*)p1)[1]; \
            xrb[0] = comb8(A0, C0, Wc); xrb[1] = comb8(A1, C1, Wc); }
        LOADCMB(0);
        for (int c = 0; c < 4; ++c){
            char* xc = xt + c * 8192;
            *(uint4*)(xc + row * 128 + ((q4 * 32) ^ swz)) = xrb[0];
            *(uint4*)(xc + row * 128 + ((q4 * 32 + 16) ^ swz)) = xrb[1];
            __syncthreads();
            if (c < 3) LOADCMB(c + 1);
            MFMAC(c);
        }
        #undef LOADCMB
    }
    #undef MFMAC
    #pragma unroll
    for (int nt = 0; nt < 4; ++nt)
        #pragma unroll
        for (int r = 0; r < 4; ++r){
            int ml = 16 * w + 4 * l4 + r;
            tpart[(size_t)sp * TSTRIDE + (size_t)(m0 + ml) * 64 + nt * 16 + lm] = f2bf(acc[nt][r]);
        }
}

// ---------------- stage t tile (sum 4 bf16 K-split partials, optional rms) into swizzled LDS
template<int DORMS>
__device__ __forceinline__ void stage_t(char* tt, const unsigned short* __restrict__ tpart,
                                        const float* __restrict__ sspart, int m0, int tid){
    int row = tid >> 2, q4 = tid & 3;
    const unsigned short* bp = tpart + (size_t)(m0 + row) * 64 + q4 * 16;
    float s[16];
    #pragma unroll
    for (int half = 0; half < 2; ++half){
        uint4 u0 = ((const uint4*)(bp + 0 * TSTRIDE))[half];
        uint4 u1 = ((const uint4*)(bp + 1 * TSTRIDE))[half];
        uint4 u2 = ((const uint4*)(bp + 2 * TSTRIDE))[half];
        uint4 u3 = ((const uint4*)(bp + 3 * TSTRIDE))[half];
        const unsigned int* a0 = (const unsigned int*)&u0;
        const unsigned int* a1 = (const unsigned int*)&u1;
        const unsigned int* a2 = (const unsigned int*)&u2;
        const unsigned int* a3 = (const unsigned int*)&u3;
        #pragma unroll
        for (int e = 0; e < 4; ++e){
            s[half*8 + 2*e]     = bflo(a0[e]) + bflo(a1[e]) + bflo(a2[e]) + bflo(a3[e]);
            s[half*8 + 2*e + 1] = bfhi(a0[e]) + bfhi(a1[e]) + bfhi(a2[e]) + bfhi(a3[e]);
        }
    }
    float rr = 1.f;
    if (DORMS){
        int m = m0 + row;
        float ssum = sspart[m] + sspart[Mn + m] + sspart[2*Mn + m] + sspart[3*Mn + m];
        rr = rsqrtf(ssum * (1.f / 1024.f) + 1.1920929e-07f);
    }
    #pragma unroll
    for (int i = 0; i < 16; ++i) s[i] *= rr;
    int swz = (row & 7) << 4;
    uint4 p0 = {pk2(s[0],s[1]), pk2(s[2],s[3]), pk2(s[4],s[5]), pk2(s[6],s[7])};
    uint4 p1 = {pk2(s[8],s[9]), pk2(s[10],s[11]), pk2(s[12],s[13]), pk2(s[14],s[15])};
    *(uint4*)(tt + row * 128 + ((q4 * 32) ^ swz)) = p0;
    *(uint4*)(tt + row * 128 + ((q4 * 32 + 16) ^ swz)) = p1;
}

// ---------------- up GEMM (final projection): DMA Bt image
template<int SILU, int HASBASE, int OUT_BF16, int DORMS>
__global__ __launch_bounds__(256) void up_g(const unsigned short* __restrict__ tpart,
                                            const float* __restrict__ sspart,
                                            const char* __restrict__ BtImg,
                                            const float* base,
                                            void* __restrict__ outp){
    __shared__ char tt[4096];
    __shared__ char bb[32768];
    int tid = threadIdx.x;
    int m0 = blockIdx.x * 32, n0 = blockIdx.y * 256;
    int w = tid >> 6, lane = tid & 63, l4 = lane >> 4, lm = lane & 15;
    int wm = w & 1, wn = w >> 1;
    dma32k(BtImg + (size_t)blockIdx.y * 32768, bb, tid);
    if (tid < 128) stage_t<DORMS>(tt, tpart, sspart, m0, tid);
    __syncthreads();
    bf16x8 af[2];
    #pragma unroll
    for (int ks = 0; ks < 2; ++ks){
        int arow = 16 * wm + lm;
        af[ks] = *(const bf16x8*)(tt + arow * 128 + ((ks*64 + l4*16) ^ ((arow & 7) << 4)));
    }
    f32x4 acc[8];
    #pragma unroll
    for (int nt = 0; nt < 8; ++nt) acc[nt] = (f32x4){0.f,0.f,0.f,0.f};
    #pragma unroll
    for (int nt = 0; nt < 8; ++nt){
        int brow = wn * 128 + nt * 16 + lm;
        #pragma unroll
        for (int ks = 0; ks < 2; ++ks){
            bf16x8 bf = *(const bf16x8*)(bb + brow * 128 + ((ks*64 + l4*16) ^ ((brow & 7) << 4)));
            acc[nt] = __builtin_amdgcn_mfma_f32_16x16x32_bf16(af[ks], bf, acc[nt], 0, 0, 0);
        }
    }
    #pragma unroll
    for (int nt = 0; nt < 8; ++nt)
        #pragma unroll
        for (int r = 0; r < 4; ++r){
            int m = m0 + 16 * wm + 4 * l4 + r;
            int n = n0 + wn * 128 + nt * 16 + lm;
            float v = acc[nt][r];
            if (SILU) v = v / (1.f + __expf(-v));
            if (HASBASE) v += base[(size_t)m * 1024 + n];
            if (OUT_BF16) ((unsigned short*)outp)[(size_t)m * 1024 + n] = f2bf(v);
            else          ((float*)outp)[(size_t)m * 1024 + n] = v;
        }
}

// ---------------- FUSED up->down: DMA BtU image, DMA AtD ud-image; bf16 tpout
template<int SILU, int HASBASE, int STOREOUT, int SUMSQ, int DORMS_IN>
__global__ __launch_bounds__(256) void updown_g(const unsigned short* __restrict__ tpin,
                                                const float* __restrict__ sspin,
                                                const char* __restrict__ BtUimg,
                                                const char* __restrict__ AtDimg,
                                                const float* base,
                                                float* outp,
                                                unsigned short* __restrict__ tpout,
                                                float* __restrict__ sspout){
    __shared__ char tt[4096];
    __shared__ char bb[32768];     // BtU image, later AtD image
    __shared__ char xb[16384];     // bounced up-output tile [32][256] bf16
    __shared__ float ssl[2][32];
    int tid = threadIdx.x;
    int m0 = blockIdx.x * 32, n0 = blockIdx.y * 256, sp = blockIdx.y;
    int w = tid >> 6, lane = tid & 63, l4 = lane >> 4, lm = lane & 15;
    int wm = w & 1, wn = w >> 1;
    dma32k(BtUimg + (size_t)sp * 32768, bb, tid);
    if (tid < 128) stage_t<DORMS_IN>(tt, tpin, sspin, m0, tid);
    __syncthreads();
    // ---- up MFMA
    bf16x8 af[2];
    #pragma unroll
    for (int ks = 0; ks < 2; ++ks){
        int arow = 16 * wm + lm;
        af[ks] = *(const bf16x8*)(tt + arow * 128 + ((ks*64 + l4*16) ^ ((arow & 7) << 4)));
    }
    f32x4 acc[8];
    #pragma unroll
    for (int nt = 0; nt < 8; ++nt) acc[nt] = (f32x4){0.f,0.f,0.f,0.f};
    #pragma unroll
    for (int nt = 0; nt < 8; ++nt){
        int brow = wn * 128 + nt * 16 + lm;
        #pragma unroll
        for (int ks = 0; ks < 2; ++ks){
            bf16x8 bf = *(const bf16x8*)(bb + brow * 128 + ((ks*64 + l4*16) ^ ((brow & 7) << 4)));
            acc[nt] = __builtin_amdgcn_mfma_f32_16x16x32_bf16(af[ks], bf, acc[nt], 0, 0, 0);
        }
    }
    // ---- epilogue
    float val[8][4];
    float sq[4] = {0.f, 0.f, 0.f, 0.f};
    #pragma unroll
    for (int nt = 0; nt < 8; ++nt)
        #pragma unroll
        for (int r = 0; r < 4; ++r){
            int m = m0 + 16 * wm + 4 * l4 + r;
            int n = n0 + wn * 128 + nt * 16 + lm;
            float v = acc[nt][r];
            if (SILU) v = v / (1.f + __expf(-v));
            if (HASBASE) v += base[(size_t)m * 1024 + n];
            val[nt][r] = v;
            if (STOREOUT) outp[(size_t)m * 1024 + n] = v;
            if (SUMSQ) sq[r] += v * v;
        }
    if (SUMSQ){
        #pragma unroll
        for (int r = 0; r < 4; ++r){
            float s_ = sq[r];
            s_ += __shfl_xor(s_, 1);
            s_ += __shfl_xor(s_, 2);
            s_ += __shfl_xor(s_, 4);
            s_ += __shfl_xor(s_, 8);
            if (lm == 0) ssl[wn][16 * wm + 4 * l4 + r] = s_;
        }
    }
    __syncthreads();   // bb reads done, ssl visible
    // ---- DMA AtD ud-image into bb; bounce val -> xb
    dma32k(AtDimg + (size_t)sp * 32768, bb, tid);
    #pragma unroll
    for (int nt = 0; nt < 8; ++nt)
        #pragma unroll
        for (int r = 0; r < 4; ++r){
            int mrow = 16 * wm + 4 * l4 + r;
            int cn = wn * 128 + nt * 16 + lm;
            *(unsigned short*)(xb + mrow * 512 + ((cn * 2) ^ ((mrow & 7) << 4))) = f2bf(val[nt][r]);
        }
    __syncthreads();
    if (SUMSQ && tid < 32)
        sspout[sp * Mn + m0 + tid] = ssl[0][tid] + ssl[1][tid];
    // ---- down MFMA
    f32x4 acc2[2];
    acc2[0] = (f32x4){0.f,0.f,0.f,0.f};
    acc2[1] = (f32x4){0.f,0.f,0.f,0.f};
    #pragma unroll
    for (int kk = 0; kk < 8; ++kk){
        int arow = 16 * (w & 1) + lm;
        bf16x8 a2 = *(const bf16x8*)(xb + arow * 512 + ((kk * 64 + l4 * 16) ^ ((arow & 7) << 4)));
        #pragma unroll
        for (int j = 0; j < 2; ++j){
            int brow = (2 * (w >> 1) + j) * 16 + lm;
            bf16x8 b2 = *(const bf16x8*)(bb + brow * 512 + ((kk * 64 + l4 * 16) ^ ((brow & 7) << 4)));
            acc2[j] = __builtin_amdgcn_mfma_f32_16x16x32_bf16(a2, b2, acc2[j], 0, 0, 0);
        }
    }
    #pragma unroll
    for (int j = 0; j < 2; ++j)
        #pragma unroll
        for (int r = 0; r < 4; ++r){
            int ml = 16 * (w & 1) + 4 * l4 + r;
            int nc = (2 * (w >> 1) + j) * 16 + lm;
            tpout[(size_t)sp * TSTRIDE + (size_t)(m0 + ml) * 64 + nc] = f2bf(acc2[j][r]);
        }
}

// ---------------- fused QKV up-proj + RoPE, SPLIT across blockIdx.z:
// z=0: Q (rope, row-major out); z=1: K (rope, permuted swizzled tile image);
// z=2: V (transposed swizzled tile image).
__global__ __launch_bounds__(256) void qkv_g(const unsigned short* __restrict__ tpart,
                                             const float* __restrict__ sspart,
                                             const char* __restrict__ BIq,
                                             const char* __restrict__ BIk,
                                             const char* __restrict__ BIv,
                                             const float2* __restrict__ rt,
                                             unsigned short* __restrict__ qout,
                                             char* __restrict__ Kimg,
                                             char* __restrict__ Vimg){
    __shared__ char tt[8192];
    __shared__ char bb[32768];
    int tid = threadIdx.x;
    int m0 = blockIdx.x * 64, n0 = blockIdx.y * 256;
    int which = blockIdx.z;
    int b = m0 >> 11, s0 = m0 & (Sn - 1);
    int h0 = n0 >> 7;
    int w = tid >> 6, lane = tid & 63, l4 = lane >> 4, lm = lane & 15;
    const char* BI = (which == 0) ? BIq : (which == 1) ? BIk : BIv;
    dma32k(BI + (size_t)blockIdx.y * 32768, bb, tid);
    stage_t<1>(tt, tpart, sspart, m0, tid);
    __syncthreads();
    bf16x8 af[2];
    #pragma unroll
    for (int ks = 0; ks < 2; ++ks){
        int arow = 16 * w + lm;
        af[ks] = *(const bf16x8*)(tt + arow * 128 + ((ks*64 + l4*16) ^ ((arow & 7) << 4)));
    }
    f32x4 acc[16];
    #pragma unroll
    for (int nt = 0; nt < 16; ++nt) acc[nt] = (f32x4){0.f,0.f,0.f,0.f};
    #pragma unroll
    for (int nt = 0; nt < 16; ++nt){
        int brow = nt * 16 + lm;
        #pragma unroll
        for (int ks = 0; ks < 2; ++ks){
            bf16x8 bf = *(const bf16x8*)(bb + brow * 128 + ((ks*64 + l4*16) ^ ((brow & 7) << 4)));
            acc[nt] = __builtin_amdgcn_mfma_f32_16x16x32_bf16(af[ks], bf, acc[nt], 0, 0, 0);
        }
    }
    if (which < 2){
        // rope
        float2 cs[4][4];
        #pragma unroll
        for (int ntb = 0; ntb < 4; ++ntb)
            #pragma unroll
            for (int r = 0; r < 4; ++r)
                cs[ntb][r] = rt[(size_t)(s0 + 16*w + 4*l4 + r) * 64 + ntb * 16 + lm];
        #pragma unroll
        for (int g = 0; g < 2; ++g)
            #pragma unroll
            for (int ntb = 0; ntb < 4; ++ntb){
                int lo = g*8 + ntb, hi = lo + 4;
                #pragma unroll
                for (int r = 0; r < 4; ++r){
                    float2 c = cs[ntb][r];
                    float a = acc[lo][r], bq = acc[hi][r];
                    acc[lo][r] = a * c.x + bq * c.y;
                    acc[hi][r] = -a * c.y + bq * c.x;
                }
            }
        __syncthreads();
        // bounce [m][n] bf16, 512B rows
        #pragma unroll
        for (int nt = 0; nt < 16; ++nt)
            #pragma unroll
            for (int r = 0; r < 4; ++r){
                int nl = nt * 16 + lm, ml2 = 16 * w + 4 * l4 + r;
                *(unsigned short*)(bb + ml2 * 512 + ((nl * 2) ^ ((ml2 & 7) << 4))) = f2bf(acc[nt][r]);
            }
        __syncthreads();
        if (which == 0){
            int ml = tid >> 2, seg = tid & 3;
            int head = h0 + (seg >> 1), hd0q = (seg & 1) * 64;
            size_t dstbase = (((size_t)(b * 8 + head) * Sn + (s0 + ml)) * 128 + hd0q);
            #pragma unroll
            for (int j = 0; j < 8; ++j){
                uint4 v = *(const uint4*)(bb + ml * 512 + ((seg * 128 + j * 16) ^ ((ml & 7) << 4)));
                *(uint4*)(qout + dstbase + j * 8) = v;
            }
        } else {
            int ml = tid >> 2, seg = tid & 3;
            int hd0q = (seg & 1) * 64;
            int head = h0 + (seg >> 1);
            int pr = 16 * (ml & 3) + (ml >> 2);
            size_t rowb = (((size_t)(b * 8 + head) * 32 + (s0 >> 6)) * 64 + pr) * 256;
            #pragma unroll
            for (int j = 0; j < 8; ++j){
                uint4 v = *(const uint4*)(bb + ml * 512 + ((seg * 128 + j * 16) ^ ((ml & 7) << 4)));
                int cb = hd0q * 2 + j * 16;
                *(uint4*)(Kimg + rowb + (cb ^ ((pr & 7) << 4))) = v;
            }
        }
    } else {
        // V: transposed bounce [n][m] bf16, 128B rows
        __syncthreads();
        #pragma unroll
        for (int nt = 0; nt < 16; ++nt)
            #pragma unroll
            for (int r = 0; r < 4; ++r){
                int nl = nt * 16 + lm, ml2 = 16 * w + 4 * l4 + r;
                *(unsigned short*)(bb + nl * 128 + ((ml2 * 2) ^ ((nl & 7) << 4))) = f2bf(acc[nt][r]);
            }
        __syncthreads();
        int head = h0 + (tid >> 7), d = tid & 127;
        size_t rowb = (((size_t)(b * 8 + head) * 32 + (s0 >> 6)) * 128 + d) * 128;
        #pragma unroll
        for (int j = 0; j < 8; ++j){
            uint4 v = *(const uint4*)(bb + tid * 128 + ((j * 16) ^ ((tid & 7) << 4)));
            *(uint4*)(Vimg + rowb + ((j * 16) ^ ((d & 7) << 4))) = v;
        }
    }
}

// ---------------- K-split flash attention (R19, unchanged): DMA staging K+V, bf16 partials
__global__ __launch_bounds__(256, 2) void attn2_kernel(const unsigned short* __restrict__ qb,
                                                       const char* __restrict__ Kimg,
                                                       const char* __restrict__ Vimg,
                                                       unsigned short* __restrict__ ybf,
                                                       unsigned short* __restrict__ pab,
                                                       float* __restrict__ pl){
    __shared__ uint4 smem4[81920 / 16];
    char* smem = (char*)smem4;
    int tid = threadIdx.x;
    int w = tid >> 6, lane = tid & 63, l4 = lane >> 4, lm = lane & 15;
    int i = blockIdx.x;
    int xg = i & 7, j5 = i >> 3;
    int bh = 2 * xg + (j5 & 1);
    int slot = j5 >> 1;
    int grp = slot >> 3, g = slot & 7;
    int J, t0, niters, direct, slice;
    if (grp == 0){ J = 8 + g;  t0 = 0;  niters = 16;         direct = 0; slice = (bh * 8 + g) * 2; }
    else if (grp == 1){ J = 15 - g; t0 = 16; niters = 2 * J - 14; direct = 0; slice = (bh * 8 + (J - 8)) * 2 + 1; }
    else { J = 7 - g;  t0 = 0;  niters = 2 * J + 2;  direct = 1; slice = 0; }
    int b = bh >> 3, h = bh & 7;
    int qrow0w = 128 * J + 32 * w;
    int wqmax = qrow0w + 31;

    bf16x8 qf[2][4];
    #pragma unroll
    for (int f = 0; f < 2; ++f){
        const unsigned short* qg = qb + ((size_t)bh * Sn + qrow0w + 16 * f + lm) * HDn;
        #pragma unroll
        for (int df = 0; df < 4; ++df)
            qf[f][df] = *(const bf16x8*)(qg + df * 32 + l4 * 8);
    }
    f32x4 acc[2][8];
    #pragma unroll
    for (int f = 0; f < 2; ++f)
        #pragma unroll
        for (int dg = 0; dg < 8; ++dg) acc[f][dg] = (f32x4){0.f,0.f,0.f,0.f};
    float lp[2][4];
    #pragma unroll
    for (int f = 0; f < 2; ++f)
        #pragma unroll
        for (int r = 0; r < 4; ++r) lp[f][r] = 0.f;

    const float OFF = 11.541560327111708f;   // 8 * log2(e)
    size_t imgbase = (size_t)bh * 32 * 16384;

    #define STAGE_DMA(T, BUFB) { size_t tb = imgbase + (size_t)(T) * 16384; \
        _Pragma("unroll") for (int i2 = 0; i2 < 4; ++i2){ \
            gld16(Kimg + tb + i2 * 4096 + tid * 16, smem + (BUFB) + i2 * 4096 + tid * 16); \
            gld16(Vimg + tb + i2 * 4096 + tid * 16, smem + (BUFB) + 16384 + i2 * 4096 + tid * 16); } }

    STAGE_DMA(t0, 0);
    __syncthreads();

    for (int it = 0; it < niters; ++it){
        int t = t0 + it;
        int bsel = (it & 1) << 15;
        if (it + 1 < niters)
            STAGE_DMA(t + 1, bsel ^ 32768);
        if (64 * t <= wqmax){
            char* KL = smem + bsel;
            char* VL = smem + bsel + 16384;
            char* pb = smem + 65536 + (w << 12);
            __builtin_amdgcn_s_setprio(1);
            f32x4 sf[2][4];
            #pragma unroll
            for (int kc = 0; kc < 4; ++kc){ sf[0][kc] = (f32x4){0.f,0.f,0.f,0.f}; sf[1][kc] = (f32x4){0.f,0.f,0.f,0.f}; }
            #pragma unroll
            for (int kc = 0; kc < 4; ++kc){
                int krow = 16 * kc + lm;
                int ksw = (krow & 7) << 4;
                #pragma unroll
                for (int df = 0; df < 4; ++df){
                    bf16x8 kf = *(const bf16x8*)(KL + krow * 256 + ((df * 64 + l4 * 16) ^ ksw));
                    sf[0][kc] = __builtin_amdgcn_mfma_f32_16x16x32_bf16(qf[0][df], kf, sf[0][kc], 0, 0, 0);
                    sf[1][kc] = __builtin_amdgcn_mfma_f32_16x16x32_bf16(qf[1][df], kf, sf[1][kc], 0, 0, 0);
                }
            }
            bool needmask = (64 * t + 63 > qrow0w);
            #pragma unroll
            for (int f = 0; f < 2; ++f){
                #pragma unroll
                for (int r = 0; r < 4; ++r){
                    float s0v = sf[f][0][r], s1v = sf[f][1][r],
                          s2v = sf[f][2][r], s3v = sf[f][3][r];
                    if (needmask){
                        int qr = qrow0w + 16 * f + 4 * l4 + r;
                        int j0k = 64 * t + 4 * lm;
                        s0v = (j0k     > qr) ? -1e30f : s0v;
                        s1v = (j0k + 1 > qr) ? -1e30f : s1v;
                        s2v = (j0k + 2 > qr) ? -1e30f : s2v;
                        s3v = (j0k + 3 > qr) ? -1e30f : s3v;
                    }
                    float p0 = vexp2(s0v - OFF), p1 = vexp2(s1v - OFF),
                          p2 = vexp2(s2v - OFF), p3 = vexp2(s3v - OFF);
                    lp[f][r] += p0 + p1 + p2 + p3;
                    int prow = 16 * f + 4 * l4 + r;
                    uint2 pkd = {pk2(p0, p1), pk2(p2, p3)};
                    *(uint2*)(pb + prow * 128 + ((lm * 8) ^ ((prow & 7) << 4))) = pkd;
                }
            }
            #pragma unroll
            for (int ks = 0; ks < 2; ++ks){
                int pcol = (ks * 64 + l4 * 16) ^ ((lm & 7) << 4);
                bf16x8 pa0 = *(const bf16x8*)(pb + lm * 128 + pcol);
                bf16x8 pa1 = *(const bf16x8*)(pb + (16 + lm) * 128 + pcol);
                #pragma unroll
                for (int dg = 0; dg < 8; ++dg){
                    int vrow = 16 * dg + lm;
                    bf16x8 vf = *(const bf16x8*)(VL + vrow * 128 + ((ks * 64 + l4 * 16) ^ ((vrow & 7) << 4)));
                    acc[0][dg] = __builtin_amdgcn_mfma_f32_16x16x32_bf16(pa0, vf, acc[0][dg], 0, 0, 0);
                    acc[1][dg] = __builtin_amdgcn_mfma_f32_16x16x32_bf16(pa1, vf, acc[1][dg], 0, 0, 0);
                }
            }
            __builtin_amdgcn_s_setprio(0);
        }
        __syncthreads();
    }
    #undef STAGE_DMA
    float lsum[2][4];
    #pragma unroll
    for (int f = 0; f < 2; ++f)
        #pragma unroll
        for (int r = 0; r < 4; ++r){
            float l_ = lp[f][r];
            l_ += __shfl_xor(l_, 1);
            l_ += __shfl_xor(l_, 2);
            l_ += __shfl_xor(l_, 4);
            l_ += __shfl_xor(l_, 8);
            lsum[f][r] = l_;
        }
    if (direct){
        #pragma unroll
        for (int f = 0; f < 2; ++f)
            #pragma unroll
            for (int r = 0; r < 4; ++r){
                float inv = 1.f / lsum[f][r];
                int row = qrow0w + 16 * f + 4 * l4 + r;
                unsigned short* yr = ybf + ((size_t)b * Sn + row) * Dn + h * HDn;
                #pragma unroll
                for (int dg = 0; dg < 8; ++dg)
                    yr[16 * dg + lm] = f2bf(acc[f][dg][r] * inv);
            }
    } else {
        unsigned short* pa_ = pab + (size_t)slice * 16384;
        #pragma unroll
        for (int f = 0; f < 2; ++f)
            #pragma unroll
            for (int r = 0; r < 4; ++r){
                int row = 32 * w + 16 * f + 4 * l4 + r;
                #pragma unroll
                for (int dg = 0; dg < 8; ++dg)
                    pa_[row * 128 + 16 * dg + lm] = f2bf(acc[f][dg][r]);
                if (lm == 0)
                    pl[slice * 128 + row] = lsum[f][r];
            }
    }
}

extern "C" void kernel_launch(void* const* d_in, const int* in_sizes, int n_in,
                              void* d_out, int out_size, void* d_ws, size_t ws_size,
                              hipStream_t stream){
    const float* x      = (const float*)d_in[0];
    const float* A      = (const float*)d_in[1];
    const float* Bm     = (const float*)d_in[2];
    const float* C_q    = (const float*)d_in[3];
    const float* C_k    = (const float*)d_in[4];
    const float* C_v    = (const float*)d_in[5];
    const float* C_o    = (const float*)d_in[6];
    const float* C_fc   = (const float*)d_in[7];
    const float* C_proj = (const float*)d_in[8];
    const float* scale1 = (const float*)d_in[9];
    const float* scale2 = (const float*)d_in[10];
    float* out = (float*)d_out;

    char* ws = (char*)d_ws;
    size_t off = 0;
    auto alloc = [&](size_t bytes)->char*{ char* p = ws + off; off += (bytes + 255) & ~(size_t)255; return p; };
    unsigned short* qb   = (unsigned short*)alloc((size_t)Mn * Dn * 2);   // 8MB
    char*           Kimg = alloc((size_t)16 * 32 * 16384);                // 8MB
    char*           Vimg = alloc((size_t)16 * 32 * 16384);                // 8MB
    unsigned short* ybf  = (unsigned short*)alloc((size_t)Mn * Dn * 2);   // 8MB
    unsigned short* pab  = (unsigned short*)alloc((size_t)256 * 16384 * 2); // 8MB
    float*          pl   = (float*)alloc((size_t)256 * 128 * 4);          // 128KB
    unsigned short* tpA  = (unsigned short*)alloc(4 * TSTRIDE * 2);       // 2MB (bf16)
    unsigned short* tpB  = (unsigned short*)alloc(4 * TSTRIDE * 2);       // 2MB (bf16)
    float*          sspA = (float*)alloc(4 * (size_t)Mn * 4);             // 64KB
    float*          sspB = (float*)alloc(4 * (size_t)Mn * 4);             // 64KB
    char*           AtI1c = alloc(131072);
    char*           AtI0c = alloc(131072);
    char*           AtI2u = alloc(131072);
    char*           AtI0u = alloc(131072);
    char*           BIq   = alloc(131072);
    char*           BIk   = alloc(131072);
    char*           BIv   = alloc(131072);
    char*           BIo   = alloc(131072);
    char*           BIfc  = alloc(131072);
    char*           BIpr  = alloc(131072);
    float2*         rt    = (float2*)alloc((size_t)Sn * 64 * 8);          // 1MB

    prep_g<<<3072, 256, 0, stream>>>(A, Bm, C_q, C_k, C_v, C_o, C_fc, C_proj,
                                     scale1, scale2,
                                     AtI1c, AtI0c, AtI2u, AtI0u,
                                     BIq, BIk, BIv, BIo, BIfc, BIpr, rt);
    // t1 partials = x @ At1 (s1 folded), ss = rowwise sumsq(x)
    down_g<<<dim3(Mn / 64, 4), 256, 0, stream>>>(x, AtI1c, tpA, sspA);
    // q (scaled+roped), K-image, V-image — SPLIT across z (768 blocks)
    qkv_g<<<dim3(Mn / 64, 4, 3), 256, 0, stream>>>(tpA, sspA, BIq, BIk, BIv, rt, qb, Kimg, Vimg);
    // attention (direct y for j<8; bf16 partials for j>=8)
    attn2_kernel<<<384, 256, 0, stream>>>(qb, Kimg, Vimg, ybf, pab, pl);
    // t2 partials = y @ At0 with slice-combine fused into staging
    downy_g<<<dim3(Mn / 64, 4), 256, 0, stream>>>(ybf, pab, pl, AtI0c, tpA);
    // FUSED: x1 = x + t2@Bto -> out; sumsq(x1) -> sspB; t3 = x1@At2 -> tpB
    updown_g<0, 1, 1, 1, 0><<<dim3(Mn / 32, 4), 256, 0, stream>>>(
        tpA, nullptr, BIo, AtI2u, x, out, tpB, sspB);
    // FUSED: m = silu(rms(t3)@Btfc) (never stored); t4 = m@At0 -> tpA
    updown_g<1, 0, 0, 0, 1><<<dim3(Mn / 32, 4), 256, 0, stream>>>(
        tpB, sspB, BIfc, AtI0u, nullptr, nullptr, tpA, nullptr);
    // out = x1 + t4 @ Btpr
    up_g<0, 1, 0, 0><<<dim3(Mn / 32, 4), 256, 0, stream>>>(tpA, nullptr, BIpr, out, out);
}

// Round 23
// 101.283 us; speedup vs baseline: 1.4515x; 1.0494x over previous
//
#include <hip/hip_runtime.h>

// HolographicBlock: B=2, S=2048, D=1024, R=64, H=8, HD=128
// Pre-swizzled weight images + global_load_lds everywhere; bf16 t-partials;
// qkv z-split; NEW: bf16 residual carrier x1b (updown1 store + final up base).
// Attention = R19 (DMA staging K+V 80KB dbuf, bf16 attention partials).

#define Bn 2
#define Sn 2048
#define Dn 1024
#define Rn 64
#define Hn 8
#define HDn 128
#define Mn (Bn*Sn)   // 4096 rows
#define TSTRIDE ((size_t)Mn * Rn)

typedef __bf16 bf16x8 __attribute__((ext_vector_type(8)));
typedef float f32x4 __attribute__((ext_vector_type(4)));
typedef __attribute__((address_space(1))) const unsigned int g_u32;
typedef __attribute__((address_space(3))) unsigned int l_u32;

__device__ __forceinline__ float bf2f(unsigned short u){
    union { unsigned int i; float f; } x; x.i = ((unsigned int)u) << 16; return x.f;
}
__device__ __forceinline__ unsigned short f2bf(float f){
    union { float f; unsigned int i; } x; x.f = f;
    unsigned int r = x.i + 0x7fffu + ((x.i >> 16) & 1u);
    return (unsigned short)(r >> 16);
}
__device__ __forceinline__ unsigned int pk2(float a, float b){
    unsigned int r;
    asm("v_cvt_pk_bf16_f32 %0, %1, %2" : "=v"(r) : "v"(a), "v"(b));
    return r;
}
__device__ __forceinline__ float vexp2(float x){
    float r;
    asm("v_exp_f32 %0, %1" : "=v"(r) : "v"(x));
    return r;
}
__device__ __forceinline__ void gld16(const void* g, void* l){
    __builtin_amdgcn_global_load_lds((g_u32*)g, (l_u32*)l, 16, 0, 0);
}
__device__ __forceinline__ void dma32k(const char* src, char* dst, int tid){
    #pragma unroll
    for (int p = 0; p < 8; ++p)
        gld16(src + p * 4096 + tid * 16, dst + p * 4096 + tid * 16);
}
__device__ __forceinline__ float bflo(unsigned int u){
    union { unsigned int i; float f; } x; x.i = u << 16; return x.f;
}
__device__ __forceinline__ float bfhi(unsigned int u){
    union { unsigned int i; float f; } x; x.i = u & 0xffff0000u; return x.f;
}
__device__ __forceinline__ uint4 comb8(uint4 A, uint4 C, float Wc){
    uint4 r;
    unsigned int* a = (unsigned int*)&A;
    unsigned int* c = (unsigned int*)&C;
    unsigned int* o = (unsigned int*)&r;
    #pragma unroll
    for (int e = 0; e < 4; ++e){
        float lo = (bflo(a[e]) + bflo(c[e])) * Wc;
        float hi = (bfhi(a[e]) + bfhi(c[e])) * Wc;
        o[e] = pk2(lo, hi);
    }
    return r;
}

// ---------------- prep: PRE-SWIZZLED weight images + rope table
__global__ __launch_bounds__(256) void prep_g(const float* __restrict__ A,
                                              const float* __restrict__ Bsrc,
                                              const float* __restrict__ Cq, const float* __restrict__ Ck,
                                              const float* __restrict__ Cv, const float* __restrict__ Co,
                                              const float* __restrict__ Cfc, const float* __restrict__ Cpr,
                                              const float* __restrict__ s1, const float* __restrict__ s2,
                                              char* __restrict__ AtI1c, char* __restrict__ AtI0c,
                                              char* __restrict__ AtI2u, char* __restrict__ AtI0u,
                                              char* __restrict__ BIq, char* __restrict__ BIk,
                                              char* __restrict__ BIv, char* __restrict__ BIo,
                                              char* __restrict__ BIfc, char* __restrict__ BIpr,
                                              float2* __restrict__ rt){
    int idx = blockIdx.x * 256 + threadIdx.x;
    if (idx < 4 * 65536){
        int v = idx >> 16, e = idx & 65535;
        int r = e & 63, d = e >> 6;
        float sc = (v == 0) ? s1[d] : (v == 2) ? s2[d] : 1.f;
        unsigned short val = f2bf(A[d * 64 + r] * sc);
        if (v < 2){
            int us = (d >> 6) * 4096 + r * 64 + (((((d >> 3) & 7) << 4) ^ ((r & 7) << 4)) >> 1) + (d & 7);
            ((unsigned short*)(v == 0 ? AtI1c : AtI0c))[us] = val;
        } else {
            int us = (d >> 8) * 16384 + r * 256 + (((((d >> 3) & 31) << 4) ^ ((r & 7) << 4)) >> 1) + (d & 7);
            ((unsigned short*)(v == 2 ? AtI2u : AtI0u))[us] = val;
        }
    } else if (idx < 10 * 65536){
        int v = (idx >> 16) - 4, e = idx & 65535;
        int d = e & 1023, r = e >> 10;
        const float* C = v==0?Cq : v==1?Ck : v==2?Cv : v==3?Co : v==4?Cfc : Cpr;
        float extra = (v == 0) ? (0.08838834764831845f * 1.4426950408889634f) : 1.f;
        unsigned short val = f2bf(Bsrc[r * 1024 + d] * C[r] * extra);
        int us = (d >> 8) * 16384 + (d & 255) * 64 + ((((r >> 3) << 4) ^ ((d & 7) << 4)) >> 1) + (r & 7);
        ((unsigned short*)(v==0?BIq : v==1?BIk : v==2?BIv : v==3?BIo : v==4?BIfc : BIpr))[us] = val;
    } else if (idx < 10 * 65536 + Sn * 64){
        int e = idx - 10 * 65536;
        int s = e >> 6, f = e & 63;
        float inv = exp2f(-(float)f * (13.287712379549449f / 64.0f));
        float fr = (float)s * inv;
        float sn, cs; sincosf(fr, &sn, &cs);
        rt[e] = make_float2(cs, sn);
    }
}

// ---------------- down GEMM (f32 input + sumsq): DMA At image, bf16 t-partials out
__global__ __launch_bounds__(256) void down_g(const float* __restrict__ inp,
                                              const char* __restrict__ AtImg,
                                              unsigned short* __restrict__ tpart,
                                              float* __restrict__ sspart){
    __shared__ char xt[32768];
    __shared__ char at[32768];
    int tid = threadIdx.x;
    int m0 = blockIdx.x * 64, sp = blockIdx.y;
    int row = tid >> 2, q4 = tid & 3;
    int w = tid >> 6, lane = tid & 63, l4 = lane >> 4, lm = lane & 15;
    int swz = (row & 7) << 4;
    dma32k(AtImg + (size_t)sp * 32768, at, tid);
    float ss = 0.f;
    f32x4 acc[4];
    #pragma unroll
    for (int nt = 0; nt < 4; ++nt) acc[nt] = (f32x4){0.f,0.f,0.f,0.f};

    float4 xr[4];
    #define LOADX(c) { int k0 = sp * 256 + (c) * 64; \
        const float4* s = (const float4*)(inp + (size_t)(m0+row)*1024 + k0 + q4*16); \
        xr[0]=s[0]; xr[1]=s[1]; xr[2]=s[2]; xr[3]=s[3]; }

    LOADX(0);
    for (int c = 0; c < 4; ++c){
        char* xc = xt + c * 8192;
        #pragma unroll
        for (int i = 0; i < 4; ++i)
            ss += xr[i].x*xr[i].x + xr[i].y*xr[i].y + xr[i].z*xr[i].z + xr[i].w*xr[i].w;
        uint4 p0 = {pk2(xr[0].x,xr[0].y), pk2(xr[0].z,xr[0].w), pk2(xr[1].x,xr[1].y), pk2(xr[1].z,xr[1].w)};
        uint4 p1 = {pk2(xr[2].x,xr[2].y), pk2(xr[2].z,xr[2].w), pk2(xr[3].x,xr[3].y), pk2(xr[3].z,xr[3].w)};
        *(uint4*)(xc + row * 128 + ((q4 * 32) ^ swz)) = p0;
        *(uint4*)(xc + row * 128 + ((q4 * 32 + 16) ^ swz)) = p1;
        __syncthreads();            // c==0 also drains the At DMA
        if (c < 3) LOADX(c + 1);
        #pragma unroll
        for (int ks = 0; ks < 2; ++ks){
            int arow = 16 * w + lm;
            bf16x8 af = *(const bf16x8*)(xc + arow * 128 + ((ks*64 + l4*16) ^ ((arow & 7) << 4)));
            #pragma unroll
            for (int nt = 0; nt < 4; ++nt){
                int brow = nt * 16 + lm;
                bf16x8 bf = *(const bf16x8*)(at + c * 8192 + brow * 128 + ((ks*64 + l4*16) ^ ((brow & 7) << 4)));
                acc[nt] = __builtin_amdgcn_mfma_f32_16x16x32_bf16(af, bf, acc[nt], 0, 0, 0);
            }
        }
    }
    #undef LOADX
    ss += __shfl_xor(ss, 1); ss += __shfl_xor(ss, 2);
    if (q4 == 0) sspart[sp * Mn + m0 + row] = ss;
    #pragma unroll
    for (int nt = 0; nt < 4; ++nt)
        #pragma unroll
        for (int r = 0; r < 4; ++r){
            int ml = 16 * w + 4 * l4 + r;
            tpart[(size_t)sp * TSTRIDE + (size_t)(m0 + ml) * 64 + nt * 16 + lm] = f2bf(acc[nt][r]);
        }
}

// ---------------- down GEMM for y (fused slice-combine), bf16 t-partials out
__global__ __launch_bounds__(256) void downy_g(const unsigned short* __restrict__ ybf,
                                               const unsigned short* __restrict__ pab,
                                               const float* __restrict__ pl,
                                               const char* __restrict__ AtImg,
                                               unsigned short* __restrict__ tpart){
    __shared__ char xt[32768];
    __shared__ char at[32768];
    int tid = threadIdx.x;
    int m0 = blockIdx.x * 64, sp = blockIdx.y;
    int row = tid >> 2, q4 = tid & 3;
    int w = tid >> 6, lane = tid & 63, l4 = lane >> 4, lm = lane & 15;
    int swz = (row & 7) << 4;
    int jq = (m0 & (Sn - 1)) >> 7;
    int bpos = m0 >> 11;
    int srow = (m0 & 127) + row;
    dma32k(AtImg + (size_t)sp * 32768, at, tid);
    f32x4 acc[4];
    #pragma unroll
    for (int nt = 0; nt < 4; ++nt) acc[nt] = (f32x4){0.f,0.f,0.f,0.f};

    #define MFMAC(c) { \
        _Pragma("unroll") \
        for (int ks = 0; ks < 2; ++ks){ \
            int arow = 16 * w + lm; \
            bf16x8 af = *(const bf16x8*)(xt + (c) * 8192 + arow * 128 + ((ks*64 + l4*16) ^ ((arow & 7) << 4))); \
            _Pragma("unroll") \
            for (int nt = 0; nt < 4; ++nt){ \
                int brow = nt * 16 + lm; \
                bf16x8 bf = *(const bf16x8*)(at + (c) * 8192 + brow * 128 + ((ks*64 + l4*16) ^ ((brow & 7) << 4))); \
                acc[nt] = __builtin_amdgcn_mfma_f32_16x16x32_bf16(af, bf, acc[nt], 0, 0, 0); \
            } \
        } }

    if (jq < 8){
        const char* yb = (const char*)ybf;
        #pragma unroll
        for (int p = 0; p < 8; ++p){
            int c = p >> 1;
            int rw = (p & 1) * 32 + (tid >> 3);
            int gp = (tid & 7) ^ (rw & 7);
            gld16(yb + (size_t)(m0 + rw) * 2048 + sp * 512 + c * 128 + gp * 16,
                  xt + p * 4096 + tid * 16);
        }
        __syncthreads();
        for (int c = 0; c < 4; ++c) MFMAC(c);
    } else {
        uint4 xrb[2];
        #define LOADCMB(c) { int k0 = sp * 256 + (c) * 64; \
            int h = k0 >> 7; int d0 = k0 & 127; \
            int s0sl = (((bpos * 8 + h) * 8) + (jq - 8)) * 2; \
            const unsigned short* p0 = pab + (size_t)s0sl * 16384 + srow * 128 + d0 + q4 * 16; \
            const unsigned short* p1 = p0 + 16384; \
            float Wc = 1.f / (pl[s0sl * 128 + srow] + pl[(s0sl + 1) * 128 + srow]); \
            uint4 A0 = ((const uint4*)p0)[0], A1 = ((const uint4*)p0)[1]; \
            uint4 C0 = ((const uint4*)p1)[0], C1 = ((const uint4*)p1)[1]; \
            xrb[0] = comb8(A0, C0, Wc); xrb[1] = comb8(A1, C1, Wc); }
        LOADCMB(0);
        for (int c = 0; c < 4; ++c){
            char* xc = xt + c * 8192;
            *(uint4*)(xc + row * 128 + ((q4 * 32) ^ swz)) = xrb[0];
            *(uint4*)(xc + row * 128 + ((q4 * 32 + 16) ^ swz)) = xrb[1];
            __syncthreads();
            if (c < 3) LOADCMB(c + 1);
            MFMAC(c);
        }
        #undef LOADCMB
    }
    #undef MFMAC
    #pragma unroll
    for (int nt = 0; nt < 4; ++nt)
        #pragma unroll
        for (int r = 0; r < 4; ++r){
            int ml = 16 * w + 4 * l4 + r;
            tpart[(size_t)sp * TSTRIDE + (size_t)(m0 + ml) * 64 + nt * 16 + lm] = f2bf(acc[nt][r]);
        }
}

// ---------------- stage t tile (sum 4 bf16 K-split partials, optional rms) into swizzled LDS
template<int DORMS>
__device__ __forceinline__ void stage_t(char* tt, const unsigned short* __restrict__ tpart,
                                        const float* __restrict__ sspart, int m0, int tid){
    int row = tid >> 2, q4 = tid & 3;
    const unsigned short* bp = tpart + (size_t)(m0 + row) * 64 + q4 * 16;
    float s[16];
    #pragma unroll
    for (int half = 0; half < 2; ++half){
        uint4 u0 = ((const uint4*)(bp + 0 * TSTRIDE))[half];
        uint4 u1 = ((const uint4*)(bp + 1 * TSTRIDE))[half];
        uint4 u2 = ((const uint4*)(bp + 2 * TSTRIDE))[half];
        uint4 u3 = ((const uint4*)(bp + 3 * TSTRIDE))[half];
        const unsigned int* a0 = (const unsigned int*)&u0;
        const unsigned int* a1 = (const unsigned int*)&u1;
        const unsigned int* a2 = (const unsigned int*)&u2;
        const unsigned int* a3 = (const unsigned int*)&u3;
        #pragma unroll
        for (int e = 0; e < 4; ++e){
            s[half*8 + 2*e]     = bflo(a0[e]) + bflo(a1[e]) + bflo(a2[e]) + bflo(a3[e]);
            s[half*8 + 2*e + 1] = bfhi(a0[e]) + bfhi(a1[e]) + bfhi(a2[e]) + bfhi(a3[e]);
        }
    }
    float rr = 1.f;
    if (DORMS){
        int m = m0 + row;
        float ssum = sspart[m] + sspart[Mn + m] + sspart[2*Mn + m] + sspart[3*Mn + m];
        rr = rsqrtf(ssum * (1.f / 1024.f) + 1.1920929e-07f);
    }
    #pragma unroll
    for (int i = 0; i < 16; ++i) s[i] *= rr;
    int swz = (row & 7) << 4;
    uint4 p0 = {pk2(s[0],s[1]), pk2(s[2],s[3]), pk2(s[4],s[5]), pk2(s[6],s[7])};
    uint4 p1 = {pk2(s[8],s[9]), pk2(s[10],s[11]), pk2(s[12],s[13]), pk2(s[14],s[15])};
    *(uint4*)(tt + row * 128 + ((q4 * 32) ^ swz)) = p0;
    *(uint4*)(tt + row * 128 + ((q4 * 32 + 16) ^ swz)) = p1;
}

// ---------------- up GEMM (final projection): DMA Bt image; base optionally bf16
template<int SILU, int HASBASE, int OUT_BF16, int DORMS, int BASEBF16>
__global__ __launch_bounds__(256) void up_g(const unsigned short* __restrict__ tpart,
                                            const float* __restrict__ sspart,
                                            const char* __restrict__ BtImg,
                                            const void* base,
                                            void* __restrict__ outp){
    __shared__ char tt[4096];
    __shared__ char bb[32768];
    int tid = threadIdx.x;
    int m0 = blockIdx.x * 32, n0 = blockIdx.y * 256;
    int w = tid >> 6, lane = tid & 63, l4 = lane >> 4, lm = lane & 15;
    int wm = w & 1, wn = w >> 1;
    dma32k(BtImg + (size_t)blockIdx.y * 32768, bb, tid);
    if (tid < 128) stage_t<DORMS>(tt, tpart, sspart, m0, tid);
    __syncthreads();
    bf16x8 af[2];
    #pragma unroll
    for (int ks = 0; ks < 2; ++ks){
        int arow = 16 * wm + lm;
        af[ks] = *(const bf16x8*)(tt + arow * 128 + ((ks*64 + l4*16) ^ ((arow & 7) << 4)));
    }
    f32x4 acc[8];
    #pragma unroll
    for (int nt = 0; nt < 8; ++nt) acc[nt] = (f32x4){0.f,0.f,0.f,0.f};
    #pragma unroll
    for (int nt = 0; nt < 8; ++nt){
        int brow = wn * 128 + nt * 16 + lm;
        #pragma unroll
        for (int ks = 0; ks < 2; ++ks){
            bf16x8 bf = *(const bf16x8*)(bb + brow * 128 + ((ks*64 + l4*16) ^ ((brow & 7) << 4)));
            acc[nt] = __builtin_amdgcn_mfma_f32_16x16x32_bf16(af[ks], bf, acc[nt], 0, 0, 0);
        }
    }
    #pragma unroll
    for (int nt = 0; nt < 8; ++nt)
        #pragma unroll
        for (int r = 0; r < 4; ++r){
            int m = m0 + 16 * wm + 4 * l4 + r;
            int n = n0 + wn * 128 + nt * 16 + lm;
            float v = acc[nt][r];
            if (SILU) v = v / (1.f + __expf(-v));
            if (HASBASE){
                if (BASEBF16) v += bf2f(((const unsigned short*)base)[(size_t)m * 1024 + n]);
                else          v += ((const float*)base)[(size_t)m * 1024 + n];
            }
            if (OUT_BF16) ((unsigned short*)outp)[(size_t)m * 1024 + n] = f2bf(v);
            else          ((float*)outp)[(size_t)m * 1024 + n] = v;
        }
}

// ---------------- FUSED up->down: DMA BtU image, DMA AtD ud-image; bf16 tpout;
// STOREOUT stores x1 as bf16 to x1out
template<int SILU, int HASBASE, int STOREOUT, int SUMSQ, int DORMS_IN>
__global__ __launch_bounds__(256) void updown_g(const unsigned short* __restrict__ tpin,
                                                const float* __restrict__ sspin,
                                                const char* __restrict__ BtUimg,
                                                const char* __restrict__ AtDimg,
                                                const float* base,
                                                unsigned short* x1out,
                                                unsigned short* __restrict__ tpout,
                                                float* __restrict__ sspout){
    __shared__ char tt[4096];
    __shared__ char bb[32768];     // BtU image, later AtD image
    __shared__ char xb[16384];     // bounced up-output tile [32][256] bf16
    __shared__ float ssl[2][32];
    int tid = threadIdx.x;
    int m0 = blockIdx.x * 32, n0 = blockIdx.y * 256, sp = blockIdx.y;
    int w = tid >> 6, lane = tid & 63, l4 = lane >> 4, lm = lane & 15;
    int wm = w & 1, wn = w >> 1;
    dma32k(BtUimg + (size_t)sp * 32768, bb, tid);
    if (tid < 128) stage_t<DORMS_IN>(tt, tpin, sspin, m0, tid);
    __syncthreads();
    // ---- up MFMA
    bf16x8 af[2];
    #pragma unroll
    for (int ks = 0; ks < 2; ++ks){
        int arow = 16 * wm + lm;
        af[ks] = *(const bf16x8*)(tt + arow * 128 + ((ks*64 + l4*16) ^ ((arow & 7) << 4)));
    }
    f32x4 acc[8];
    #pragma unroll
    for (int nt = 0; nt < 8; ++nt) acc[nt] = (f32x4){0.f,0.f,0.f,0.f};
    #pragma unroll
    for (int nt = 0; nt < 8; ++nt){
        int brow = wn * 128 + nt * 16 + lm;
        #pragma unroll
        for (int ks = 0; ks < 2; ++ks){
            bf16x8 bf = *(const bf16x8*)(bb + brow * 128 + ((ks*64 + l4*16) ^ ((brow & 7) << 4)));
            acc[nt] = __builtin_amdgcn_mfma_f32_16x16x32_bf16(af[ks], bf, acc[nt], 0, 0, 0);
        }
    }
    // ---- epilogue
    float val[8][4];
    float sq[4] = {0.f, 0.f, 0.f, 0.f};
    #pragma unroll
    for (int nt = 0; nt < 8; ++nt)
        #pragma unroll
        for (int r = 0; r < 4; ++r){
            int m = m0 + 16 * wm + 4 * l4 + r;
            int n = n0 + wn * 128 + nt * 16 + lm;
            float v = acc[nt][r];
            if (SILU) v = v / (1.f + __expf(-v));
            if (HASBASE) v += base[(size_t)m * 1024 + n];
            val[nt][r] = v;
            if (STOREOUT) x1out[(size_t)m * 1024 + n] = f2bf(v);
            if (SUMSQ) sq[r] += v * v;
        }
    if (SUMSQ){
        #pragma unroll
        for (int r = 0; r < 4; ++r){
            float s_ = sq[r];
            s_ += __shfl_xor(s_, 1);
            s_ += __shfl_xor(s_, 2);
            s_ += __shfl_xor(s_, 4);
            s_ += __shfl_xor(s_, 8);
            if (lm == 0) ssl[wn][16 * wm + 4 * l4 + r] = s_;
        }
    }
    __syncthreads();   // bb reads done, ssl visible
    // ---- DMA AtD ud-image into bb; bounce val -> xb
    dma32k(AtDimg + (size_t)sp * 32768, bb, tid);
    #pragma unroll
    for (int nt = 0; nt < 8; ++nt)
        #pragma unroll
        for (int r = 0; r < 4; ++r){
            int mrow = 16 * wm + 4 * l4 + r;
            int cn = wn * 128 + nt * 16 + lm;
            *(unsigned short*)(xb + mrow * 512 + ((cn * 2) ^ ((mrow & 7) << 4))) = f2bf(val[nt][r]);
        }
    __syncthreads();
    if (SUMSQ && tid < 32)
        sspout[sp * Mn + m0 + tid] = ssl[0][tid] + ssl[1][tid];
    // ---- down MFMA
    f32x4 acc2[2];
    acc2[0] = (f32x4){0.f,0.f,0.f,0.f};
    acc2[1] = (f32x4){0.f,0.f,0.f,0.f};
    #pragma unroll
    for (int kk = 0; kk < 8; ++kk){
        int arow = 16 * (w & 1) + lm;
        bf16x8 a2 = *(const bf16x8*)(xb + arow * 512 + ((kk * 64 + l4 * 16) ^ ((arow & 7) << 4)));
        #pragma unroll
        for (int j = 0; j < 2; ++j){
            int brow = (2 * (w >> 1) + j) * 16 + lm;
            bf16x8 b2 = *(const bf16x8*)(bb + brow * 512 + ((kk * 64 + l4 * 16) ^ ((brow & 7) << 4)));
            acc2[j] = __builtin_amdgcn_mfma_f32_16x16x32_bf16(a2, b2, acc2[j], 0, 0, 0);
        }
    }
    #pragma unroll
    for (int j = 0; j < 2; ++j)
        #pragma unroll
        for (int r = 0; r < 4; ++r){
            int ml = 16 * (w & 1) + 4 * l4 + r;
            int nc = (2 * (w >> 1) + j) * 16 + lm;
            tpout[(size_t)sp * TSTRIDE + (size_t)(m0 + ml) * 64 + nc] = f2bf(acc2[j][r]);
        }
}

// ---------------- fused QKV up-proj + RoPE, SPLIT across blockIdx.z
__global__ __launch_bounds__(256) void qkv_g(const unsigned short* __restrict__ tpart,
                                             const float* __restrict__ sspart,
                                             const char* __restrict__ BIq,
                                             const char* __restrict__ BIk,
                                             const char* __restrict__ BIv,
                                             const float2* __restrict__ rt,
                                             unsigned short* __restrict__ qout,
                                             char* __restrict__ Kimg,
                                             char* __restrict__ Vimg){
    __shared__ char tt[8192];
    __shared__ char bb[32768];
    int tid = threadIdx.x;
    int m0 = blockIdx.x * 64, n0 = blockIdx.y * 256;
    int which = blockIdx.z;
    int b = m0 >> 11, s0 = m0 & (Sn - 1);
    int h0 = n0 >> 7;
    int w = tid >> 6, lane = tid & 63, l4 = lane >> 4, lm = lane & 15;
    const char* BI = (which == 0) ? BIq : (which == 1) ? BIk : BIv;
    dma32k(BI + (size_t)blockIdx.y * 32768, bb, tid);
    stage_t<1>(tt, tpart, sspart, m0, tid);
    __syncthreads();
    bf16x8 af[2];
    #pragma unroll
    for (int ks = 0; ks < 2; ++ks){
        int arow = 16 * w + lm;
        af[ks] = *(const bf16x8*)(tt + arow * 128 + ((ks*64 + l4*16) ^ ((arow & 7) << 4)));
    }
    f32x4 acc[16];
    #pragma unroll
    for (int nt = 0; nt < 16; ++nt) acc[nt] = (f32x4){0.f,0.f,0.f,0.f};
    #pragma unroll
    for (int nt = 0; nt < 16; ++nt){
        int brow = nt * 16 + lm;
        #pragma unroll
        for (int ks = 0; ks < 2; ++ks){
            bf16x8 bf = *(const bf16x8*)(bb + brow * 128 + ((ks*64 + l4*16) ^ ((brow & 7) << 4)));
            acc[nt] = __builtin_amdgcn_mfma_f32_16x16x32_bf16(af[ks], bf, acc[nt], 0, 0, 0);
        }
    }
    if (which < 2){
        float2 cs[4][4];
        #pragma unroll
        for (int ntb = 0; ntb < 4; ++ntb)
            #pragma unroll
            for (int r = 0; r < 4; ++r)
                cs[ntb][r] = rt[(size_t)(s0 + 16*w + 4*l4 + r) * 64 + ntb * 16 + lm];
        #pragma unroll
        for (int g = 0; g < 2; ++g)
            #pragma unroll
            for (int ntb = 0; ntb < 4; ++ntb){
                int lo = g*8 + ntb, hi = lo + 4;
                #pragma unroll
                for (int r = 0; r < 4; ++r){
                    float2 c = cs[ntb][r];
                    float a = acc[lo][r], bq = acc[hi][r];
                    acc[lo][r] = a * c.x + bq * c.y;
                    acc[hi][r] = -a * c.y + bq * c.x;
                }
            }
        __syncthreads();
        #pragma unroll
        for (int nt = 0; nt < 16; ++nt)
            #pragma unroll
            for (int r = 0; r < 4; ++r){
                int nl = nt * 16 + lm, ml2 = 16 * w + 4 * l4 + r;
                *(unsigned short*)(bb + ml2 * 512 + ((nl * 2) ^ ((ml2 & 7) << 4))) = f2bf(acc[nt][r]);
            }
        __syncthreads();
        if (which == 0){
            int ml = tid >> 2, seg = tid & 3;
            int head = h0 + (seg >> 1), hd0q = (seg & 1) * 64;
            size_t dstbase = (((size_t)(b * 8 + head) * Sn + (s0 + ml)) * 128 + hd0q);
            #pragma unroll
            for (int j = 0; j < 8; ++j){
                uint4 v = *(const uint4*)(bb + ml * 512 + ((seg * 128 + j * 16) ^ ((ml & 7) << 4)));
                *(uint4*)(qout + dstbase + j * 8) = v;
            }
        } else {
            int ml = tid >> 2, seg = tid & 3;
            int hd0q = (seg & 1) * 64;
            int head = h0 + (seg >> 1);
            int pr = 16 * (ml & 3) + (ml >> 2);
            size_t rowb = (((size_t)(b * 8 + head) * 32 + (s0 >> 6)) * 64 + pr) * 256;
            #pragma unroll
            for (int j = 0; j < 8; ++j){
                uint4 v = *(const uint4*)(bb + ml * 512 + ((seg * 128 + j * 16) ^ ((ml & 7) << 4)));
                int cb = hd0q * 2 + j * 16;
                *(uint4*)(Kimg + rowb + (cb ^ ((pr & 7) << 4))) = v;
            }
        }
    } else {
        __syncthreads();
        #pragma unroll
        for (int nt = 0; nt < 16; ++nt)
            #pragma unroll
            for (int r = 0; r < 4; ++r){
                int nl = nt * 16 + lm, ml2 = 16 * w + 4 * l4 + r;
                *(unsigned short*)(bb + nl * 128 + ((ml2 * 2) ^ ((nl & 7) << 4))) = f2bf(acc[nt][r]);
            }
        __syncthreads();
        int head = h0 + (tid >> 7), d = tid & 127;
        size_t rowb = (((size_t)(b * 8 + head) * 32 + (s0 >> 6)) * 128 + d) * 128;
        #pragma unroll
        for (int j = 0; j < 8; ++j){
            uint4 v = *(const uint4*)(bb + tid * 128 + ((j * 16) ^ ((tid & 7) << 4)));
            *(uint4*)(Vimg + rowb + ((j * 16) ^ ((d & 7) << 4))) = v;
        }
    }
}

// ---------------- K-split flash attention (R19, unchanged)
__global__ __launch_bounds__(256, 2) void attn2_kernel(const unsigned short* __restrict__ qb,
                                                       const char* __restrict__ Kimg,
                                                       const char* __restrict__ Vimg,
                                                       unsigned short* __restrict__ ybf,
                                                       unsigned short* __restrict__ pab,
                                                       float* __restrict__ pl){
    __shared__ uint4 smem4[81920 / 16];
    char* smem = (char*)smem4;
    int tid = threadIdx.x;
    int w = tid >> 6, lane = tid & 63, l4 = lane >> 4, lm = lane & 15;
    int i = blockIdx.x;
    int xg = i & 7, j5 = i >> 3;
    int bh = 2 * xg + (j5 & 1);
    int slot = j5 >> 1;
    int grp = slot >> 3, g = slot & 7;
    int J, t0, niters, direct, slice;
    if (grp == 0){ J = 8 + g;  t0 = 0;  niters = 16;         direct = 0; slice = (bh * 8 + g) * 2; }
    else if (grp == 1){ J = 15 - g; t0 = 16; niters = 2 * J - 14; direct = 0; slice = (bh * 8 + (J - 8)) * 2 + 1; }
    else { J = 7 - g;  t0 = 0;  niters = 2 * J + 2;  direct = 1; slice = 0; }
    int b = bh >> 3, h = bh & 7;
    int qrow0w = 128 * J + 32 * w;
    int wqmax = qrow0w + 31;

    bf16x8 qf[2][4];
    #pragma unroll
    for (int f = 0; f < 2; ++f){
        const unsigned short* qg = qb + ((size_t)bh * Sn + qrow0w + 16 * f + lm) * HDn;
        #pragma unroll
        for (int df = 0; df < 4; ++df)
            qf[f][df] = *(const bf16x8*)(qg + df * 32 + l4 * 8);
    }
    f32x4 acc[2][8];
    #pragma unroll
    for (int f = 0; f < 2; ++f)
        #pragma unroll
        for (int dg = 0; dg < 8; ++dg) acc[f][dg] = (f32x4){0.f,0.f,0.f,0.f};
    float lp[2][4];
    #pragma unroll
    for (int f = 0; f < 2; ++f)
        #pragma unroll
        for (int r = 0; r < 4; ++r) lp[f][r] = 0.f;

    const float OFF = 11.541560327111708f;   // 8 * log2(e)
    size_t imgbase = (size_t)bh * 32 * 16384;

    #define STAGE_DMA(T, BUFB) { size_t tb = imgbase + (size_t)(T) * 16384; \
        _Pragma("unroll") for (int i2 = 0; i2 < 4; ++i2){ \
            gld16(Kimg + tb + i2 * 4096 + tid * 16, smem + (BUFB) + i2 * 4096 + tid * 16); \
            gld16(Vimg + tb + i2 * 4096 + tid * 16, smem + (BUFB) + 16384 + i2 * 4096 + tid * 16); } }

    STAGE_DMA(t0, 0);
    __syncthreads();

    for (int it = 0; it < niters; ++it){
        int t = t0 + it;
        int bsel = (it & 1) << 15;
        if (it + 1 < niters)
            STAGE_DMA(t + 1, bsel ^ 32768);
        if (64 * t <= wqmax){
            char* KL = smem + bsel;
            char* VL = smem + bsel + 16384;
            char* pb = smem + 65536 + (w << 12);
            __builtin_amdgcn_s_setprio(1);
            f32x4 sf[2][4];
            #pragma unroll
            for (int kc = 0; kc < 4; ++kc){ sf[0][kc] = (f32x4){0.f,0.f,0.f,0.f}; sf[1][kc] = (f32x4){0.f,0.f,0.f,0.f}; }
            #pragma unroll
            for (int kc = 0; kc < 4; ++kc){
                int krow = 16 * kc + lm;
                int ksw = (krow & 7) << 4;
                #pragma unroll
                for (int df = 0; df < 4; ++df){
                    bf16x8 kf = *(const bf16x8*)(KL + krow * 256 + ((df * 64 + l4 * 16) ^ ksw));
                    sf[0][kc] = __builtin_amdgcn_mfma_f32_16x16x32_bf16(qf[0][df], kf, sf[0][kc], 0, 0, 0);
                    sf[1][kc] = __builtin_amdgcn_mfma_f32_16x16x32_bf16(qf[1][df], kf, sf[1][kc], 0, 0, 0);
                }
            }
            bool needmask = (64 * t + 63 > qrow0w);
            #pragma unroll
            for (int f = 0; f < 2; ++f){
                #pragma unroll
                for (int r = 0; r < 4; ++r){
                    float s0v = sf[f][0][r], s1v = sf[f][1][r],
                          s2v = sf[f][2][r], s3v = sf[f][3][r];
                    if (needmask){
                        int qr = qrow0w + 16 * f + 4 * l4 + r;
                        int j0k = 64 * t + 4 * lm;
                        s0v = (j0k     > qr) ? -1e30f : s0v;
                        s1v = (j0k + 1 > qr) ? -1e30f : s1v;
                        s2v = (j0k + 2 > qr) ? -1e30f : s2v;
                        s3v = (j0k + 3 > qr) ? -1e30f : s3v;
                    }
                    float p0 = vexp2(s0v - OFF), p1 = vexp2(s1v - OFF),
                          p2 = vexp2(s2v - OFF), p3 = vexp2(s3v - OFF);
                    lp[f][r] += p0 + p1 + p2 + p3;
                    int prow = 16 * f + 4 * l4 + r;
                    uint2 pkd = {pk2(p0, p1), pk2(p2, p3)};
                    *(uint2*)(pb + prow * 128 + ((lm * 8) ^ ((prow & 7) << 4))) = pkd;
                }
            }
            #pragma unroll
            for (int ks = 0; ks < 2; ++ks){
                int pcol = (ks * 64 + l4 * 16) ^ ((lm & 7) << 4);
                bf16x8 pa0 = *(const bf16x8*)(pb + lm * 128 + pcol);
                bf16x8 pa1 = *(const bf16x8*)(pb + (16 + lm) * 128 + pcol);
                #pragma unroll
                for (int dg = 0; dg < 8; ++dg){
                    int vrow = 16 * dg + lm;
                    bf16x8 vf = *(const bf16x8*)(VL + vrow * 128 + ((ks * 64 + l4 * 16) ^ ((vrow & 7) << 4)));
                    acc[0][dg] = __builtin_amdgcn_mfma_f32_16x16x32_bf16(pa0, vf, acc[0][dg], 0, 0, 0);
                    acc[1][dg] = __builtin_amdgcn_mfma_f32_16x16x32_bf16(pa1, vf, acc[1][dg], 0, 0, 0);
                }
            }
            __builtin_amdgcn_s_setprio(0);
        }
        __syncthreads();
    }
    #undef STAGE_DMA
    float lsum[2][4];
    #pragma unroll
    for (int f = 0; f < 2; ++f)
        #pragma unroll
        for (int r = 0; r < 4; ++r){
            float l_ = lp[f][r];
            l_ += __shfl_xor(l_, 1);
            l_ += __shfl_xor(l_, 2);
            l_ += __shfl_xor(l_, 4);
            l_ += __shfl_xor(l_, 8);
            lsum[f][r] = l_;
        }
    if (direct){
        #pragma unroll
        for (int f = 0; f < 2; ++f)
            #pragma unroll
            for (int r = 0; r < 4; ++r){
                float inv = 1.f / lsum[f][r];
                int row = qrow0w + 16 * f + 4 * l4 + r;
                unsigned short* yr = ybf + ((size_t)b * Sn + row) * Dn + h * HDn;
                #pragma unroll
                for (int dg = 0; dg < 8; ++dg)
                    yr[16 * dg + lm] = f2bf(acc[f][dg][r] * inv);
            }
    } else {
        unsigned short* pa_ = pab + (size_t)slice * 16384;
        #pragma unroll
        for (int f = 0; f < 2; ++f)
            #pragma unroll
            for (int r = 0; r < 4; ++r){
                int row = 32 * w + 16 * f + 4 * l4 + r;
                #pragma unroll
                for (int dg = 0; dg < 8; ++dg)
                    pa_[row * 128 + 16 * dg + lm] = f2bf(acc[f][dg][r]);
                if (lm == 0)
                    pl[slice * 128 + row] = lsum[f][r];
            }
    }
}

extern "C" void kernel_launch(void* const* d_in, const int* in_sizes, int n_in,
                              void* d_out, int out_size, void* d_ws, size_t ws_size,
                              hipStream_t stream){
    const float* x      = (const float*)d_in[0];
    const float* A      = (const float*)d_in[1];
    const float* Bm     = (const float*)d_in[2];
    const float* C_q    = (const float*)d_in[3];
    const float* C_k    = (const float*)d_in[4];
    const float* C_v    = (const float*)d_in[5];
    const float* C_o    = (const float*)d_in[6];
    const float* C_fc   = (const float*)d_in[7];
    const float* C_proj = (const float*)d_in[8];
    const float* scale1 = (const float*)d_in[9];
    const float* scale2 = (const float*)d_in[10];
    float* out = (float*)d_out;

    char* ws = (char*)d_ws;
    size_t off = 0;
    auto alloc = [&](size_t bytes)->char*{ char* p = ws + off; off += (bytes + 255) & ~(size_t)255; return p; };
    unsigned short* qb   = (unsigned short*)alloc((size_t)Mn * Dn * 2);   // 8MB
    char*           Kimg = alloc((size_t)16 * 32 * 16384);                // 8MB
    char*           Vimg = alloc((size_t)16 * 32 * 16384);                // 8MB
    unsigned short* ybf  = (unsigned short*)alloc((size_t)Mn * Dn * 2);   // 8MB
    unsigned short* pab  = (unsigned short*)alloc((size_t)256 * 16384 * 2); // 8MB
    float*          pl   = (float*)alloc((size_t)256 * 128 * 4);          // 128KB
    unsigned short* tpA  = (unsigned short*)alloc(4 * TSTRIDE * 2);       // 2MB (bf16)
    unsigned short* tpB  = (unsigned short*)alloc(4 * TSTRIDE * 2);       // 2MB (bf16)
    unsigned short* x1b  = (unsigned short*)alloc((size_t)Mn * Dn * 2);   // 8MB (bf16 x1)
    float*          sspA = (float*)alloc(4 * (size_t)Mn * 4);             // 64KB
    float*          sspB = (float*)alloc(4 * (size_t)Mn * 4);             // 64KB
    char*           AtI1c = alloc(131072);
    char*           AtI0c = alloc(131072);
    char*           AtI2u = alloc(131072);
    char*           AtI0u = alloc(131072);
    char*           BIq   = alloc(131072);
    char*           BIk   = alloc(131072);
    char*           BIv   = alloc(131072);
    char*           BIo   = alloc(131072);
    char*           BIfc  = alloc(131072);
    char*           BIpr  = alloc(131072);
    float2*         rt    = (float2*)alloc((size_t)Sn * 64 * 8);          // 1MB

    prep_g<<<3072, 256, 0, stream>>>(A, Bm, C_q, C_k, C_v, C_o, C_fc, C_proj,
                                     scale1, scale2,
                                     AtI1c, AtI0c, AtI2u, AtI0u,
                                     BIq, BIk, BIv, BIo, BIfc, BIpr, rt);
    // t1 partials = x @ At1 (s1 folded), ss = rowwise sumsq(x)
    down_g<<<dim3(Mn / 64, 4), 256, 0, stream>>>(x, AtI1c, tpA, sspA);
    // q (scaled+roped), K-image, V-image — SPLIT across z (768 blocks)
    qkv_g<<<dim3(Mn / 64, 4, 3), 256, 0, stream>>>(tpA, sspA, BIq, BIk, BIv, rt, qb, Kimg, Vimg);
    // attention (direct y for j<8; bf16 partials for j>=8)
    attn2_kernel<<<384, 256, 0, stream>>>(qb, Kimg, Vimg, ybf, pab, pl);
    // t2 partials = y @ At0 with slice-combine fused into staging
    downy_g<<<dim3(Mn / 64, 4), 256, 0, stream>>>(ybf, pab, pl, AtI0c, tpA);
    // FUSED: x1 = x + t2@Bto -> x1b (bf16); sumsq(x1) -> sspB; t3 = x1@At2 -> tpB
    updown_g<0, 1, 1, 1, 0><<<dim3(Mn / 32, 4), 256, 0, stream>>>(
        tpA, nullptr, BIo, AtI2u, x, x1b, tpB, sspB);
    // FUSED: m = silu(rms(t3)@Btfc) (never stored); t4 = m@At0 -> tpA
    updown_g<1, 0, 0, 0, 1><<<dim3(Mn / 32, 4), 256, 0, stream>>>(
        tpB, sspB, BIfc, AtI0u, nullptr, nullptr, tpA, nullptr);
    // out = x1b + t4 @ Btpr  (bf16 base, f32 out)
    up_g<0, 1, 0, 0, 1><<<dim3(Mn / 32, 4), 256, 0, stream>>>(tpA, nullptr, BIpr, x1b, out);
}

// Round 24
// 95.301 us; speedup vs baseline: 1.5426x; 1.0628x over previous
//
#include <hip/hip_runtime.h>

// HolographicBlock: B=2, S=2048, D=1024, R=64, H=8, HD=128
// Pre-swizzled weight images + global_load_lds everywhere; bf16 t-partials;
// qkv z-split; bf16 residual carrier x1b.
// Attention = R19 + NEW: rank-ordered block permutation (long slots spread
// across CUs first; short slots co-resident) — pure index remap.

#define Bn 2
#define Sn 2048
#define Dn 1024
#define Rn 64
#define Hn 8
#define HDn 128
#define Mn (Bn*Sn)   // 4096 rows
#define TSTRIDE ((size_t)Mn * Rn)

typedef __bf16 bf16x8 __attribute__((ext_vector_type(8)));
typedef float f32x4 __attribute__((ext_vector_type(4)));
typedef __attribute__((address_space(1))) const unsigned int g_u32;
typedef __attribute__((address_space(3))) unsigned int l_u32;

__device__ __forceinline__ float bf2f(unsigned short u){
    union { unsigned int i; float f; } x; x.i = ((unsigned int)u) << 16; return x.f;
}
__device__ __forceinline__ unsigned short f2bf(float f){
    union { float f; unsigned int i; } x; x.f = f;
    unsigned int r = x.i + 0x7fffu + ((x.i >> 16) & 1u);
    return (unsigned short)(r >> 16);
}
__device__ __forceinline__ unsigned int pk2(float a, float b){
    unsigned int r;
    asm("v_cvt_pk_bf16_f32 %0, %1, %2" : "=v"(r) : "v"(a), "v"(b));
    return r;
}
__device__ __forceinline__ float vexp2(float x){
    float r;
    asm("v_exp_f32 %0, %1" : "=v"(r) : "v"(x));
    return r;
}
__device__ __forceinline__ void gld16(const void* g, void* l){
    __builtin_amdgcn_global_load_lds((g_u32*)g, (l_u32*)l, 16, 0, 0);
}
__device__ __forceinline__ void dma32k(const char* src, char* dst, int tid){
    #pragma unroll
    for (int p = 0; p < 8; ++p)
        gld16(src + p * 4096 + tid * 16, dst + p * 4096 + tid * 16);
}
__device__ __forceinline__ float bflo(unsigned int u){
    union { unsigned int i; float f; } x; x.i = u << 16; return x.f;
}
__device__ __forceinline__ float bfhi(unsigned int u){
    union { unsigned int i; float f; } x; x.i = u & 0xffff0000u; return x.f;
}
__device__ __forceinline__ uint4 comb8(uint4 A, uint4 C, float Wc){
    uint4 r;
    unsigned int* a = (unsigned int*)&A;
    unsigned int* c = (unsigned int*)&C;
    unsigned int* o = (unsigned int*)&r;
    #pragma unroll
    for (int e = 0; e < 4; ++e){
        float lo = (bflo(a[e]) + bflo(c[e])) * Wc;
        float hi = (bfhi(a[e]) + bfhi(c[e])) * Wc;
        o[e] = pk2(lo, hi);
    }
    return r;
}

// ---------------- prep: PRE-SWIZZLED weight images + rope table
__global__ __launch_bounds__(256) void prep_g(const float* __restrict__ A,
                                              const float* __restrict__ Bsrc,
                                              const float* __restrict__ Cq, const float* __restrict__ Ck,
                                              const float* __restrict__ Cv, const float* __restrict__ Co,
                                              const float* __restrict__ Cfc, const float* __restrict__ Cpr,
                                              const float* __restrict__ s1, const float* __restrict__ s2,
                                              char* __restrict__ AtI1c, char* __restrict__ AtI0c,
                                              char* __restrict__ AtI2u, char* __restrict__ AtI0u,
                                              char* __restrict__ BIq, char* __restrict__ BIk,
                                              char* __restrict__ BIv, char* __restrict__ BIo,
                                              char* __restrict__ BIfc, char* __restrict__ BIpr,
                                              float2* __restrict__ rt){
    int idx = blockIdx.x * 256 + threadIdx.x;
    if (idx < 4 * 65536){
        int v = idx >> 16, e = idx & 65535;
        int r = e & 63, d = e >> 6;
        float sc = (v == 0) ? s1[d] : (v == 2) ? s2[d] : 1.f;
        unsigned short val = f2bf(A[d * 64 + r] * sc);
        if (v < 2){
            int us = (d >> 6) * 4096 + r * 64 + (((((d >> 3) & 7) << 4) ^ ((r & 7) << 4)) >> 1) + (d & 7);
            ((unsigned short*)(v == 0 ? AtI1c : AtI0c))[us] = val;
        } else {
            int us = (d >> 8) * 16384 + r * 256 + (((((d >> 3) & 31) << 4) ^ ((r & 7) << 4)) >> 1) + (d & 7);
            ((unsigned short*)(v == 2 ? AtI2u : AtI0u))[us] = val;
        }
    } else if (idx < 10 * 65536){
        int v = (idx >> 16) - 4, e = idx & 65535;
        int d = e & 1023, r = e >> 10;
        const float* C = v==0?Cq : v==1?Ck : v==2?Cv : v==3?Co : v==4?Cfc : Cpr;
        float extra = (v == 0) ? (0.08838834764831845f * 1.4426950408889634f) : 1.f;
        unsigned short val = f2bf(Bsrc[r * 1024 + d] * C[r] * extra);
        int us = (d >> 8) * 16384 + (d & 255) * 64 + ((((r >> 3) << 4) ^ ((d & 7) << 4)) >> 1) + (r & 7);
        ((unsigned short*)(v==0?BIq : v==1?BIk : v==2?BIv : v==3?BIo : v==4?BIfc : BIpr))[us] = val;
    } else if (idx < 10 * 65536 + Sn * 64){
        int e = idx - 10 * 65536;
        int s = e >> 6, f = e & 63;
        float inv = exp2f(-(float)f * (13.287712379549449f / 64.0f));
        float fr = (float)s * inv;
        float sn, cs; sincosf(fr, &sn, &cs);
        rt[e] = make_float2(cs, sn);
    }
}

// ---------------- down GEMM (f32 input + sumsq): DMA At image, bf16 t-partials out
__global__ __launch_bounds__(256) void down_g(const float* __restrict__ inp,
                                              const char* __restrict__ AtImg,
                                              unsigned short* __restrict__ tpart,
                                              float* __restrict__ sspart){
    __shared__ char xt[32768];
    __shared__ char at[32768];
    int tid = threadIdx.x;
    int m0 = blockIdx.x * 64, sp = blockIdx.y;
    int row = tid >> 2, q4 = tid & 3;
    int w = tid >> 6, lane = tid & 63, l4 = lane >> 4, lm = lane & 15;
    int swz = (row & 7) << 4;
    dma32k(AtImg + (size_t)sp * 32768, at, tid);
    float ss = 0.f;
    f32x4 acc[4];
    #pragma unroll
    for (int nt = 0; nt < 4; ++nt) acc[nt] = (f32x4){0.f,0.f,0.f,0.f};

    float4 xr[4];
    #define LOADX(c) { int k0 = sp * 256 + (c) * 64; \
        const float4* s = (const float4*)(inp + (size_t)(m0+row)*1024 + k0 + q4*16); \
        xr[0]=s[0]; xr[1]=s[1]; xr[2]=s[2]; xr[3]=s[3]; }

    LOADX(0);
    for (int c = 0; c < 4; ++c){
        char* xc = xt + c * 8192;
        #pragma unroll
        for (int i = 0; i < 4; ++i)
            ss += xr[i].x*xr[i].x + xr[i].y*xr[i].y + xr[i].z*xr[i].z + xr[i].w*xr[i].w;
        uint4 p0 = {pk2(xr[0].x,xr[0].y), pk2(xr[0].z,xr[0].w), pk2(xr[1].x,xr[1].y), pk2(xr[1].z,xr[1].w)};
        uint4 p1 = {pk2(xr[2].x,xr[2].y), pk2(xr[2].z,xr[2].w), pk2(xr[3].x,xr[3].y), pk2(xr[3].z,xr[3].w)};
        *(uint4*)(xc + row * 128 + ((q4 * 32) ^ swz)) = p0;
        *(uint4*)(xc + row * 128 + ((q4 * 32 + 16) ^ swz)) = p1;
        __syncthreads();            // c==0 also drains the At DMA
        if (c < 3) LOADX(c + 1);
        #pragma unroll
        for (int ks = 0; ks < 2; ++ks){
            int arow = 16 * w + lm;
            bf16x8 af = *(const bf16x8*)(xc + arow * 128 + ((ks*64 + l4*16) ^ ((arow & 7) << 4)));
            #pragma unroll
            for (int nt = 0; nt < 4; ++nt){
                int brow = nt * 16 + lm;
                bf16x8 bf = *(const bf16x8*)(at + c * 8192 + brow * 128 + ((ks*64 + l4*16) ^ ((brow & 7) << 4)));
                acc[nt] = __builtin_amdgcn_mfma_f32_16x16x32_bf16(af, bf, acc[nt], 0, 0, 0);
            }
        }
    }
    #undef LOADX
    ss += __shfl_xor(ss, 1); ss += __shfl_xor(ss, 2);
    if (q4 == 0) sspart[sp * Mn + m0 + row] = ss;
    #pragma unroll
    for (int nt = 0; nt < 4; ++nt)
        #pragma unroll
        for (int r = 0; r < 4; ++r){
            int ml = 16 * w + 4 * l4 + r;
            tpart[(size_t)sp * TSTRIDE + (size_t)(m0 + ml) * 64 + nt * 16 + lm] = f2bf(acc[nt][r]);
        }
}

// ---------------- down GEMM for y (fused slice-combine), bf16 t-partials out
__global__ __launch_bounds__(256) void downy_g(const unsigned short* __restrict__ ybf,
                                               const unsigned short* __restrict__ pab,
                                               const float* __restrict__ pl,
                                               const char* __restrict__ AtImg,
                                               unsigned short* __restrict__ tpart){
    __shared__ char xt[32768];
    __shared__ char at[32768];
    int tid = threadIdx.x;
    int m0 = blockIdx.x * 64, sp = blockIdx.y;
    int row = tid >> 2, q4 = tid & 3;
    int w = tid >> 6, lane = tid & 63, l4 = lane >> 4, lm = lane & 15;
    int swz = (row & 7) << 4;
    int jq = (m0 & (Sn - 1)) >> 7;
    int bpos = m0 >> 11;
    int srow = (m0 & 127) + row;
    dma32k(AtImg + (size_t)sp * 32768, at, tid);
    f32x4 acc[4];
    #pragma unroll
    for (int nt = 0; nt < 4; ++nt) acc[nt] = (f32x4){0.f,0.f,0.f,0.f};

    #define MFMAC(c) { \
        _Pragma("unroll") \
        for (int ks = 0; ks < 2; ++ks){ \
            int arow = 16 * w + lm; \
            bf16x8 af = *(const bf16x8*)(xt + (c) * 8192 + arow * 128 + ((ks*64 + l4*16) ^ ((arow & 7) << 4))); \
            _Pragma("unroll") \
            for (int nt = 0; nt < 4; ++nt){ \
                int brow = nt * 16 + lm; \
                bf16x8 bf = *(const bf16x8*)(at + (c) * 8192 + brow * 128 + ((ks*64 + l4*16) ^ ((brow & 7) << 4))); \
                acc[nt] = __builtin_amdgcn_mfma_f32_16x16x32_bf16(af, bf, acc[nt], 0, 0, 0); \
            } \
        } }

    if (jq < 8){
        const char* yb = (const char*)ybf;
        #pragma unroll
        for (int p = 0; p < 8; ++p){
            int c = p >> 1;
            int rw = (p & 1) * 32 + (tid >> 3);
            int gp = (tid & 7) ^ (rw & 7);
            gld16(yb + (size_t)(m0 + rw) * 2048 + sp * 512 + c * 128 + gp * 16,
                  xt + p * 4096 + tid * 16);
        }
        __syncthreads();
        for (int c = 0; c < 4; ++c) MFMAC(c);
    } else {
        uint4 xrb[2];
        #define LOADCMB(c) { int k0 = sp * 256 + (c) * 64; \
            int h = k0 >> 7; int d0 = k0 & 127; \
            int s0sl = (((bpos * 8 + h) * 8) + (jq - 8)) * 2; \
            const unsigned short* p0 = pab + (size_t)s0sl * 16384 + srow * 128 + d0 + q4 * 16; \
            const unsigned short* p1 = p0 + 16384; \
            float Wc = 1.f / (pl[s0sl * 128 + srow] + pl[(s0sl + 1) * 128 + srow]); \
            uint4 A0 = ((const uint4*)p0)[0], A1 = ((const uint4*)p0)[1]; \
            uint4 C0 = ((const uint4*)p1)[0], C1 = ((const uint4*)p1)[1]; \
            xrb[0] = comb8(A0, C0, Wc); xrb[1] = comb8(A1, C1, Wc); }
        LOADCMB(0);
        for (int c = 0; c < 4; ++c){
            char* xc = xt + c * 8192;
            *(uint4*)(xc + row * 128 + ((q4 * 32) ^ swz)) = xrb[0];
            *(uint4*)(xc + row * 128 + ((q4 * 32 + 16) ^ swz)) = xrb[1];
            __syncthreads();
            if (c < 3) LOADCMB(c + 1);
            MFMAC(c);
        }
        #undef LOADCMB
    }
    #undef MFMAC
    #pragma unroll
    for (int nt = 0; nt < 4; ++nt)
        #pragma unroll
        for (int r = 0; r < 4; ++r){
            int ml = 16 * w + 4 * l4 + r;
            tpart[(size_t)sp * TSTRIDE + (size_t)(m0 + ml) * 64 + nt * 16 + lm] = f2bf(acc[nt][r]);
        }
}

// ---------------- stage t tile (sum 4 bf16 K-split partials, optional rms) into swizzled LDS
template<int DORMS>
__device__ __forceinline__ void stage_t(char* tt, const unsigned short* __restrict__ tpart,
                                        const float* __restrict__ sspart, int m0, int tid){
    int row = tid >> 2, q4 = tid & 3;
    const unsigned short* bp = tpart + (size_t)(m0 + row) * 64 + q4 * 16;
    float s[16];
    #pragma unroll
    for (int half = 0; half < 2; ++half){
        uint4 u0 = ((const uint4*)(bp + 0 * TSTRIDE))[half];
        uint4 u1 = ((const uint4*)(bp + 1 * TSTRIDE))[half];
        uint4 u2 = ((const uint4*)(bp + 2 * TSTRIDE))[half];
        uint4 u3 = ((const uint4*)(bp + 3 * TSTRIDE))[half];
        const unsigned int* a0 = (const unsigned int*)&u0;
        const unsigned int* a1 = (const unsigned int*)&u1;
        const unsigned int* a2 = (const unsigned int*)&u2;
        const unsigned int* a3 = (const unsigned int*)&u3;
        #pragma unroll
        for (int e = 0; e < 4; ++e){
            s[half*8 + 2*e]     = bflo(a0[e]) + bflo(a1[e]) + bflo(a2[e]) + bflo(a3[e]);
            s[half*8 + 2*e + 1] = bfhi(a0[e]) + bfhi(a1[e]) + bfhi(a2[e]) + bfhi(a3[e]);
        }
    }
    float rr = 1.f;
    if (DORMS){
        int m = m0 + row;
        float ssum = sspart[m] + sspart[Mn + m] + sspart[2*Mn + m] + sspart[3*Mn + m];
        rr = rsqrtf(ssum * (1.f / 1024.f) + 1.1920929e-07f);
    }
    #pragma unroll
    for (int i = 0; i < 16; ++i) s[i] *= rr;
    int swz = (row & 7) << 4;
    uint4 p0 = {pk2(s[0],s[1]), pk2(s[2],s[3]), pk2(s[4],s[5]), pk2(s[6],s[7])};
    uint4 p1 = {pk2(s[8],s[9]), pk2(s[10],s[11]), pk2(s[12],s[13]), pk2(s[14],s[15])};
    *(uint4*)(tt + row * 128 + ((q4 * 32) ^ swz)) = p0;
    *(uint4*)(tt + row * 128 + ((q4 * 32 + 16) ^ swz)) = p1;
}

// ---------------- up GEMM (final projection): DMA Bt image; base optionally bf16
template<int SILU, int HASBASE, int OUT_BF16, int DORMS, int BASEBF16>
__global__ __launch_bounds__(256) void up_g(const unsigned short* __restrict__ tpart,
                                            const float* __restrict__ sspart,
                                            const char* __restrict__ BtImg,
                                            const void* base,
                                            void* __restrict__ outp){
    __shared__ char tt[4096];
    __shared__ char bb[32768];
    int tid = threadIdx.x;
    int m0 = blockIdx.x * 32, n0 = blockIdx.y * 256;
    int w = tid >> 6, lane = tid & 63, l4 = lane >> 4, lm = lane & 15;
    int wm = w & 1, wn = w >> 1;
    dma32k(BtImg + (size_t)blockIdx.y * 32768, bb, tid);
    if (tid < 128) stage_t<DORMS>(tt, tpart, sspart, m0, tid);
    __syncthreads();
    bf16x8 af[2];
    #pragma unroll
    for (int ks = 0; ks < 2; ++ks){
        int arow = 16 * wm + lm;
        af[ks] = *(const bf16x8*)(tt + arow * 128 + ((ks*64 + l4*16) ^ ((arow & 7) << 4)));
    }
    f32x4 acc[8];
    #pragma unroll
    for (int nt = 0; nt < 8; ++nt) acc[nt] = (f32x4){0.f,0.f,0.f,0.f};
    #pragma unroll
    for (int nt = 0; nt < 8; ++nt){
        int brow = wn * 128 + nt * 16 + lm;
        #pragma unroll
        for (int ks = 0; ks < 2; ++ks){
            bf16x8 bf = *(const bf16x8*)(bb + brow * 128 + ((ks*64 + l4*16) ^ ((brow & 7) << 4)));
            acc[nt] = __builtin_amdgcn_mfma_f32_16x16x32_bf16(af[ks], bf, acc[nt], 0, 0, 0);
        }
    }
    #pragma unroll
    for (int nt = 0; nt < 8; ++nt)
        #pragma unroll
        for (int r = 0; r < 4; ++r){
            int m = m0 + 16 * wm + 4 * l4 + r;
            int n = n0 + wn * 128 + nt * 16 + lm;
            float v = acc[nt][r];
            if (SILU) v = v / (1.f + __expf(-v));
            if (HASBASE){
                if (BASEBF16) v += bf2f(((const unsigned short*)base)[(size_t)m * 1024 + n]);
                else          v += ((const float*)base)[(size_t)m * 1024 + n];
            }
            if (OUT_BF16) ((unsigned short*)outp)[(size_t)m * 1024 + n] = f2bf(v);
            else          ((float*)outp)[(size_t)m * 1024 + n] = v;
        }
}

// ---------------- FUSED up->down: DMA BtU image, DMA AtD ud-image; bf16 tpout;
// STOREOUT stores x1 as bf16 to x1out
template<int SILU, int HASBASE, int STOREOUT, int SUMSQ, int DORMS_IN>
__global__ __launch_bounds__(256) void updown_g(const unsigned short* __restrict__ tpin,
                                                const float* __restrict__ sspin,
                                                const char* __restrict__ BtUimg,
                                                const char* __restrict__ AtDimg,
                                                const float* base,
                                                unsigned short* x1out,
                                                unsigned short* __restrict__ tpout,
                                                float* __restrict__ sspout){
    __shared__ char tt[4096];
    __shared__ char bb[32768];     // BtU image, later AtD image
    __shared__ char xb[16384];     // bounced up-output tile [32][256] bf16
    __shared__ float ssl[2][32];
    int tid = threadIdx.x;
    int m0 = blockIdx.x * 32, n0 = blockIdx.y * 256, sp = blockIdx.y;
    int w = tid >> 6, lane = tid & 63, l4 = lane >> 4, lm = lane & 15;
    int wm = w & 1, wn = w >> 1;
    dma32k(BtUimg + (size_t)sp * 32768, bb, tid);
    if (tid < 128) stage_t<DORMS_IN>(tt, tpin, sspin, m0, tid);
    __syncthreads();
    // ---- up MFMA
    bf16x8 af[2];
    #pragma unroll
    for (int ks = 0; ks < 2; ++ks){
        int arow = 16 * wm + lm;
        af[ks] = *(const bf16x8*)(tt + arow * 128 + ((ks*64 + l4*16) ^ ((arow & 7) << 4)));
    }
    f32x4 acc[8];
    #pragma unroll
    for (int nt = 0; nt < 8; ++nt) acc[nt] = (f32x4){0.f,0.f,0.f,0.f};
    #pragma unroll
    for (int nt = 0; nt < 8; ++nt){
        int brow = wn * 128 + nt * 16 + lm;
        #pragma unroll
        for (int ks = 0; ks < 2; ++ks){
            bf16x8 bf = *(const bf16x8*)(bb + brow * 128 + ((ks*64 + l4*16) ^ ((brow & 7) << 4)));
            acc[nt] = __builtin_amdgcn_mfma_f32_16x16x32_bf16(af[ks], bf, acc[nt], 0, 0, 0);
        }
    }
    // ---- epilogue
    float val[8][4];
    float sq[4] = {0.f, 0.f, 0.f, 0.f};
    #pragma unroll
    for (int nt = 0; nt < 8; ++nt)
        #pragma unroll
        for (int r = 0; r < 4; ++r){
            int m = m0 + 16 * wm + 4 * l4 + r;
            int n = n0 + wn * 128 + nt * 16 + lm;
            float v = acc[nt][r];
            if (SILU) v = v / (1.f + __expf(-v));
            if (HASBASE) v += base[(size_t)m * 1024 + n];
            val[nt][r] = v;
            if (STOREOUT) x1out[(size_t)m * 1024 + n] = f2bf(v);
            if (SUMSQ) sq[r] += v * v;
        }
    if (SUMSQ){
        #pragma unroll
        for (int r = 0; r < 4; ++r){
            float s_ = sq[r];
            s_ += __shfl_xor(s_, 1);
            s_ += __shfl_xor(s_, 2);
            s_ += __shfl_xor(s_, 4);
            s_ += __shfl_xor(s_, 8);
            if (lm == 0) ssl[wn][16 * wm + 4 * l4 + r] = s_;
        }
    }
    __syncthreads();   // bb reads done, ssl visible
    // ---- DMA AtD ud-image into bb; bounce val -> xb
    dma32k(AtDimg + (size_t)sp * 32768, bb, tid);
    #pragma unroll
    for (int nt = 0; nt < 8; ++nt)
        #pragma unroll
        for (int r = 0; r < 4; ++r){
            int mrow = 16 * wm + 4 * l4 + r;
            int cn = wn * 128 + nt * 16 + lm;
            *(unsigned short*)(xb + mrow * 512 + ((cn * 2) ^ ((mrow & 7) << 4))) = f2bf(val[nt][r]);
        }
    __syncthreads();
    if (SUMSQ && tid < 32)
        sspout[sp * Mn + m0 + tid] = ssl[0][tid] + ssl[1][tid];
    // ---- down MFMA
    f32x4 acc2[2];
    acc2[0] = (f32x4){0.f,0.f,0.f,0.f};
    acc2[1] = (f32x4){0.f,0.f,0.f,0.f};
    #pragma unroll
    for (int kk = 0; kk < 8; ++kk){
        int arow = 16 * (w & 1) + lm;
        bf16x8 a2 = *(const bf16x8*)(xb + arow * 512 + ((kk * 64 + l4 * 16) ^ ((arow & 7) << 4)));
        #pragma unroll
        for (int j = 0; j < 2; ++j){
            int brow = (2 * (w >> 1) + j) * 16 + lm;
            bf16x8 b2 = *(const bf16x8*)(bb + brow * 512 + ((kk * 64 + l4 * 16) ^ ((brow & 7) << 4)));
            acc2[j] = __builtin_amdgcn_mfma_f32_16x16x32_bf16(a2, b2, acc2[j], 0, 0, 0);
        }
    }
    #pragma unroll
    for (int j = 0; j < 2; ++j)
        #pragma unroll
        for (int r = 0; r < 4; ++r){
            int ml = 16 * (w & 1) + 4 * l4 + r;
            int nc = (2 * (w >> 1) + j) * 16 + lm;
            tpout[(size_t)sp * TSTRIDE + (size_t)(m0 + ml) * 64 + nc] = f2bf(acc2[j][r]);
        }
}

// ---------------- fused QKV up-proj + RoPE, SPLIT across blockIdx.z
__global__ __launch_bounds__(256) void qkv_g(const unsigned short* __restrict__ tpart,
                                             const float* __restrict__ sspart,
                                             const char* __restrict__ BIq,
                                             const char* __restrict__ BIk,
                                             const char* __restrict__ BIv,
                                             const float2* __restrict__ rt,
                                             unsigned short* __restrict__ qout,
                                             char* __restrict__ Kimg,
                                             char* __restrict__ Vimg){
    __shared__ char tt[8192];
    __shared__ char bb[32768];
    int tid = threadIdx.x;
    int m0 = blockIdx.x * 64, n0 = blockIdx.y * 256;
    int which = blockIdx.z;
    int b = m0 >> 11, s0 = m0 & (Sn - 1);
    int h0 = n0 >> 7;
    int w = tid >> 6, lane = tid & 63, l4 = lane >> 4, lm = lane & 15;
    const char* BI = (which == 0) ? BIq : (which == 1) ? BIk : BIv;
    dma32k(BI + (size_t)blockIdx.y * 32768, bb, tid);
    stage_t<1>(tt, tpart, sspart, m0, tid);
    __syncthreads();
    bf16x8 af[2];
    #pragma unroll
    for (int ks = 0; ks < 2; ++ks){
        int arow = 16 * w + lm;
        af[ks] = *(const bf16x8*)(tt + arow * 128 + ((ks*64 + l4*16) ^ ((arow & 7) << 4)));
    }
    f32x4 acc[16];
    #pragma unroll
    for (int nt = 0; nt < 16; ++nt) acc[nt] = (f32x4){0.f,0.f,0.f,0.f};
    #pragma unroll
    for (int nt = 0; nt < 16; ++nt){
        int brow = nt * 16 + lm;
        #pragma unroll
        for (int ks = 0; ks < 2; ++ks){
            bf16x8 bf = *(const bf16x8*)(bb + brow * 128 + ((ks*64 + l4*16) ^ ((brow & 7) << 4)));
            acc[nt] = __builtin_amdgcn_mfma_f32_16x16x32_bf16(af[ks], bf, acc[nt], 0, 0, 0);
        }
    }
    if (which < 2){
        float2 cs[4][4];
        #pragma unroll
        for (int ntb = 0; ntb < 4; ++ntb)
            #pragma unroll
            for (int r = 0; r < 4; ++r)
                cs[ntb][r] = rt[(size_t)(s0 + 16*w + 4*l4 + r) * 64 + ntb * 16 + lm];
        #pragma unroll
        for (int g = 0; g < 2; ++g)
            #pragma unroll
            for (int ntb = 0; ntb < 4; ++ntb){
                int lo = g*8 + ntb, hi = lo + 4;
                #pragma unroll
                for (int r = 0; r < 4; ++r){
                    float2 c = cs[ntb][r];
                    float a = acc[lo][r], bq = acc[hi][r];
                    acc[lo][r] = a * c.x + bq * c.y;
                    acc[hi][r] = -a * c.y + bq * c.x;
                }
            }
        __syncthreads();
        #pragma unroll
        for (int nt = 0; nt < 16; ++nt)
            #pragma unroll
            for (int r = 0; r < 4; ++r){
                int nl = nt * 16 + lm, ml2 = 16 * w + 4 * l4 + r;
                *(unsigned short*)(bb + ml2 * 512 + ((nl * 2) ^ ((ml2 & 7) << 4))) = f2bf(acc[nt][r]);
            }
        __syncthreads();
        if (which == 0){
            int ml = tid >> 2, seg = tid & 3;
            int head = h0 + (seg >> 1), hd0q = (seg & 1) * 64;
            size_t dstbase = (((size_t)(b * 8 + head) * Sn + (s0 + ml)) * 128 + hd0q);
            #pragma unroll
            for (int j = 0; j < 8; ++j){
                uint4 v = *(const uint4*)(bb + ml * 512 + ((seg * 128 + j * 16) ^ ((ml & 7) << 4)));
                *(uint4*)(qout + dstbase + j * 8) = v;
            }
        } else {
            int ml = tid >> 2, seg = tid & 3;
            int hd0q = (seg & 1) * 64;
            int head = h0 + (seg >> 1);
            int pr = 16 * (ml & 3) + (ml >> 2);
            size_t rowb = (((size_t)(b * 8 + head) * 32 + (s0 >> 6)) * 64 + pr) * 256;
            #pragma unroll
            for (int j = 0; j < 8; ++j){
                uint4 v = *(const uint4*)(bb + ml * 512 + ((seg * 128 + j * 16) ^ ((ml & 7) << 4)));
                int cb = hd0q * 2 + j * 16;
                *(uint4*)(Kimg + rowb + (cb ^ ((pr & 7) << 4))) = v;
            }
        }
    } else {
        __syncthreads();
        #pragma unroll
        for (int nt = 0; nt < 16; ++nt)
            #pragma unroll
            for (int r = 0; r < 4; ++r){
                int nl = nt * 16 + lm, ml2 = 16 * w + 4 * l4 + r;
                *(unsigned short*)(bb + nl * 128 + ((ml2 * 2) ^ ((nl & 7) << 4))) = f2bf(acc[nt][r]);
            }
        __syncthreads();
        int head = h0 + (tid >> 7), d = tid & 127;
        size_t rowb = (((size_t)(b * 8 + head) * 32 + (s0 >> 6)) * 128 + d) * 128;
        #pragma unroll
        for (int j = 0; j < 8; ++j){
            uint4 v = *(const uint4*)(bb + tid * 128 + ((j * 16) ^ ((tid & 7) << 4)));
            *(uint4*)(Vimg + rowb + ((j * 16) ^ ((d & 7) << 4))) = v;
        }
    }
}

// ---------------- K-split flash attention (R19 inner loop) with rank-ordered
// block permutation: slots taken in descending-niters order so all 16-iter
// blocks land on distinct CUs first; short slots become co-residents.
__global__ __launch_bounds__(256, 2) void attn2_kernel(const unsigned short* __restrict__ qb,
                                                       const char* __restrict__ Kimg,
                                                       const char* __restrict__ Vimg,
                                                       unsigned short* __restrict__ ybf,
                                                       unsigned short* __restrict__ pab,
                                                       float* __restrict__ pl){
    __shared__ uint4 smem4[81920 / 16];
    char* smem = (char*)smem4;
    int tid = threadIdx.x;
    int w = tid >> 6, lane = tid & 63, l4 = lane >> 4, lm = lane & 15;
    int i = blockIdx.x;
    // rank-ordered remap: rank 0..23 -> slot by descending niters
    // iters per slot: s0-7:16, s8..15: 16,14,12,10,8,6,4,2, s16..23: 16,14,12,10,8,6,4,2
    int xg = i & 7;
    int pairbit = (i >> 3) & 1;
    int rank = i >> 4;             // 0..23, ranks 0-15 dispatched first
    int bh = 2 * xg + pairbit;
    int slot;
    if (rank < 9)       slot = rank;        // 16-iter slots 0..8
    else if (rank == 9) slot = 16;          // 16-iter slot 16
    else {
        int rr = rank - 10;
        int q = rr >> 1;
        slot = (rr & 1) ? (17 + q) : (9 + q);  // 14,14,12,12,10,10,8,8,6,6,4,4,2,2
    }
    int grp = slot >> 3, g = slot & 7;
    int J, t0, niters, direct, slice;
    if (grp == 0){ J = 8 + g;  t0 = 0;  niters = 16;         direct = 0; slice = (bh * 8 + g) * 2; }
    else if (grp == 1){ J = 15 - g; t0 = 16; niters = 2 * J - 14; direct = 0; slice = (bh * 8 + (J - 8)) * 2 + 1; }
    else { J = 7 - g;  t0 = 0;  niters = 2 * J + 2;  direct = 1; slice = 0; }
    int b = bh >> 3, h = bh & 7;
    int qrow0w = 128 * J + 32 * w;
    int wqmax = qrow0w + 31;

    bf16x8 qf[2][4];
    #pragma unroll
    for (int f = 0; f < 2; ++f){
        const unsigned short* qg = qb + ((size_t)bh * Sn + qrow0w + 16 * f + lm) * HDn;
        #pragma unroll
        for (int df = 0; df < 4; ++df)
            qf[f][df] = *(const bf16x8*)(qg + df * 32 + l4 * 8);
    }
    f32x4 acc[2][8];
    #pragma unroll
    for (int f = 0; f < 2; ++f)
        #pragma unroll
        for (int dg = 0; dg < 8; ++dg) acc[f][dg] = (f32x4){0.f,0.f,0.f,0.f};
    float lp[2][4];
    #pragma unroll
    for (int f = 0; f < 2; ++f)
        #pragma unroll
        for (int r = 0; r < 4; ++r) lp[f][r] = 0.f;

    const float OFF = 11.541560327111708f;   // 8 * log2(e)
    size_t imgbase = (size_t)bh * 32 * 16384;

    #define STAGE_DMA(T, BUFB) { size_t tb = imgbase + (size_t)(T) * 16384; \
        _Pragma("unroll") for (int i2 = 0; i2 < 4; ++i2){ \
            gld16(Kimg + tb + i2 * 4096 + tid * 16, smem + (BUFB) + i2 * 4096 + tid * 16); \
            gld16(Vimg + tb + i2 * 4096 + tid * 16, smem + (BUFB) + 16384 + i2 * 4096 + tid * 16); } }

    STAGE_DMA(t0, 0);
    __syncthreads();

    for (int it = 0; it < niters; ++it){
        int t = t0 + it;
        int bsel = (it & 1) << 15;
        if (it + 1 < niters)
            STAGE_DMA(t + 1, bsel ^ 32768);
        if (64 * t <= wqmax){
            char* KL = smem + bsel;
            char* VL = smem + bsel + 16384;
            char* pb = smem + 65536 + (w << 12);
            __builtin_amdgcn_s_setprio(1);
            f32x4 sf[2][4];
            #pragma unroll
            for (int kc = 0; kc < 4; ++kc){ sf[0][kc] = (f32x4){0.f,0.f,0.f,0.f}; sf[1][kc] = (f32x4){0.f,0.f,0.f,0.f}; }
            #pragma unroll
            for (int kc = 0; kc < 4; ++kc){
                int krow = 16 * kc + lm;
                int ksw = (krow & 7) << 4;
                #pragma unroll
                for (int df = 0; df < 4; ++df){
                    bf16x8 kf = *(const bf16x8*)(KL + krow * 256 + ((df * 64 + l4 * 16) ^ ksw));
                    sf[0][kc] = __builtin_amdgcn_mfma_f32_16x16x32_bf16(qf[0][df], kf, sf[0][kc], 0, 0, 0);
                    sf[1][kc] = __builtin_amdgcn_mfma_f32_16x16x32_bf16(qf[1][df], kf, sf[1][kc], 0, 0, 0);
                }
            }
            bool needmask = (64 * t + 63 > qrow0w);
            #pragma unroll
            for (int f = 0; f < 2; ++f){
                #pragma unroll
                for (int r = 0; r < 4; ++r){
                    float s0v = sf[f][0][r], s1v = sf[f][1][r],
                          s2v = sf[f][2][r], s3v = sf[f][3][r];
                    if (needmask){
                        int qr = qrow0w + 16 * f + 4 * l4 + r;
                        int j0k = 64 * t + 4 * lm;
                        s0v = (j0k     > qr) ? -1e30f : s0v;
                        s1v = (j0k + 1 > qr) ? -1e30f : s1v;
                        s2v = (j0k + 2 > qr) ? -1e30f : s2v;
                        s3v = (j0k + 3 > qr) ? -1e30f : s3v;
                    }
                    float p0 = vexp2(s0v - OFF), p1 = vexp2(s1v - OFF),
                          p2 = vexp2(s2v - OFF), p3 = vexp2(s3v - OFF);
                    lp[f][r] += p0 + p1 + p2 + p3;
                    int prow = 16 * f + 4 * l4 + r;
                    uint2 pkd = {pk2(p0, p1), pk2(p2, p3)};
                    *(uint2*)(pb + prow * 128 + ((lm * 8) ^ ((prow & 7) << 4))) = pkd;
                }
            }
            #pragma unroll
            for (int ks = 0; ks < 2; ++ks){
                int pcol = (ks * 64 + l4 * 16) ^ ((lm & 7) << 4);
                bf16x8 pa0 = *(const bf16x8*)(pb + lm * 128 + pcol);
                bf16x8 pa1 = *(const bf16x8*)(pb + (16 + lm) * 128 + pcol);
                #pragma unroll
                for (int dg = 0; dg < 8; ++dg){
                    int vrow = 16 * dg + lm;
                    bf16x8 vf = *(const bf16x8*)(VL + vrow * 128 + ((ks * 64 + l4 * 16) ^ ((vrow & 7) << 4)));
                    acc[0][dg] = __builtin_amdgcn_mfma_f32_16x16x32_bf16(pa0, vf, acc[0][dg], 0, 0, 0);
                    acc[1][dg] = __builtin_amdgcn_mfma_f32_16x16x32_bf16(pa1, vf, acc[1][dg], 0, 0, 0);
                }
            }
            __builtin_amdgcn_s_setprio(0);
        }
        __syncthreads();
    }
    #undef STAGE_DMA
    float lsum[2][4];
    #pragma unroll
    for (int f = 0; f < 2; ++f)
        #pragma unroll
        for (int r = 0; r < 4; ++r){
            float l_ = lp[f][r];
            l_ += __shfl_xor(l_, 1);
            l_ += __shfl_xor(l_, 2);
            l_ += __shfl_xor(l_, 4);
            l_ += __shfl_xor(l_, 8);
            lsum[f][r] = l_;
        }
    if (direct){
        #pragma unroll
        for (int f = 0; f < 2; ++f)
            #pragma unroll
            for (int r = 0; r < 4; ++r){
                float inv = 1.f / lsum[f][r];
                int row = qrow0w + 16 * f + 4 * l4 + r;
                unsigned short* yr = ybf + ((size_t)b * Sn + row) * Dn + h * HDn;
                #pragma unroll
                for (int dg = 0; dg < 8; ++dg)
                    yr[16 * dg + lm] = f2bf(acc[f][dg][r] * inv);
            }
    } else {
        unsigned short* pa_ = pab + (size_t)slice * 16384;
        #pragma unroll
        for (int f = 0; f < 2; ++f)
            #pragma unroll
            for (int r = 0; r < 4; ++r){
                int row = 32 * w + 16 * f + 4 * l4 + r;
                #pragma unroll
                for (int dg = 0; dg < 8; ++dg)
                    pa_[row * 128 + 16 * dg + lm] = f2bf(acc[f][dg][r]);
                if (lm == 0)
                    pl[slice * 128 + row] = lsum[f][r];
            }
    }
}

extern "C" void kernel_launch(void* const* d_in, const int* in_sizes, int n_in,
                              void* d_out, int out_size, void* d_ws, size_t ws_size,
                              hipStream_t stream){
    const float* x      = (const float*)d_in[0];
    const float* A      = (const float*)d_in[1];
    const float* Bm     = (const float*)d_in[2];
    const float* C_q    = (const float*)d_in[3];
    const float* C_k    = (const float*)d_in[4];
    const float* C_v    = (const float*)d_in[5];
    const float* C_o    = (const float*)d_in[6];
    const float* C_fc   = (const float*)d_in[7];
    const float* C_proj = (const float*)d_in[8];
    const float* scale1 = (const float*)d_in[9];
    const float* scale2 = (const float*)d_in[10];
    float* out = (float*)d_out;

    char* ws = (char*)d_ws;
    size_t off = 0;
    auto alloc = [&](size_t bytes)->char*{ char* p = ws + off; off += (bytes + 255) & ~(size_t)255; return p; };
    unsigned short* qb   = (unsigned short*)alloc((size_t)Mn * Dn * 2);   // 8MB
    char*           Kimg = alloc((size_t)16 * 32 * 16384);                // 8MB
    char*           Vimg = alloc((size_t)16 * 32 * 16384);                // 8MB
    unsigned short* ybf  = (unsigned short*)alloc((size_t)Mn * Dn * 2);   // 8MB
    unsigned short* pab  = (unsigned short*)alloc((size_t)256 * 16384 * 2); // 8MB
    float*          pl   = (float*)alloc((size_t)256 * 128 * 4);          // 128KB
    unsigned short* tpA  = (unsigned short*)alloc(4 * TSTRIDE * 2);       // 2MB (bf16)
    unsigned short* tpB  = (unsigned short*)alloc(4 * TSTRIDE * 2);       // 2MB (bf16)
    unsigned short* x1b  = (unsigned short*)alloc((size_t)Mn * Dn * 2);   // 8MB (bf16 x1)
    float*          sspA = (float*)alloc(4 * (size_t)Mn * 4);             // 64KB
    float*          sspB = (float*)alloc(4 * (size_t)Mn * 4);             // 64KB
    char*           AtI1c = alloc(131072);
    char*           AtI0c = alloc(131072);
    char*           AtI2u = alloc(131072);
    char*           AtI0u = alloc(131072);
    char*           BIq   = alloc(131072);
    char*           BIk   = alloc(131072);
    char*           BIv   = alloc(131072);
    char*           BIo   = alloc(131072);
    char*           BIfc  = alloc(131072);
    char*           BIpr  = alloc(131072);
    float2*         rt    = (float2*)alloc((size_t)Sn * 64 * 8);          // 1MB

    prep_g<<<3072, 256, 0, stream>>>(A, Bm, C_q, C_k, C_v, C_o, C_fc, C_proj,
                                     scale1, scale2,
                                     AtI1c, AtI0c, AtI2u, AtI0u,
                                     BIq, BIk, BIv, BIo, BIfc, BIpr, rt);
    // t1 partials = x @ At1 (s1 folded), ss = rowwise sumsq(x)
    down_g<<<dim3(Mn / 64, 4), 256, 0, stream>>>(x, AtI1c, tpA, sspA);
    // q (scaled+roped), K-image, V-image — SPLIT across z (768 blocks)
    qkv_g<<<dim3(Mn / 64, 4, 3), 256, 0, stream>>>(tpA, sspA, BIq, BIk, BIv, rt, qb, Kimg, Vimg);
    // attention (direct y for j<8; bf16 partials for j>=8)
    attn2_kernel<<<384, 256, 0, stream>>>(qb, Kimg, Vimg, ybf, pab, pl);
    // t2 partials = y @ At0 with slice-combine fused into staging
    downy_g<<<dim3(Mn / 64, 4), 256, 0, stream>>>(ybf, pab, pl, AtI0c, tpA);
    // FUSED: x1 = x + t2@Bto -> x1b (bf16); sumsq(x1) -> sspB; t3 = x1@At2 -> tpB
    updown_g<0, 1, 1, 1, 0><<<dim3(Mn / 32, 4), 256, 0, stream>>>(
        tpA, nullptr, BIo, AtI2u, x, x1b, tpB, sspB);
    // FUSED: m = silu(rms(t3)@Btfc) (never stored); t4 = m@At0 -> tpA
    updown_g<1, 0, 0, 0, 1><<<dim3(Mn / 32, 4), 256, 0, stream>>>(
        tpB, sspB, BIfc, AtI0u, nullptr, nullptr, tpA, nullptr);
    // out = x1b + t4 @ Btpr  (bf16 base, f32 out)
    up_g<0, 1, 0, 0, 1><<<dim3(Mn / 32, 4), 256, 0, stream>>>(tpA, nullptr, BIpr, x1b, out);
}

// Round 25
// 92.997 us; speedup vs baseline: 1.5808x; 1.0248x over previous
//
#include <hip/hip_runtime.h>

// HolographicBlock: B=2, S=2048, D=1024, R=64, H=8, HD=128
// Pre-swizzled weight images + global_load_lds everywhere; bf16 t-partials;
// qkv z-split; bf16 residual carrier x1b.
// Attention = R19 + R25 complementary-pair block permutation:
// pairs (16+2),(14+4),(12+6),(10+8) on CUs 0-127, 16-iter singles on 128-255.

#define Bn 2
#define Sn 2048
#define Dn 1024
#define Rn 64
#define Hn 8
#define HDn 128
#define Mn (Bn*Sn)   // 4096 rows
#define TSTRIDE ((size_t)Mn * Rn)

typedef __bf16 bf16x8 __attribute__((ext_vector_type(8)));
typedef float f32x4 __attribute__((ext_vector_type(4)));
typedef __attribute__((address_space(1))) const unsigned int g_u32;
typedef __attribute__((address_space(3))) unsigned int l_u32;

__device__ __forceinline__ float bf2f(unsigned short u){
    union { unsigned int i; float f; } x; x.i = ((unsigned int)u) << 16; return x.f;
}
__device__ __forceinline__ unsigned short f2bf(float f){
    union { float f; unsigned int i; } x; x.f = f;
    unsigned int r = x.i + 0x7fffu + ((x.i >> 16) & 1u);
    return (unsigned short)(r >> 16);
}
__device__ __forceinline__ unsigned int pk2(float a, float b){
    unsigned int r;
    asm("v_cvt_pk_bf16_f32 %0, %1, %2" : "=v"(r) : "v"(a), "v"(b));
    return r;
}
__device__ __forceinline__ float vexp2(float x){
    float r;
    asm("v_exp_f32 %0, %1" : "=v"(r) : "v"(x));
    return r;
}
__device__ __forceinline__ void gld16(const void* g, void* l){
    __builtin_amdgcn_global_load_lds((g_u32*)g, (l_u32*)l, 16, 0, 0);
}
__device__ __forceinline__ void dma32k(const char* src, char* dst, int tid){
    #pragma unroll
    for (int p = 0; p < 8; ++p)
        gld16(src + p * 4096 + tid * 16, dst + p * 4096 + tid * 16);
}
__device__ __forceinline__ float bflo(unsigned int u){
    union { unsigned int i; float f; } x; x.i = u << 16; return x.f;
}
__device__ __forceinline__ float bfhi(unsigned int u){
    union { unsigned int i; float f; } x; x.i = u & 0xffff0000u; return x.f;
}
__device__ __forceinline__ uint4 comb8(uint4 A, uint4 C, float Wc){
    uint4 r;
    unsigned int* a = (unsigned int*)&A;
    unsigned int* c = (unsigned int*)&C;
    unsigned int* o = (unsigned int*)&r;
    #pragma unroll
    for (int e = 0; e < 4; ++e){
        float lo = (bflo(a[e]) + bflo(c[e])) * Wc;
        float hi = (bfhi(a[e]) + bfhi(c[e])) * Wc;
        o[e] = pk2(lo, hi);
    }
    return r;
}

// ---------------- prep: PRE-SWIZZLED weight images + rope table
__global__ __launch_bounds__(256) void prep_g(const float* __restrict__ A,
                                              const float* __restrict__ Bsrc,
                                              const float* __restrict__ Cq, const float* __restrict__ Ck,
                                              const float* __restrict__ Cv, const float* __restrict__ Co,
                                              const float* __restrict__ Cfc, const float* __restrict__ Cpr,
                                              const float* __restrict__ s1, const float* __restrict__ s2,
                                              char* __restrict__ AtI1c, char* __restrict__ AtI0c,
                                              char* __restrict__ AtI2u, char* __restrict__ AtI0u,
                                              char* __restrict__ BIq, char* __restrict__ BIk,
                                              char* __restrict__ BIv, char* __restrict__ BIo,
                                              char* __restrict__ BIfc, char* __restrict__ BIpr,
                                              float2* __restrict__ rt){
    int idx = blockIdx.x * 256 + threadIdx.x;
    if (idx < 4 * 65536){
        int v = idx >> 16, e = idx & 65535;
        int r = e & 63, d = e >> 6;
        float sc = (v == 0) ? s1[d] : (v == 2) ? s2[d] : 1.f;
        unsigned short val = f2bf(A[d * 64 + r] * sc);
        if (v < 2){
            int us = (d >> 6) * 4096 + r * 64 + (((((d >> 3) & 7) << 4) ^ ((r & 7) << 4)) >> 1) + (d & 7);
            ((unsigned short*)(v == 0 ? AtI1c : AtI0c))[us] = val;
        } else {
            int us = (d >> 8) * 16384 + r * 256 + (((((d >> 3) & 31) << 4) ^ ((r & 7) << 4)) >> 1) + (d & 7);
            ((unsigned short*)(v == 2 ? AtI2u : AtI0u))[us] = val;
        }
    } else if (idx < 10 * 65536){
        int v = (idx >> 16) - 4, e = idx & 65535;
        int d = e & 1023, r = e >> 10;
        const float* C = v==0?Cq : v==1?Ck : v==2?Cv : v==3?Co : v==4?Cfc : Cpr;
        float extra = (v == 0) ? (0.08838834764831845f * 1.4426950408889634f) : 1.f;
        unsigned short val = f2bf(Bsrc[r * 1024 + d] * C[r] * extra);
        int us = (d >> 8) * 16384 + (d & 255) * 64 + ((((r >> 3) << 4) ^ ((d & 7) << 4)) >> 1) + (r & 7);
        ((unsigned short*)(v==0?BIq : v==1?BIk : v==2?BIv : v==3?BIo : v==4?BIfc : BIpr))[us] = val;
    } else if (idx < 10 * 65536 + Sn * 64){
        int e = idx - 10 * 65536;
        int s = e >> 6, f = e & 63;
        float inv = exp2f(-(float)f * (13.287712379549449f / 64.0f));
        float fr = (float)s * inv;
        float sn, cs; sincosf(fr, &sn, &cs);
        rt[e] = make_float2(cs, sn);
    }
}

// ---------------- down GEMM (f32 input + sumsq): DMA At image, bf16 t-partials out
__global__ __launch_bounds__(256) void down_g(const float* __restrict__ inp,
                                              const char* __restrict__ AtImg,
                                              unsigned short* __restrict__ tpart,
                                              float* __restrict__ sspart){
    __shared__ char xt[32768];
    __shared__ char at[32768];
    int tid = threadIdx.x;
    int m0 = blockIdx.x * 64, sp = blockIdx.y;
    int row = tid >> 2, q4 = tid & 3;
    int w = tid >> 6, lane = tid & 63, l4 = lane >> 4, lm = lane & 15;
    int swz = (row & 7) << 4;
    dma32k(AtImg + (size_t)sp * 32768, at, tid);
    float ss = 0.f;
    f32x4 acc[4];
    #pragma unroll
    for (int nt = 0; nt < 4; ++nt) acc[nt] = (f32x4){0.f,0.f,0.f,0.f};

    float4 xr[4];
    #define LOADX(c) { int k0 = sp * 256 + (c) * 64; \
        const float4* s = (const float4*)(inp + (size_t)(m0+row)*1024 + k0 + q4*16); \
        xr[0]=s[0]; xr[1]=s[1]; xr[2]=s[2]; xr[3]=s[3]; }

    LOADX(0);
    for (int c = 0; c < 4; ++c){
        char* xc = xt + c * 8192;
        #pragma unroll
        for (int i = 0; i < 4; ++i)
            ss += xr[i].x*xr[i].x + xr[i].y*xr[i].y + xr[i].z*xr[i].z + xr[i].w*xr[i].w;
        uint4 p0 = {pk2(xr[0].x,xr[0].y), pk2(xr[0].z,xr[0].w), pk2(xr[1].x,xr[1].y), pk2(xr[1].z,xr[1].w)};
        uint4 p1 = {pk2(xr[2].x,xr[2].y), pk2(xr[2].z,xr[2].w), pk2(xr[3].x,xr[3].y), pk2(xr[3].z,xr[3].w)};
        *(uint4*)(xc + row * 128 + ((q4 * 32) ^ swz)) = p0;
        *(uint4*)(xc + row * 128 + ((q4 * 32 + 16) ^ swz)) = p1;
        __syncthreads();            // c==0 also drains the At DMA
        if (c < 3) LOADX(c + 1);
        #pragma unroll
        for (int ks = 0; ks < 2; ++ks){
            int arow = 16 * w + lm;
            bf16x8 af = *(const bf16x8*)(xc + arow * 128 + ((ks*64 + l4*16) ^ ((arow & 7) << 4)));
            #pragma unroll
            for (int nt = 0; nt < 4; ++nt){
                int brow = nt * 16 + lm;
                bf16x8 bf = *(const bf16x8*)(at + c * 8192 + brow * 128 + ((ks*64 + l4*16) ^ ((brow & 7) << 4)));
                acc[nt] = __builtin_amdgcn_mfma_f32_16x16x32_bf16(af, bf, acc[nt], 0, 0, 0);
            }
        }
    }
    #undef LOADX
    ss += __shfl_xor(ss, 1); ss += __shfl_xor(ss, 2);
    if (q4 == 0) sspart[sp * Mn + m0 + row] = ss;
    #pragma unroll
    for (int nt = 0; nt < 4; ++nt)
        #pragma unroll
        for (int r = 0; r < 4; ++r){
            int ml = 16 * w + 4 * l4 + r;
            tpart[(size_t)sp * TSTRIDE + (size_t)(m0 + ml) * 64 + nt * 16 + lm] = f2bf(acc[nt][r]);
        }
}

// ---------------- down GEMM for y (fused slice-combine), bf16 t-partials out
__global__ __launch_bounds__(256) void downy_g(const unsigned short* __restrict__ ybf,
                                               const unsigned short* __restrict__ pab,
                                               const float* __restrict__ pl,
                                               const char* __restrict__ AtImg,
                                               unsigned short* __restrict__ tpart){
    __shared__ char xt[32768];
    __shared__ char at[32768];
    int tid = threadIdx.x;
    int m0 = blockIdx.x * 64, sp = blockIdx.y;
    int row = tid >> 2, q4 = tid & 3;
    int w = tid >> 6, lane = tid & 63, l4 = lane >> 4, lm = lane & 15;
    int swz = (row & 7) << 4;
    int jq = (m0 & (Sn - 1)) >> 7;
    int bpos = m0 >> 11;
    int srow = (m0 & 127) + row;
    dma32k(AtImg + (size_t)sp * 32768, at, tid);
    f32x4 acc[4];
    #pragma unroll
    for (int nt = 0; nt < 4; ++nt) acc[nt] = (f32x4){0.f,0.f,0.f,0.f};

    #define MFMAC(c) { \
        _Pragma("unroll") \
        for (int ks = 0; ks < 2; ++ks){ \
            int arow = 16 * w + lm; \
            bf16x8 af = *(const bf16x8*)(xt + (c) * 8192 + arow * 128 + ((ks*64 + l4*16) ^ ((arow & 7) << 4))); \
            _Pragma("unroll") \
            for (int nt = 0; nt < 4; ++nt){ \
                int brow = nt * 16 + lm; \
                bf16x8 bf = *(const bf16x8*)(at + (c) * 8192 + brow * 128 + ((ks*64 + l4*16) ^ ((brow & 7) << 4))); \
                acc[nt] = __builtin_amdgcn_mfma_f32_16x16x32_bf16(af, bf, acc[nt], 0, 0, 0); \
            } \
        } }

    if (jq < 8){
        const char* yb = (const char*)ybf;
        #pragma unroll
        for (int p = 0; p < 8; ++p){
            int c = p >> 1;
            int rw = (p & 1) * 32 + (tid >> 3);
            int gp = (tid & 7) ^ (rw & 7);
            gld16(yb + (size_t)(m0 + rw) * 2048 + sp * 512 + c * 128 + gp * 16,
                  xt + p * 4096 + tid * 16);
        }
        __syncthreads();
        for (int c = 0; c < 4; ++c) MFMAC(c);
    } else {
        uint4 xrb[2];
        #define LOADCMB(c) { int k0 = sp * 256 + (c) * 64; \
            int h = k0 >> 7; int d0 = k0 & 127; \
            int s0sl = (((bpos * 8 + h) * 8) + (jq - 8)) * 2; \
            const unsigned short* p0 = pab + (size_t)s0sl * 16384 + srow * 128 + d0 + q4 * 16; \
            const unsigned short* p1 = p0 + 16384; \
            float Wc = 1.f / (pl[s0sl * 128 + srow] + pl[(s0sl + 1) * 128 + srow]); \
            uint4 A0 = ((const uint4*)p0)[0], A1 = ((const uint4*)p0)[1]; \
            uint4 C0 = ((const uint4*)p1)[0], C1 = ((const uint4*)p1)[1]; \
            xrb[0] = comb8(A0, C0, Wc); xrb[1] = comb8(A1, C1, Wc); }
        LOADCMB(0);
        for (int c = 0; c < 4; ++c){
            char* xc = xt + c * 8192;
            *(uint4*)(xc + row * 128 + ((q4 * 32) ^ swz)) = xrb[0];
            *(uint4*)(xc + row * 128 + ((q4 * 32 + 16) ^ swz)) = xrb[1];
            __syncthreads();
            if (c < 3) LOADCMB(c + 1);
            MFMAC(c);
        }
        #undef LOADCMB
    }
    #undef MFMAC
    #pragma unroll
    for (int nt = 0; nt < 4; ++nt)
        #pragma unroll
        for (int r = 0; r < 4; ++r){
            int ml = 16 * w + 4 * l4 + r;
            tpart[(size_t)sp * TSTRIDE + (size_t)(m0 + ml) * 64 + nt * 16 + lm] = f2bf(acc[nt][r]);
        }
}

// ---------------- stage t tile (sum 4 bf16 K-split partials, optional rms) into swizzled LDS
template<int DORMS>
__device__ __forceinline__ void stage_t(char* tt, const unsigned short* __restrict__ tpart,
                                        const float* __restrict__ sspart, int m0, int tid){
    int row = tid >> 2, q4 = tid & 3;
    const unsigned short* bp = tpart + (size_t)(m0 + row) * 64 + q4 * 16;
    float s[16];
    #pragma unroll
    for (int half = 0; half < 2; ++half){
        uint4 u0 = ((const uint4*)(bp + 0 * TSTRIDE))[half];
        uint4 u1 = ((const uint4*)(bp + 1 * TSTRIDE))[half];
        uint4 u2 = ((const uint4*)(bp + 2 * TSTRIDE))[half];
        uint4 u3 = ((const uint4*)(bp + 3 * TSTRIDE))[half];
        const unsigned int* a0 = (const unsigned int*)&u0;
        const unsigned int* a1 = (const unsigned int*)&u1;
        const unsigned int* a2 = (const unsigned int*)&u2;
        const unsigned int* a3 = (const unsigned int*)&u3;
        #pragma unroll
        for (int e = 0; e < 4; ++e){
            s[half*8 + 2*e]     = bflo(a0[e]) + bflo(a1[e]) + bflo(a2[e]) + bflo(a3[e]);
            s[half*8 + 2*e + 1] = bfhi(a0[e]) + bfhi(a1[e]) + bfhi(a2[e]) + bfhi(a3[e]);
        }
    }
    float rr = 1.f;
    if (DORMS){
        int m = m0 + row;
        float ssum = sspart[m] + sspart[Mn + m] + sspart[2*Mn + m] + sspart[3*Mn + m];
        rr = rsqrtf(ssum * (1.f / 1024.f) + 1.1920929e-07f);
    }
    #pragma unroll
    for (int i = 0; i < 16; ++i) s[i] *= rr;
    int swz = (row & 7) << 4;
    uint4 p0 = {pk2(s[0],s[1]), pk2(s[2],s[3]), pk2(s[4],s[5]), pk2(s[6],s[7])};
    uint4 p1 = {pk2(s[8],s[9]), pk2(s[10],s[11]), pk2(s[12],s[13]), pk2(s[14],s[15])};
    *(uint4*)(tt + row * 128 + ((q4 * 32) ^ swz)) = p0;
    *(uint4*)(tt + row * 128 + ((q4 * 32 + 16) ^ swz)) = p1;
}

// ---------------- up GEMM (final projection): DMA Bt image; base optionally bf16
template<int SILU, int HASBASE, int OUT_BF16, int DORMS, int BASEBF16>
__global__ __launch_bounds__(256) void up_g(const unsigned short* __restrict__ tpart,
                                            const float* __restrict__ sspart,
                                            const char* __restrict__ BtImg,
                                            const void* base,
                                            void* __restrict__ outp){
    __shared__ char tt[4096];
    __shared__ char bb[32768];
    int tid = threadIdx.x;
    int m0 = blockIdx.x * 32, n0 = blockIdx.y * 256;
    int w = tid >> 6, lane = tid & 63, l4 = lane >> 4, lm = lane & 15;
    int wm = w & 1, wn = w >> 1;
    dma32k(BtImg + (size_t)blockIdx.y * 32768, bb, tid);
    if (tid < 128) stage_t<DORMS>(tt, tpart, sspart, m0, tid);
    __syncthreads();
    bf16x8 af[2];
    #pragma unroll
    for (int ks = 0; ks < 2; ++ks){
        int arow = 16 * wm + lm;
        af[ks] = *(const bf16x8*)(tt + arow * 128 + ((ks*64 + l4*16) ^ ((arow & 7) << 4)));
    }
    f32x4 acc[8];
    #pragma unroll
    for (int nt = 0; nt < 8; ++nt) acc[nt] = (f32x4){0.f,0.f,0.f,0.f};
    #pragma unroll
    for (int nt = 0; nt < 8; ++nt){
        int brow = wn * 128 + nt * 16 + lm;
        #pragma unroll
        for (int ks = 0; ks < 2; ++ks){
            bf16x8 bf = *(const bf16x8*)(bb + brow * 128 + ((ks*64 + l4*16) ^ ((brow & 7) << 4)));
            acc[nt] = __builtin_amdgcn_mfma_f32_16x16x32_bf16(af[ks], bf, acc[nt], 0, 0, 0);
        }
    }
    #pragma unroll
    for (int nt = 0; nt < 8; ++nt)
        #pragma unroll
        for (int r = 0; r < 4; ++r){
            int m = m0 + 16 * wm + 4 * l4 + r;
            int n = n0 + wn * 128 + nt * 16 + lm;
            float v = acc[nt][r];
            if (SILU) v = v / (1.f + __expf(-v));
            if (HASBASE){
                if (BASEBF16) v += bf2f(((const unsigned short*)base)[(size_t)m * 1024 + n]);
                else          v += ((const float*)base)[(size_t)m * 1024 + n];
            }
            if (OUT_BF16) ((unsigned short*)outp)[(size_t)m * 1024 + n] = f2bf(v);
            else          ((float*)outp)[(size_t)m * 1024 + n] = v;
        }
}

// ---------------- FUSED up->down: DMA BtU image, DMA AtD ud-image; bf16 tpout;
// STOREOUT stores x1 as bf16 to x1out
template<int SILU, int HASBASE, int STOREOUT, int SUMSQ, int DORMS_IN>
__global__ __launch_bounds__(256) void updown_g(const unsigned short* __restrict__ tpin,
                                                const float* __restrict__ sspin,
                                                const char* __restrict__ BtUimg,
                                                const char* __restrict__ AtDimg,
                                                const float* base,
                                                unsigned short* x1out,
                                                unsigned short* __restrict__ tpout,
                                                float* __restrict__ sspout){
    __shared__ char tt[4096];
    __shared__ char bb[32768];     // BtU image, later AtD image
    __shared__ char xb[16384];     // bounced up-output tile [32][256] bf16
    __shared__ float ssl[2][32];
    int tid = threadIdx.x;
    int m0 = blockIdx.x * 32, n0 = blockIdx.y * 256, sp = blockIdx.y;
    int w = tid >> 6, lane = tid & 63, l4 = lane >> 4, lm = lane & 15;
    int wm = w & 1, wn = w >> 1;
    dma32k(BtUimg + (size_t)sp * 32768, bb, tid);
    if (tid < 128) stage_t<DORMS_IN>(tt, tpin, sspin, m0, tid);
    __syncthreads();
    // ---- up MFMA
    bf16x8 af[2];
    #pragma unroll
    for (int ks = 0; ks < 2; ++ks){
        int arow = 16 * wm + lm;
        af[ks] = *(const bf16x8*)(tt + arow * 128 + ((ks*64 + l4*16) ^ ((arow & 7) << 4)));
    }
    f32x4 acc[8];
    #pragma unroll
    for (int nt = 0; nt < 8; ++nt) acc[nt] = (f32x4){0.f,0.f,0.f,0.f};
    #pragma unroll
    for (int nt = 0; nt < 8; ++nt){
        int brow = wn * 128 + nt * 16 + lm;
        #pragma unroll
        for (int ks = 0; ks < 2; ++ks){
            bf16x8 bf = *(const bf16x8*)(bb + brow * 128 + ((ks*64 + l4*16) ^ ((brow & 7) << 4)));
            acc[nt] = __builtin_amdgcn_mfma_f32_16x16x32_bf16(af[ks], bf, acc[nt], 0, 0, 0);
        }
    }
    // ---- epilogue
    float val[8][4];
    float sq[4] = {0.f, 0.f, 0.f, 0.f};
    #pragma unroll
    for (int nt = 0; nt < 8; ++nt)
        #pragma unroll
        for (int r = 0; r < 4; ++r){
            int m = m0 + 16 * wm + 4 * l4 + r;
            int n = n0 + wn * 128 + nt * 16 + lm;
            float v = acc[nt][r];
            if (SILU) v = v / (1.f + __expf(-v));
            if (HASBASE) v += base[(size_t)m * 1024 + n];
            val[nt][r] = v;
            if (STOREOUT) x1out[(size_t)m * 1024 + n] = f2bf(v);
            if (SUMSQ) sq[r] += v * v;
        }
    if (SUMSQ){
        #pragma unroll
        for (int r = 0; r < 4; ++r){
            float s_ = sq[r];
            s_ += __shfl_xor(s_, 1);
            s_ += __shfl_xor(s_, 2);
            s_ += __shfl_xor(s_, 4);
            s_ += __shfl_xor(s_, 8);
            if (lm == 0) ssl[wn][16 * wm + 4 * l4 + r] = s_;
        }
    }
    __syncthreads();   // bb reads done, ssl visible
    // ---- DMA AtD ud-image into bb; bounce val -> xb
    dma32k(AtDimg + (size_t)sp * 32768, bb, tid);
    #pragma unroll
    for (int nt = 0; nt < 8; ++nt)
        #pragma unroll
        for (int r = 0; r < 4; ++r){
            int mrow = 16 * wm + 4 * l4 + r;
            int cn = wn * 128 + nt * 16 + lm;
            *(unsigned short*)(xb + mrow * 512 + ((cn * 2) ^ ((mrow & 7) << 4))) = f2bf(val[nt][r]);
        }
    __syncthreads();
    if (SUMSQ && tid < 32)
        sspout[sp * Mn + m0 + tid] = ssl[0][tid] + ssl[1][tid];
    // ---- down MFMA
    f32x4 acc2[2];
    acc2[0] = (f32x4){0.f,0.f,0.f,0.f};
    acc2[1] = (f32x4){0.f,0.f,0.f,0.f};
    #pragma unroll
    for (int kk = 0; kk < 8; ++kk){
        int arow = 16 * (w & 1) + lm;
        bf16x8 a2 = *(const bf16x8*)(xb + arow * 512 + ((kk * 64 + l4 * 16) ^ ((arow & 7) << 4)));
        #pragma unroll
        for (int j = 0; j < 2; ++j){
            int brow = (2 * (w >> 1) + j) * 16 + lm;
            bf16x8 b2 = *(const bf16x8*)(bb + brow * 512 + ((kk * 64 + l4 * 16) ^ ((brow & 7) << 4)));
            acc2[j] = __builtin_amdgcn_mfma_f32_16x16x32_bf16(a2, b2, acc2[j], 0, 0, 0);
        }
    }
    #pragma unroll
    for (int j = 0; j < 2; ++j)
        #pragma unroll
        for (int r = 0; r < 4; ++r){
            int ml = 16 * (w & 1) + 4 * l4 + r;
            int nc = (2 * (w >> 1) + j) * 16 + lm;
            tpout[(size_t)sp * TSTRIDE + (size_t)(m0 + ml) * 64 + nc] = f2bf(acc2[j][r]);
        }
}

// ---------------- fused QKV up-proj + RoPE, SPLIT across blockIdx.z
__global__ __launch_bounds__(256) void qkv_g(const unsigned short* __restrict__ tpart,
                                             const float* __restrict__ sspart,
                                             const char* __restrict__ BIq,
                                             const char* __restrict__ BIk,
                                             const char* __restrict__ BIv,
                                             const float2* __restrict__ rt,
                                             unsigned short* __restrict__ qout,
                                             char* __restrict__ Kimg,
                                             char* __restrict__ Vimg){
    __shared__ char tt[8192];
    __shared__ char bb[32768];
    int tid = threadIdx.x;
    int m0 = blockIdx.x * 64, n0 = blockIdx.y * 256;
    int which = blockIdx.z;
    int b = m0 >> 11, s0 = m0 & (Sn - 1);
    int h0 = n0 >> 7;
    int w = tid >> 6, lane = tid & 63, l4 = lane >> 4, lm = lane & 15;
    const char* BI = (which == 0) ? BIq : (which == 1) ? BIk : BIv;
    dma32k(BI + (size_t)blockIdx.y * 32768, bb, tid);
    stage_t<1>(tt, tpart, sspart, m0, tid);
    __syncthreads();
    bf16x8 af[2];
    #pragma unroll
    for (int ks = 0; ks < 2; ++ks){
        int arow = 16 * w + lm;
        af[ks] = *(const bf16x8*)(tt + arow * 128 + ((ks*64 + l4*16) ^ ((arow & 7) << 4)));
    }
    f32x4 acc[16];
    #pragma unroll
    for (int nt = 0; nt < 16; ++nt) acc[nt] = (f32x4){0.f,0.f,0.f,0.f};
    #pragma unroll
    for (int nt = 0; nt < 16; ++nt){
        int brow = nt * 16 + lm;
        #pragma unroll
        for (int ks = 0; ks < 2; ++ks){
            bf16x8 bf = *(const bf16x8*)(bb + brow * 128 + ((ks*64 + l4*16) ^ ((brow & 7) << 4)));
            acc[nt] = __builtin_amdgcn_mfma_f32_16x16x32_bf16(af[ks], bf, acc[nt], 0, 0, 0);
        }
    }
    if (which < 2){
        float2 cs[4][4];
        #pragma unroll
        for (int ntb = 0; ntb < 4; ++ntb)
            #pragma unroll
            for (int r = 0; r < 4; ++r)
                cs[ntb][r] = rt[(size_t)(s0 + 16*w + 4*l4 + r) * 64 + ntb * 16 + lm];
        #pragma unroll
        for (int g = 0; g < 2; ++g)
            #pragma unroll
            for (int ntb = 0; ntb < 4; ++ntb){
                int lo = g*8 + ntb, hi = lo + 4;
                #pragma unroll
                for (int r = 0; r < 4; ++r){
                    float2 c = cs[ntb][r];
                    float a = acc[lo][r], bq = acc[hi][r];
                    acc[lo][r] = a * c.x + bq * c.y;
                    acc[hi][r] = -a * c.y + bq * c.x;
                }
            }
        __syncthreads();
        #pragma unroll
        for (int nt = 0; nt < 16; ++nt)
            #pragma unroll
            for (int r = 0; r < 4; ++r){
                int nl = nt * 16 + lm, ml2 = 16 * w + 4 * l4 + r;
                *(unsigned short*)(bb + ml2 * 512 + ((nl * 2) ^ ((ml2 & 7) << 4))) = f2bf(acc[nt][r]);
            }
        __syncthreads();
        if (which == 0){
            int ml = tid >> 2, seg = tid & 3;
            int head = h0 + (seg >> 1), hd0q = (seg & 1) * 64;
            size_t dstbase = (((size_t)(b * 8 + head) * Sn + (s0 + ml)) * 128 + hd0q);
            #pragma unroll
            for (int j = 0; j < 8; ++j){
                uint4 v = *(const uint4*)(bb + ml * 512 + ((seg * 128 + j * 16) ^ ((ml & 7) << 4)));
                *(uint4*)(qout + dstbase + j * 8) = v;
            }
        } else {
            int ml = tid >> 2, seg = tid & 3;
            int hd0q = (seg & 1) * 64;
            int head = h0 + (seg >> 1);
            int pr = 16 * (ml & 3) + (ml >> 2);
            size_t rowb = (((size_t)(b * 8 + head) * 32 + (s0 >> 6)) * 64 + pr) * 256;
            #pragma unroll
            for (int j = 0; j < 8; ++j){
                uint4 v = *(const uint4*)(bb + ml * 512 + ((seg * 128 + j * 16) ^ ((ml & 7) << 4)));
                int cb = hd0q * 2 + j * 16;
                *(uint4*)(Kimg + rowb + (cb ^ ((pr & 7) << 4))) = v;
            }
        }
    } else {
        __syncthreads();
        #pragma unroll
        for (int nt = 0; nt < 16; ++nt)
            #pragma unroll
            for (int r = 0; r < 4; ++r){
                int nl = nt * 16 + lm, ml2 = 16 * w + 4 * l4 + r;
                *(unsigned short*)(bb + nl * 128 + ((ml2 * 2) ^ ((nl & 7) << 4))) = f2bf(acc[nt][r]);
            }
        __syncthreads();
        int head = h0 + (tid >> 7), d = tid & 127;
        size_t rowb = (((size_t)(b * 8 + head) * 32 + (s0 >> 6)) * 128 + d) * 128;
        #pragma unroll
        for (int j = 0; j < 8; ++j){
            uint4 v = *(const uint4*)(bb + tid * 128 + ((j * 16) ^ ((tid & 7) << 4)));
            *(uint4*)(Vimg + rowb + ((j * 16) ^ ((d & 7) << 4))) = v;
        }
    }
}

// ---------------- K-split flash attention (R19 inner loop) with complementary-
// pair block permutation: CUs 0-127 host pairs summing to 18 iters
// (16+2, 14+4, 12+6, 10+8); CUs 128-255 host 16-iter singles.
__global__ __launch_bounds__(256, 2) void attn2_kernel(const unsigned short* __restrict__ qb,
                                                       const char* __restrict__ Kimg,
                                                       const char* __restrict__ Vimg,
                                                       unsigned short* __restrict__ ybf,
                                                       unsigned short* __restrict__ pab,
                                                       float* __restrict__ pl){
    __shared__ uint4 smem4[81920 / 16];
    char* smem = (char*)smem4;
    int tid = threadIdx.x;
    int w = tid >> 6, lane = tid & 63, l4 = lane >> 4, lm = lane & 15;
    int o = blockIdx.x;
    // slot inventory per bh: 16-iter: s0..s8,s16 (inst 0..9);
    // 14: s9/s17; 12: s10/s18; 10: s11/s19; 8: s12/s20; 6: s13/s21; 4: s14/s22; 2: s15/s23
    int bh, slot;
    if (o < 128){
        int cat = o >> 5;           // 0:C16, 1:C14, 2:C12, 3:C10 (long pair members)
        int k = o & 31;
        if (cat == 0){ bh = k & 15; slot = (k >> 4); }          // inst 0..1 -> slots 0,1
        else { bh = k >> 1; slot = (k & 1) ? (8 + cat + 8) : (8 + cat); }  // 9/17,10/18,11/19
    } else if (o < 256){
        int k16 = 32 + (o - 128);   // inst 2..9 of 16-iter slots
        bh = k16 & 15;
        int inst = k16 >> 4;
        slot = (inst < 9) ? inst : 16;
    } else {
        int cat = (o - 256) >> 5;   // 0:C2, 1:C4, 2:C6, 3:C8 (short pair members)
        int k = (o - 256) & 31;
        bh = k >> 1;
        int base = 15 - cat;        // 15,14,13,12
        slot = (k & 1) ? (base + 8) : base;
    }
    int grp = slot >> 3, g = slot & 7;
    int J, t0, niters, direct, slice;
    if (grp == 0){ J = 8 + g;  t0 = 0;  niters = 16;         direct = 0; slice = (bh * 8 + g) * 2; }
    else if (grp == 1){ J = 15 - g; t0 = 16; niters = 2 * J - 14; direct = 0; slice = (bh * 8 + (J - 8)) * 2 + 1; }
    else { J = 7 - g;  t0 = 0;  niters = 2 * J + 2;  direct = 1; slice = 0; }
    int b = bh >> 3, h = bh & 7;
    int qrow0w = 128 * J + 32 * w;
    int wqmax = qrow0w + 31;

    bf16x8 qf[2][4];
    #pragma unroll
    for (int f = 0; f < 2; ++f){
        const unsigned short* qg = qb + ((size_t)bh * Sn + qrow0w + 16 * f + lm) * HDn;
        #pragma unroll
        for (int df = 0; df < 4; ++df)
            qf[f][df] = *(const bf16x8*)(qg + df * 32 + l4 * 8);
    }
    f32x4 acc[2][8];
    #pragma unroll
    for (int f = 0; f < 2; ++f)
        #pragma unroll
        for (int dg = 0; dg < 8; ++dg) acc[f][dg] = (f32x4){0.f,0.f,0.f,0.f};
    float lp[2][4];
    #pragma unroll
    for (int f = 0; f < 2; ++f)
        #pragma unroll
        for (int r = 0; r < 4; ++r) lp[f][r] = 0.f;

    const float OFF = 11.541560327111708f;   // 8 * log2(e)
    size_t imgbase = (size_t)bh * 32 * 16384;

    #define STAGE_DMA(T, BUFB) { size_t tb = imgbase + (size_t)(T) * 16384; \
        _Pragma("unroll") for (int i2 = 0; i2 < 4; ++i2){ \
            gld16(Kimg + tb + i2 * 4096 + tid * 16, smem + (BUFB) + i2 * 4096 + tid * 16); \
            gld16(Vimg + tb + i2 * 4096 + tid * 16, smem + (BUFB) + 16384 + i2 * 4096 + tid * 16); } }

    STAGE_DMA(t0, 0);
    __syncthreads();

    for (int it = 0; it < niters; ++it){
        int t = t0 + it;
        int bsel = (it & 1) << 15;
        if (it + 1 < niters)
            STAGE_DMA(t + 1, bsel ^ 32768);
        if (64 * t <= wqmax){
            char* KL = smem + bsel;
            char* VL = smem + bsel + 16384;
            char* pb = smem + 65536 + (w << 12);
            __builtin_amdgcn_s_setprio(1);
            f32x4 sf[2][4];
            #pragma unroll
            for (int kc = 0; kc < 4; ++kc){ sf[0][kc] = (f32x4){0.f,0.f,0.f,0.f}; sf[1][kc] = (f32x4){0.f,0.f,0.f,0.f}; }
            #pragma unroll
            for (int kc = 0; kc < 4; ++kc){
                int krow = 16 * kc + lm;
                int ksw = (krow & 7) << 4;
                #pragma unroll
                for (int df = 0; df < 4; ++df){
                    bf16x8 kf = *(const bf16x8*)(KL + krow * 256 + ((df * 64 + l4 * 16) ^ ksw));
                    sf[0][kc] = __builtin_amdgcn_mfma_f32_16x16x32_bf16(qf[0][df], kf, sf[0][kc], 0, 0, 0);
                    sf[1][kc] = __builtin_amdgcn_mfma_f32_16x16x32_bf16(qf[1][df], kf, sf[1][kc], 0, 0, 0);
                }
            }
            bool needmask = (64 * t + 63 > qrow0w);
            #pragma unroll
            for (int f = 0; f < 2; ++f){
                #pragma unroll
                for (int r = 0; r < 4; ++r){
                    float s0v = sf[f][0][r], s1v = sf[f][1][r],
                          s2v = sf[f][2][r], s3v = sf[f][3][r];
                    if (needmask){
                        int qr = qrow0w + 16 * f + 4 * l4 + r;
                        int j0k = 64 * t + 4 * lm;
                        s0v = (j0k     > qr) ? -1e30f : s0v;
                        s1v = (j0k + 1 > qr) ? -1e30f : s1v;
                        s2v = (j0k + 2 > qr) ? -1e30f : s2v;
                        s3v = (j0k + 3 > qr) ? -1e30f : s3v;
                    }
                    float p0 = vexp2(s0v - OFF), p1 = vexp2(s1v - OFF),
                          p2 = vexp2(s2v - OFF), p3 = vexp2(s3v - OFF);
                    lp[f][r] += p0 + p1 + p2 + p3;
                    int prow = 16 * f + 4 * l4 + r;
                    uint2 pkd = {pk2(p0, p1), pk2(p2, p3)};
                    *(uint2*)(pb + prow * 128 + ((lm * 8) ^ ((prow & 7) << 4))) = pkd;
                }
            }
            #pragma unroll
            for (int ks = 0; ks < 2; ++ks){
                int pcol = (ks * 64 + l4 * 16) ^ ((lm & 7) << 4);
                bf16x8 pa0 = *(const bf16x8*)(pb + lm * 128 + pcol);
                bf16x8 pa1 = *(const bf16x8*)(pb + (16 + lm) * 128 + pcol);
                #pragma unroll
                for (int dg = 0; dg < 8; ++dg){
                    int vrow = 16 * dg + lm;
                    bf16x8 vf = *(const bf16x8*)(VL + vrow * 128 + ((ks * 64 + l4 * 16) ^ ((vrow & 7) << 4)));
                    acc[0][dg] = __builtin_amdgcn_mfma_f32_16x16x32_bf16(pa0, vf, acc[0][dg], 0, 0, 0);
                    acc[1][dg] = __builtin_amdgcn_mfma_f32_16x16x32_bf16(pa1, vf, acc[1][dg], 0, 0, 0);
                }
            }
            __builtin_amdgcn_s_setprio(0);
        }
        __syncthreads();
    }
    #undef STAGE_DMA
    float lsum[2][4];
    #pragma unroll
    for (int f = 0; f < 2; ++f)
        #pragma unroll
        for (int r = 0; r < 4; ++r){
            float l_ = lp[f][r];
            l_ += __shfl_xor(l_, 1);
            l_ += __shfl_xor(l_, 2);
            l_ += __shfl_xor(l_, 4);
            l_ += __shfl_xor(l_, 8);
            lsum[f][r] = l_;
        }
    if (direct){
        #pragma unroll
        for (int f = 0; f < 2; ++f)
            #pragma unroll
            for (int r = 0; r < 4; ++r){
                float inv = 1.f / lsum[f][r];
                int row = qrow0w + 16 * f + 4 * l4 + r;
                unsigned short* yr = ybf + ((size_t)b * Sn + row) * Dn + h * HDn;
                #pragma unroll
                for (int dg = 0; dg < 8; ++dg)
                    yr[16 * dg + lm] = f2bf(acc[f][dg][r] * inv);
            }
    } else {
        unsigned short* pa_ = pab + (size_t)slice * 16384;
        #pragma unroll
        for (int f = 0; f < 2; ++f)
            #pragma unroll
            for (int r = 0; r < 4; ++r){
                int row = 32 * w + 16 * f + 4 * l4 + r;
                #pragma unroll
                for (int dg = 0; dg < 8; ++dg)
                    pa_[row * 128 + 16 * dg + lm] = f2bf(acc[f][dg][r]);
                if (lm == 0)
                    pl[slice * 128 + row] = lsum[f][r];
            }
    }
}

extern "C" void kernel_launch(void* const* d_in, const int* in_sizes, int n_in,
                              void* d_out, int out_size, void* d_ws, size_t ws_size,
                              hipStream_t stream){
    const float* x      = (const float*)d_in[0];
    const float* A      = (const float*)d_in[1];
    const float* Bm     = (const float*)d_in[2];
    const float* C_q    = (const float*)d_in[3];
    const float* C_k    = (const float*)d_in[4];
    const float* C_v    = (const float*)d_in[5];
    const float* C_o    = (const float*)d_in[6];
    const float* C_fc   = (const float*)d_in[7];
    const float* C_proj = (const float*)d_in[8];
    const float* scale1 = (const float*)d_in[9];
    const float* scale2 = (const float*)d_in[10];
    float* out = (float*)d_out;

    char* ws = (char*)d_ws;
    size_t off = 0;
    auto alloc = [&](size_t bytes)->char*{ char* p = ws + off; off += (bytes + 255) & ~(size_t)255; return p; };
    unsigned short* qb   = (unsigned short*)alloc((size_t)Mn * Dn * 2);   // 8MB
    char*           Kimg = alloc((size_t)16 * 32 * 16384);                // 8MB
    char*           Vimg = alloc((size_t)16 * 32 * 16384);                // 8MB
    unsigned short* ybf  = (unsigned short*)alloc((size_t)Mn * Dn * 2);   // 8MB
    unsigned short* pab  = (unsigned short*)alloc((size_t)256 * 16384 * 2); // 8MB
    float*          pl   = (float*)alloc((size_t)256 * 128 * 4);          // 128KB
    unsigned short* tpA  = (unsigned short*)alloc(4 * TSTRIDE * 2);       // 2MB (bf16)
    unsigned short* tpB  = (unsigned short*)alloc(4 * TSTRIDE * 2);       // 2MB (bf16)
    unsigned short* x1b  = (unsigned short*)alloc((size_t)Mn * Dn * 2);   // 8MB (bf16 x1)
    float*          sspA = (float*)alloc(4 * (size_t)Mn * 4);             // 64KB
    float*          sspB = (float*)alloc(4 * (size_t)Mn * 4);             // 64KB
    char*           AtI1c = alloc(131072);
    char*           AtI0c = alloc(131072);
    char*           AtI2u = alloc(131072);
    char*           AtI0u = alloc(131072);
    char*           BIq   = alloc(131072);
    char*           BIk   = alloc(131072);
    char*           BIv   = alloc(131072);
    char*           BIo   = alloc(131072);
    char*           BIfc  = alloc(131072);
    char*           BIpr  = alloc(131072);
    float2*         rt    = (float2*)alloc((size_t)Sn * 64 * 8);          // 1MB

    prep_g<<<3072, 256, 0, stream>>>(A, Bm, C_q, C_k, C_v, C_o, C_fc, C_proj,
                                     scale1, scale2,
                                     AtI1c, AtI0c, AtI2u, AtI0u,
                                     BIq, BIk, BIv, BIo, BIfc, BIpr, rt);
    // t1 partials = x @ At1 (s1 folded), ss = rowwise sumsq(x)
    down_g<<<dim3(Mn / 64, 4), 256, 0, stream>>>(x, AtI1c, tpA, sspA);
    // q (scaled+roped), K-image, V-image — SPLIT across z (768 blocks)
    qkv_g<<<dim3(Mn / 64, 4, 3), 256, 0, stream>>>(tpA, sspA, BIq, BIk, BIv, rt, qb, Kimg, Vimg);
    // attention (direct y for j<8; bf16 partials for j>=8)
    attn2_kernel<<<384, 256, 0, stream>>>(qb, Kimg, Vimg, ybf, pab, pl);
    // t2 partials = y @ At0 with slice-combine fused into staging
    downy_g<<<dim3(Mn / 64, 4), 256, 0, stream>>>(ybf, pab, pl, AtI0c, tpA);
    // FUSED: x1 = x + t2@Bto -> x1b (bf16); sumsq(x1) -> sspB; t3 = x1@At2 -> tpB
    updown_g<0, 1, 1, 1, 0><<<dim3(Mn / 32, 4), 256, 0, stream>>>(
        tpA, nullptr, BIo, AtI2u, x, x1b, tpB, sspB);
    // FUSED: m = silu(rms(t3)@Btfc) (never stored); t4 = m@At0 -> tpA
    updown_g<1, 0, 0, 0, 1><<<dim3(Mn / 32, 4), 256, 0, stream>>>(
        tpB, sspB, BIfc, AtI0u, nullptr, nullptr, tpA, nullptr);
    // out = x1b + t4 @ Btpr  (bf16 base, f32 out)
    up_g<0, 1, 0, 0, 1><<<dim3(Mn / 32, 4), 256, 0, stream>>>(tpA, nullptr, BIpr, x1b, out);
}

// Round 26
// 92.462 us; speedup vs baseline: 1.5900x; 1.0058x over previous
//
#include <hip/hip_runtime.h>

// HolographicBlock: B=2, S=2048, D=1024, R=64, H=8, HD=128
// Pre-swizzled weight images + global_load_lds everywhere; bf16 t-partials;
// qkv z-split; bf16 residual carrier x1b; complementary-pair attn permutation.
// R26: latency hoists — early base loads in updown/up; V ks=0 prefetch in attn.

#define Bn 2
#define Sn 2048
#define Dn 1024
#define Rn 64
#define Hn 8
#define HDn 128
#define Mn (Bn*Sn)   // 4096 rows
#define TSTRIDE ((size_t)Mn * Rn)

typedef __bf16 bf16x8 __attribute__((ext_vector_type(8)));
typedef float f32x4 __attribute__((ext_vector_type(4)));
typedef __attribute__((address_space(1))) const unsigned int g_u32;
typedef __attribute__((address_space(3))) unsigned int l_u32;

__device__ __forceinline__ float bf2f(unsigned short u){
    union { unsigned int i; float f; } x; x.i = ((unsigned int)u) << 16; return x.f;
}
__device__ __forceinline__ unsigned short f2bf(float f){
    union { float f; unsigned int i; } x; x.f = f;
    unsigned int r = x.i + 0x7fffu + ((x.i >> 16) & 1u);
    return (unsigned short)(r >> 16);
}
__device__ __forceinline__ unsigned int pk2(float a, float b){
    unsigned int r;
    asm("v_cvt_pk_bf16_f32 %0, %1, %2" : "=v"(r) : "v"(a), "v"(b));
    return r;
}
__device__ __forceinline__ float vexp2(float x){
    float r;
    asm("v_exp_f32 %0, %1" : "=v"(r) : "v"(x));
    return r;
}
__device__ __forceinline__ void gld16(const void* g, void* l){
    __builtin_amdgcn_global_load_lds((g_u32*)g, (l_u32*)l, 16, 0, 0);
}
__device__ __forceinline__ void dma32k(const char* src, char* dst, int tid){
    #pragma unroll
    for (int p = 0; p < 8; ++p)
        gld16(src + p * 4096 + tid * 16, dst + p * 4096 + tid * 16);
}
__device__ __forceinline__ float bflo(unsigned int u){
    union { unsigned int i; float f; } x; x.i = u << 16; return x.f;
}
__device__ __forceinline__ float bfhi(unsigned int u){
    union { unsigned int i; float f; } x; x.i = u & 0xffff0000u; return x.f;
}
__device__ __forceinline__ uint4 comb8(uint4 A, uint4 C, float Wc){
    uint4 r;
    unsigned int* a = (unsigned int*)&A;
    unsigned int* c = (unsigned int*)&C;
    unsigned int* o = (unsigned int*)&r;
    #pragma unroll
    for (int e = 0; e < 4; ++e){
        float lo = (bflo(a[e]) + bflo(c[e])) * Wc;
        float hi = (bfhi(a[e]) + bfhi(c[e])) * Wc;
        o[e] = pk2(lo, hi);
    }
    return r;
}

// ---------------- prep: PRE-SWIZZLED weight images + rope table
__global__ __launch_bounds__(256) void prep_g(const float* __restrict__ A,
                                              const float* __restrict__ Bsrc,
                                              const float* __restrict__ Cq, const float* __restrict__ Ck,
                                              const float* __restrict__ Cv, const float* __restrict__ Co,
                                              const float* __restrict__ Cfc, const float* __restrict__ Cpr,
                                              const float* __restrict__ s1, const float* __restrict__ s2,
                                              char* __restrict__ AtI1c, char* __restrict__ AtI0c,
                                              char* __restrict__ AtI2u, char* __restrict__ AtI0u,
                                              char* __restrict__ BIq, char* __restrict__ BIk,
                                              char* __restrict__ BIv, char* __restrict__ BIo,
                                              char* __restrict__ BIfc, char* __restrict__ BIpr,
                                              float2* __restrict__ rt){
    int idx = blockIdx.x * 256 + threadIdx.x;
    if (idx < 4 * 65536){
        int v = idx >> 16, e = idx & 65535;
        int r = e & 63, d = e >> 6;
        float sc = (v == 0) ? s1[d] : (v == 2) ? s2[d] : 1.f;
        unsigned short val = f2bf(A[d * 64 + r] * sc);
        if (v < 2){
            int us = (d >> 6) * 4096 + r * 64 + (((((d >> 3) & 7) << 4) ^ ((r & 7) << 4)) >> 1) + (d & 7);
            ((unsigned short*)(v == 0 ? AtI1c : AtI0c))[us] = val;
        } else {
            int us = (d >> 8) * 16384 + r * 256 + (((((d >> 3) & 31) << 4) ^ ((r & 7) << 4)) >> 1) + (d & 7);
            ((unsigned short*)(v == 2 ? AtI2u : AtI0u))[us] = val;
        }
    } else if (idx < 10 * 65536){
        int v = (idx >> 16) - 4, e = idx & 65535;
        int d = e & 1023, r = e >> 10;
        const float* C = v==0?Cq : v==1?Ck : v==2?Cv : v==3?Co : v==4?Cfc : Cpr;
        float extra = (v == 0) ? (0.08838834764831845f * 1.4426950408889634f) : 1.f;
        unsigned short val = f2bf(Bsrc[r * 1024 + d] * C[r] * extra);
        int us = (d >> 8) * 16384 + (d & 255) * 64 + ((((r >> 3) << 4) ^ ((d & 7) << 4)) >> 1) + (r & 7);
        ((unsigned short*)(v==0?BIq : v==1?BIk : v==2?BIv : v==3?BIo : v==4?BIfc : BIpr))[us] = val;
    } else if (idx < 10 * 65536 + Sn * 64){
        int e = idx - 10 * 65536;
        int s = e >> 6, f = e & 63;
        float inv = exp2f(-(float)f * (13.287712379549449f / 64.0f));
        float fr = (float)s * inv;
        float sn, cs; sincosf(fr, &sn, &cs);
        rt[e] = make_float2(cs, sn);
    }
}

// ---------------- down GEMM (f32 input + sumsq): DMA At image, bf16 t-partials out
__global__ __launch_bounds__(256) void down_g(const float* __restrict__ inp,
                                              const char* __restrict__ AtImg,
                                              unsigned short* __restrict__ tpart,
                                              float* __restrict__ sspart){
    __shared__ char xt[32768];
    __shared__ char at[32768];
    int tid = threadIdx.x;
    int m0 = blockIdx.x * 64, sp = blockIdx.y;
    int row = tid >> 2, q4 = tid & 3;
    int w = tid >> 6, lane = tid & 63, l4 = lane >> 4, lm = lane & 15;
    int swz = (row & 7) << 4;
    dma32k(AtImg + (size_t)sp * 32768, at, tid);
    float ss = 0.f;
    f32x4 acc[4];
    #pragma unroll
    for (int nt = 0; nt < 4; ++nt) acc[nt] = (f32x4){0.f,0.f,0.f,0.f};

    float4 xr[4];
    #define LOADX(c) { int k0 = sp * 256 + (c) * 64; \
        const float4* s = (const float4*)(inp + (size_t)(m0+row)*1024 + k0 + q4*16); \
        xr[0]=s[0]; xr[1]=s[1]; xr[2]=s[2]; xr[3]=s[3]; }

    LOADX(0);
    for (int c = 0; c < 4; ++c){
        char* xc = xt + c * 8192;
        #pragma unroll
        for (int i = 0; i < 4; ++i)
            ss += xr[i].x*xr[i].x + xr[i].y*xr[i].y + xr[i].z*xr[i].z + xr[i].w*xr[i].w;
        uint4 p0 = {pk2(xr[0].x,xr[0].y), pk2(xr[0].z,xr[0].w), pk2(xr[1].x,xr[1].y), pk2(xr[1].z,xr[1].w)};
        uint4 p1 = {pk2(xr[2].x,xr[2].y), pk2(xr[2].z,xr[2].w), pk2(xr[3].x,xr[3].y), pk2(xr[3].z,xr[3].w)};
        *(uint4*)(xc + row * 128 + ((q4 * 32) ^ swz)) = p0;
        *(uint4*)(xc + row * 128 + ((q4 * 32 + 16) ^ swz)) = p1;
        __syncthreads();            // c==0 also drains the At DMA
        if (c < 3) LOADX(c + 1);
        #pragma unroll
        for (int ks = 0; ks < 2; ++ks){
            int arow = 16 * w + lm;
            bf16x8 af = *(const bf16x8*)(xc + arow * 128 + ((ks*64 + l4*16) ^ ((arow & 7) << 4)));
            #pragma unroll
            for (int nt = 0; nt < 4; ++nt){
                int brow = nt * 16 + lm;
                bf16x8 bf = *(const bf16x8*)(at + c * 8192 + brow * 128 + ((ks*64 + l4*16) ^ ((brow & 7) << 4)));
                acc[nt] = __builtin_amdgcn_mfma_f32_16x16x32_bf16(af, bf, acc[nt], 0, 0, 0);
            }
        }
    }
    #undef LOADX
    ss += __shfl_xor(ss, 1); ss += __shfl_xor(ss, 2);
    if (q4 == 0) sspart[sp * Mn + m0 + row] = ss;
    #pragma unroll
    for (int nt = 0; nt < 4; ++nt)
        #pragma unroll
        for (int r = 0; r < 4; ++r){
            int ml = 16 * w + 4 * l4 + r;
            tpart[(size_t)sp * TSTRIDE + (size_t)(m0 + ml) * 64 + nt * 16 + lm] = f2bf(acc[nt][r]);
        }
}

// ---------------- down GEMM for y (fused slice-combine), bf16 t-partials out
__global__ __launch_bounds__(256) void downy_g(const unsigned short* __restrict__ ybf,
                                               const unsigned short* __restrict__ pab,
                                               const float* __restrict__ pl,
                                               const char* __restrict__ AtImg,
                                               unsigned short* __restrict__ tpart){
    __shared__ char xt[32768];
    __shared__ char at[32768];
    int tid = threadIdx.x;
    int m0 = blockIdx.x * 64, sp = blockIdx.y;
    int row = tid >> 2, q4 = tid & 3;
    int w = tid >> 6, lane = tid & 63, l4 = lane >> 4, lm = lane & 15;
    int swz = (row & 7) << 4;
    int jq = (m0 & (Sn - 1)) >> 7;
    int bpos = m0 >> 11;
    int srow = (m0 & 127) + row;
    dma32k(AtImg + (size_t)sp * 32768, at, tid);
    f32x4 acc[4];
    #pragma unroll
    for (int nt = 0; nt < 4; ++nt) acc[nt] = (f32x4){0.f,0.f,0.f,0.f};

    #define MFMAC(c) { \
        _Pragma("unroll") \
        for (int ks = 0; ks < 2; ++ks){ \
            int arow = 16 * w + lm; \
            bf16x8 af = *(const bf16x8*)(xt + (c) * 8192 + arow * 128 + ((ks*64 + l4*16) ^ ((arow & 7) << 4))); \
            _Pragma("unroll") \
            for (int nt = 0; nt < 4; ++nt){ \
                int brow = nt * 16 + lm; \
                bf16x8 bf = *(const bf16x8*)(at + (c) * 8192 + brow * 128 + ((ks*64 + l4*16) ^ ((brow & 7) << 4))); \
                acc[nt] = __builtin_amdgcn_mfma_f32_16x16x32_bf16(af, bf, acc[nt], 0, 0, 0); \
            } \
        } }

    if (jq < 8){
        const char* yb = (const char*)ybf;
        #pragma unroll
        for (int p = 0; p < 8; ++p){
            int c = p >> 1;
            int rw = (p & 1) * 32 + (tid >> 3);
            int gp = (tid & 7) ^ (rw & 7);
            gld16(yb + (size_t)(m0 + rw) * 2048 + sp * 512 + c * 128 + gp * 16,
                  xt + p * 4096 + tid * 16);
        }
        __syncthreads();
        for (int c = 0; c < 4; ++c) MFMAC(c);
    } else {
        uint4 xrb[2];
        #define LOADCMB(c) { int k0 = sp * 256 + (c) * 64; \
            int h = k0 >> 7; int d0 = k0 & 127; \
            int s0sl = (((bpos * 8 + h) * 8) + (jq - 8)) * 2; \
            const unsigned short* p0 = pab + (size_t)s0sl * 16384 + srow * 128 + d0 + q4 * 16; \
            const unsigned short* p1 = p0 + 16384; \
            float Wc = 1.f / (pl[s0sl * 128 + srow] + pl[(s0sl + 1) * 128 + srow]); \
            uint4 A0 = ((const uint4*)p0)[0], A1 = ((const uint4*)p0)[1]; \
            uint4 C0 = ((const uint4*)p1)[0], C1 = ((const uint4*)p1)[1]; \
            xrb[0] = comb8(A0, C0, Wc); xrb[1] = comb8(A1, C1, Wc); }
        LOADCMB(0);
        for (int c = 0; c < 4; ++c){
            char* xc = xt + c * 8192;
            *(uint4*)(xc + row * 128 + ((q4 * 32) ^ swz)) = xrb[0];
            *(uint4*)(xc + row * 128 + ((q4 * 32 + 16) ^ swz)) = xrb[1];
            __syncthreads();
            if (c < 3) LOADCMB(c + 1);
            MFMAC(c);
        }
        #undef LOADCMB
    }
    #undef MFMAC
    #pragma unroll
    for (int nt = 0; nt < 4; ++nt)
        #pragma unroll
        for (int r = 0; r < 4; ++r){
            int ml = 16 * w + 4 * l4 + r;
            tpart[(size_t)sp * TSTRIDE + (size_t)(m0 + ml) * 64 + nt * 16 + lm] = f2bf(acc[nt][r]);
        }
}

// ---------------- stage t tile (sum 4 bf16 K-split partials, optional rms) into swizzled LDS
template<int DORMS>
__device__ __forceinline__ void stage_t(char* tt, const unsigned short* __restrict__ tpart,
                                        const float* __restrict__ sspart, int m0, int tid){
    int row = tid >> 2, q4 = tid & 3;
    const unsigned short* bp = tpart + (size_t)(m0 + row) * 64 + q4 * 16;
    float s[16];
    #pragma unroll
    for (int half = 0; half < 2; ++half){
        uint4 u0 = ((const uint4*)(bp + 0 * TSTRIDE))[half];
        uint4 u1 = ((const uint4*)(bp + 1 * TSTRIDE))[half];
        uint4 u2 = ((const uint4*)(bp + 2 * TSTRIDE))[half];
        uint4 u3 = ((const uint4*)(bp + 3 * TSTRIDE))[half];
        const unsigned int* a0 = (const unsigned int*)&u0;
        const unsigned int* a1 = (const unsigned int*)&u1;
        const unsigned int* a2 = (const unsigned int*)&u2;
        const unsigned int* a3 = (const unsigned int*)&u3;
        #pragma unroll
        for (int e = 0; e < 4; ++e){
            s[half*8 + 2*e]     = bflo(a0[e]) + bflo(a1[e]) + bflo(a2[e]) + bflo(a3[e]);
            s[half*8 + 2*e + 1] = bfhi(a0[e]) + bfhi(a1[e]) + bfhi(a2[e]) + bfhi(a3[e]);
        }
    }
    float rr = 1.f;
    if (DORMS){
        int m = m0 + row;
        float ssum = sspart[m] + sspart[Mn + m] + sspart[2*Mn + m] + sspart[3*Mn + m];
        rr = rsqrtf(ssum * (1.f / 1024.f) + 1.1920929e-07f);
    }
    #pragma unroll
    for (int i = 0; i < 16; ++i) s[i] *= rr;
    int swz = (row & 7) << 4;
    uint4 p0 = {pk2(s[0],s[1]), pk2(s[2],s[3]), pk2(s[4],s[5]), pk2(s[6],s[7])};
    uint4 p1 = {pk2(s[8],s[9]), pk2(s[10],s[11]), pk2(s[12],s[13]), pk2(s[14],s[15])};
    *(uint4*)(tt + row * 128 + ((q4 * 32) ^ swz)) = p0;
    *(uint4*)(tt + row * 128 + ((q4 * 32 + 16) ^ swz)) = p1;
}

// ---------------- up GEMM (final projection): DMA Bt image; base optionally bf16
// R26: base tile loaded EARLY (before barriers) to hide HBM latency.
template<int SILU, int HASBASE, int OUT_BF16, int DORMS, int BASEBF16>
__global__ __launch_bounds__(256) void up_g(const unsigned short* __restrict__ tpart,
                                            const float* __restrict__ sspart,
                                            const char* __restrict__ BtImg,
                                            const void* base,
                                            void* __restrict__ outp){
    __shared__ char tt[4096];
    __shared__ char bb[32768];
    int tid = threadIdx.x;
    int m0 = blockIdx.x * 32, n0 = blockIdx.y * 256;
    int w = tid >> 6, lane = tid & 63, l4 = lane >> 4, lm = lane & 15;
    int wm = w & 1, wn = w >> 1;
    dma32k(BtImg + (size_t)blockIdx.y * 32768, bb, tid);
    float bs[8][4];
    if (HASBASE){
        #pragma unroll
        for (int nt = 0; nt < 8; ++nt)
            #pragma unroll
            for (int r = 0; r < 4; ++r){
                int m = m0 + 16 * wm + 4 * l4 + r;
                int n = n0 + wn * 128 + nt * 16 + lm;
                bs[nt][r] = BASEBF16 ? bf2f(((const unsigned short*)base)[(size_t)m * 1024 + n])
                                     : ((const float*)base)[(size_t)m * 1024 + n];
            }
    }
    if (tid < 128) stage_t<DORMS>(tt, tpart, sspart, m0, tid);
    __syncthreads();
    bf16x8 af[2];
    #pragma unroll
    for (int ks = 0; ks < 2; ++ks){
        int arow = 16 * wm + lm;
        af[ks] = *(const bf16x8*)(tt + arow * 128 + ((ks*64 + l4*16) ^ ((arow & 7) << 4)));
    }
    f32x4 acc[8];
    #pragma unroll
    for (int nt = 0; nt < 8; ++nt) acc[nt] = (f32x4){0.f,0.f,0.f,0.f};
    #pragma unroll
    for (int nt = 0; nt < 8; ++nt){
        int brow = wn * 128 + nt * 16 + lm;
        #pragma unroll
        for (int ks = 0; ks < 2; ++ks){
            bf16x8 bf = *(const bf16x8*)(bb + brow * 128 + ((ks*64 + l4*16) ^ ((brow & 7) << 4)));
            acc[nt] = __builtin_amdgcn_mfma_f32_16x16x32_bf16(af[ks], bf, acc[nt], 0, 0, 0);
        }
    }
    #pragma unroll
    for (int nt = 0; nt < 8; ++nt)
        #pragma unroll
        for (int r = 0; r < 4; ++r){
            int m = m0 + 16 * wm + 4 * l4 + r;
            int n = n0 + wn * 128 + nt * 16 + lm;
            float v = acc[nt][r];
            if (SILU) v = v / (1.f + __expf(-v));
            if (HASBASE) v += bs[nt][r];
            if (OUT_BF16) ((unsigned short*)outp)[(size_t)m * 1024 + n] = f2bf(v);
            else          ((float*)outp)[(size_t)m * 1024 + n] = v;
        }
}

// ---------------- FUSED up->down: DMA BtU image, DMA AtD ud-image; bf16 tpout;
// STOREOUT stores x1 as bf16 to x1out. R26: base tile loaded EARLY.
template<int SILU, int HASBASE, int STOREOUT, int SUMSQ, int DORMS_IN>
__global__ __launch_bounds__(256) void updown_g(const unsigned short* __restrict__ tpin,
                                                const float* __restrict__ sspin,
                                                const char* __restrict__ BtUimg,
                                                const char* __restrict__ AtDimg,
                                                const float* base,
                                                unsigned short* x1out,
                                                unsigned short* __restrict__ tpout,
                                                float* __restrict__ sspout){
    __shared__ char tt[4096];
    __shared__ char bb[32768];     // BtU image, later AtD image
    __shared__ char xb[16384];     // bounced up-output tile [32][256] bf16
    __shared__ float ssl[2][32];
    int tid = threadIdx.x;
    int m0 = blockIdx.x * 32, n0 = blockIdx.y * 256, sp = blockIdx.y;
    int w = tid >> 6, lane = tid & 63, l4 = lane >> 4, lm = lane & 15;
    int wm = w & 1, wn = w >> 1;
    dma32k(BtUimg + (size_t)sp * 32768, bb, tid);
    float bs[8][4];
    if (HASBASE){
        #pragma unroll
        for (int nt = 0; nt < 8; ++nt)
            #pragma unroll
            for (int r = 0; r < 4; ++r){
                int m = m0 + 16 * wm + 4 * l4 + r;
                int n = n0 + wn * 128 + nt * 16 + lm;
                bs[nt][r] = base[(size_t)m * 1024 + n];
            }
    }
    if (tid < 128) stage_t<DORMS_IN>(tt, tpin, sspin, m0, tid);
    __syncthreads();
    // ---- up MFMA
    bf16x8 af[2];
    #pragma unroll
    for (int ks = 0; ks < 2; ++ks){
        int arow = 16 * wm + lm;
        af[ks] = *(const bf16x8*)(tt + arow * 128 + ((ks*64 + l4*16) ^ ((arow & 7) << 4)));
    }
    f32x4 acc[8];
    #pragma unroll
    for (int nt = 0; nt < 8; ++nt) acc[nt] = (f32x4){0.f,0.f,0.f,0.f};
    #pragma unroll
    for (int nt = 0; nt < 8; ++nt){
        int brow = wn * 128 + nt * 16 + lm;
        #pragma unroll
        for (int ks = 0; ks < 2; ++ks){
            bf16x8 bf = *(const bf16x8*)(bb + brow * 128 + ((ks*64 + l4*16) ^ ((brow & 7) << 4)));
            acc[nt] = __builtin_amdgcn_mfma_f32_16x16x32_bf16(af[ks], bf, acc[nt], 0, 0, 0);
        }
    }
    // ---- epilogue
    float val[8][4];
    float sq[4] = {0.f, 0.f, 0.f, 0.f};
    #pragma unroll
    for (int nt = 0; nt < 8; ++nt)
        #pragma unroll
        for (int r = 0; r < 4; ++r){
            int m = m0 + 16 * wm + 4 * l4 + r;
            int n = n0 + wn * 128 + nt * 16 + lm;
            float v = acc[nt][r];
            if (SILU) v = v / (1.f + __expf(-v));
            if (HASBASE) v += bs[nt][r];
            val[nt][r] = v;
            if (STOREOUT) x1out[(size_t)m * 1024 + n] = f2bf(v);
            if (SUMSQ) sq[r] += v * v;
        }
    if (SUMSQ){
        #pragma unroll
        for (int r = 0; r < 4; ++r){
            float s_ = sq[r];
            s_ += __shfl_xor(s_, 1);
            s_ += __shfl_xor(s_, 2);
            s_ += __shfl_xor(s_, 4);
            s_ += __shfl_xor(s_, 8);
            if (lm == 0) ssl[wn][16 * wm + 4 * l4 + r] = s_;
        }
    }
    __syncthreads();   // bb reads done, ssl visible
    // ---- DMA AtD ud-image into bb; bounce val -> xb
    dma32k(AtDimg + (size_t)sp * 32768, bb, tid);
    #pragma unroll
    for (int nt = 0; nt < 8; ++nt)
        #pragma unroll
        for (int r = 0; r < 4; ++r){
            int mrow = 16 * wm + 4 * l4 + r;
            int cn = wn * 128 + nt * 16 + lm;
            *(unsigned short*)(xb + mrow * 512 + ((cn * 2) ^ ((mrow & 7) << 4))) = f2bf(val[nt][r]);
        }
    __syncthreads();
    if (SUMSQ && tid < 32)
        sspout[sp * Mn + m0 + tid] = ssl[0][tid] + ssl[1][tid];
    // ---- down MFMA
    f32x4 acc2[2];
    acc2[0] = (f32x4){0.f,0.f,0.f,0.f};
    acc2[1] = (f32x4){0.f,0.f,0.f,0.f};
    #pragma unroll
    for (int kk = 0; kk < 8; ++kk){
        int arow = 16 * (w & 1) + lm;
        bf16x8 a2 = *(const bf16x8*)(xb + arow * 512 + ((kk * 64 + l4 * 16) ^ ((arow & 7) << 4)));
        #pragma unroll
        for (int j = 0; j < 2; ++j){
            int brow = (2 * (w >> 1) + j) * 16 + lm;
            bf16x8 b2 = *(const bf16x8*)(bb + brow * 512 + ((kk * 64 + l4 * 16) ^ ((brow & 7) << 4)));
            acc2[j] = __builtin_amdgcn_mfma_f32_16x16x32_bf16(a2, b2, acc2[j], 0, 0, 0);
        }
    }
    #pragma unroll
    for (int j = 0; j < 2; ++j)
        #pragma unroll
        for (int r = 0; r < 4; ++r){
            int ml = 16 * (w & 1) + 4 * l4 + r;
            int nc = (2 * (w >> 1) + j) * 16 + lm;
            tpout[(size_t)sp * TSTRIDE + (size_t)(m0 + ml) * 64 + nc] = f2bf(acc2[j][r]);
        }
}

// ---------------- fused QKV up-proj + RoPE, SPLIT across blockIdx.z
__global__ __launch_bounds__(256) void qkv_g(const unsigned short* __restrict__ tpart,
                                             const float* __restrict__ sspart,
                                             const char* __restrict__ BIq,
                                             const char* __restrict__ BIk,
                                             const char* __restrict__ BIv,
                                             const float2* __restrict__ rt,
                                             unsigned short* __restrict__ qout,
                                             char* __restrict__ Kimg,
                                             char* __restrict__ Vimg){
    __shared__ char tt[8192];
    __shared__ char bb[32768];
    int tid = threadIdx.x;
    int m0 = blockIdx.x * 64, n0 = blockIdx.y * 256;
    int which = blockIdx.z;
    int b = m0 >> 11, s0 = m0 & (Sn - 1);
    int h0 = n0 >> 7;
    int w = tid >> 6, lane = tid & 63, l4 = lane >> 4, lm = lane & 15;
    const char* BI = (which == 0) ? BIq : (which == 1) ? BIk : BIv;
    dma32k(BI + (size_t)blockIdx.y * 32768, bb, tid);
    stage_t<1>(tt, tpart, sspart, m0, tid);
    __syncthreads();
    bf16x8 af[2];
    #pragma unroll
    for (int ks = 0; ks < 2; ++ks){
        int arow = 16 * w + lm;
        af[ks] = *(const bf16x8*)(tt + arow * 128 + ((ks*64 + l4*16) ^ ((arow & 7) << 4)));
    }
    f32x4 acc[16];
    #pragma unroll
    for (int nt = 0; nt < 16; ++nt) acc[nt] = (f32x4){0.f,0.f,0.f,0.f};
    #pragma unroll
    for (int nt = 0; nt < 16; ++nt){
        int brow = nt * 16 + lm;
        #pragma unroll
        for (int ks = 0; ks < 2; ++ks){
            bf16x8 bf = *(const bf16x8*)(bb + brow * 128 + ((ks*64 + l4*16) ^ ((brow & 7) << 4)));
            acc[nt] = __builtin_amdgcn_mfma_f32_16x16x32_bf16(af[ks], bf, acc[nt], 0, 0, 0);
        }
    }
    if (which < 2){
        float2 cs[4][4];
        #pragma unroll
        for (int ntb = 0; ntb < 4; ++ntb)
            #pragma unroll
            for (int r = 0; r < 4; ++r)
                cs[ntb][r] = rt[(size_t)(s0 + 16*w + 4*l4 + r) * 64 + ntb * 16 + lm];
        #pragma unroll
        for (int g = 0; g < 2; ++g)
            #pragma unroll
            for (int ntb = 0; ntb < 4; ++ntb){
                int lo = g*8 + ntb, hi = lo + 4;
                #pragma unroll
                for (int r = 0; r < 4; ++r){
                    float2 c = cs[ntb][r];
                    float a = acc[lo][r], bq = acc[hi][r];
                    acc[lo][r] = a * c.x + bq * c.y;
                    acc[hi][r] = -a * c.y + bq * c.x;
                }
            }
        __syncthreads();
        #pragma unroll
        for (int nt = 0; nt < 16; ++nt)
            #pragma unroll
            for (int r = 0; r < 4; ++r){
                int nl = nt * 16 + lm, ml2 = 16 * w + 4 * l4 + r;
                *(unsigned short*)(bb + ml2 * 512 + ((nl * 2) ^ ((ml2 & 7) << 4))) = f2bf(acc[nt][r]);
            }
        __syncthreads();
        if (which == 0){
            int ml = tid >> 2, seg = tid & 3;
            int head = h0 + (seg >> 1), hd0q = (seg & 1) * 64;
            size_t dstbase = (((size_t)(b * 8 + head) * Sn + (s0 + ml)) * 128 + hd0q);
            #pragma unroll
            for (int j = 0; j < 8; ++j){
                uint4 v = *(const uint4*)(bb + ml * 512 + ((seg * 128 + j * 16) ^ ((ml & 7) << 4)));
                *(uint4*)(qout + dstbase + j * 8) = v;
            }
        } else {
            int ml = tid >> 2, seg = tid & 3;
            int hd0q = (seg & 1) * 64;
            int head = h0 + (seg >> 1);
            int pr = 16 * (ml & 3) + (ml >> 2);
            size_t rowb = (((size_t)(b * 8 + head) * 32 + (s0 >> 6)) * 64 + pr) * 256;
            #pragma unroll
            for (int j = 0; j < 8; ++j){
                uint4 v = *(const uint4*)(bb + ml * 512 + ((seg * 128 + j * 16) ^ ((ml & 7) << 4)));
                int cb = hd0q * 2 + j * 16;
                *(uint4*)(Kimg + rowb + (cb ^ ((pr & 7) << 4))) = v;
            }
        }
    } else {
        __syncthreads();
        #pragma unroll
        for (int nt = 0; nt < 16; ++nt)
            #pragma unroll
            for (int r = 0; r < 4; ++r){
                int nl = nt * 16 + lm, ml2 = 16 * w + 4 * l4 + r;
                *(unsigned short*)(bb + nl * 128 + ((ml2 * 2) ^ ((nl & 7) << 4))) = f2bf(acc[nt][r]);
            }
        __syncthreads();
        int head = h0 + (tid >> 7), d = tid & 127;
        size_t rowb = (((size_t)(b * 8 + head) * 32 + (s0 >> 6)) * 128 + d) * 128;
        #pragma unroll
        for (int j = 0; j < 8; ++j){
            uint4 v = *(const uint4*)(bb + tid * 128 + ((j * 16) ^ ((tid & 7) << 4)));
            *(uint4*)(Vimg + rowb + ((j * 16) ^ ((d & 7) << 4))) = v;
        }
    }
}

// ---------------- K-split flash attention: complementary-pair permutation;
// R26: ks=0 V fragments prefetched before softmax (LDS overlaps exp chain).
__global__ __launch_bounds__(256, 2) void attn2_kernel(const unsigned short* __restrict__ qb,
                                                       const char* __restrict__ Kimg,
                                                       const char* __restrict__ Vimg,
                                                       unsigned short* __restrict__ ybf,
                                                       unsigned short* __restrict__ pab,
                                                       float* __restrict__ pl){
    __shared__ uint4 smem4[81920 / 16];
    char* smem = (char*)smem4;
    int tid = threadIdx.x;
    int w = tid >> 6, lane = tid & 63, l4 = lane >> 4, lm = lane & 15;
    int o = blockIdx.x;
    // slot inventory per bh: 16-iter: s0..s8,s16 (inst 0..9);
    // 14: s9/s17; 12: s10/s18; 10: s11/s19; 8: s12/s20; 6: s13/s21; 4: s14/s22; 2: s15/s23
    int bh, slot;
    if (o < 128){
        int cat = o >> 5;           // 0:C16, 1:C14, 2:C12, 3:C10 (long pair members)
        int k = o & 31;
        if (cat == 0){ bh = k & 15; slot = (k >> 4); }          // inst 0..1 -> slots 0,1
        else { bh = k >> 1; slot = (k & 1) ? (8 + cat + 8) : (8 + cat); }  // 9/17,10/18,11/19
    } else if (o < 256){
        int k16 = 32 + (o - 128);   // inst 2..9 of 16-iter slots
        bh = k16 & 15;
        int inst = k16 >> 4;
        slot = (inst < 9) ? inst : 16;
    } else {
        int cat = (o - 256) >> 5;   // 0:C2, 1:C4, 2:C6, 3:C8 (short pair members)
        int k = (o - 256) & 31;
        bh = k >> 1;
        int base = 15 - cat;        // 15,14,13,12
        slot = (k & 1) ? (base + 8) : base;
    }
    int grp = slot >> 3, g = slot & 7;
    int J, t0, niters, direct, slice;
    if (grp == 0){ J = 8 + g;  t0 = 0;  niters = 16;         direct = 0; slice = (bh * 8 + g) * 2; }
    else if (grp == 1){ J = 15 - g; t0 = 16; niters = 2 * J - 14; direct = 0; slice = (bh * 8 + (J - 8)) * 2 + 1; }
    else { J = 7 - g;  t0 = 0;  niters = 2 * J + 2;  direct = 1; slice = 0; }
    int b = bh >> 3, h = bh & 7;
    int qrow0w = 128 * J + 32 * w;
    int wqmax = qrow0w + 31;

    bf16x8 qf[2][4];
    #pragma unroll
    for (int f = 0; f < 2; ++f){
        const unsigned short* qg = qb + ((size_t)bh * Sn + qrow0w + 16 * f + lm) * HDn;
        #pragma unroll
        for (int df = 0; df < 4; ++df)
            qf[f][df] = *(const bf16x8*)(qg + df * 32 + l4 * 8);
    }
    f32x4 acc[2][8];
    #pragma unroll
    for (int f = 0; f < 2; ++f)
        #pragma unroll
        for (int dg = 0; dg < 8; ++dg) acc[f][dg] = (f32x4){0.f,0.f,0.f,0.f};
    float lp[2][4];
    #pragma unroll
    for (int f = 0; f < 2; ++f)
        #pragma unroll
        for (int r = 0; r < 4; ++r) lp[f][r] = 0.f;

    const float OFF = 11.541560327111708f;   // 8 * log2(e)
    size_t imgbase = (size_t)bh * 32 * 16384;

    #define STAGE_DMA(T, BUFB) { size_t tb = imgbase + (size_t)(T) * 16384; \
        _Pragma("unroll") for (int i2 = 0; i2 < 4; ++i2){ \
            gld16(Kimg + tb + i2 * 4096 + tid * 16, smem + (BUFB) + i2 * 4096 + tid * 16); \
            gld16(Vimg + tb + i2 * 4096 + tid * 16, smem + (BUFB) + 16384 + i2 * 4096 + tid * 16); } }

    STAGE_DMA(t0, 0);
    __syncthreads();

    for (int it = 0; it < niters; ++it){
        int t = t0 + it;
        int bsel = (it & 1) << 15;
        if (it + 1 < niters)
            STAGE_DMA(t + 1, bsel ^ 32768);
        if (64 * t <= wqmax){
            char* KL = smem + bsel;
            char* VL = smem + bsel + 16384;
            char* pb = smem + 65536 + (w << 12);
            __builtin_amdgcn_s_setprio(1);
            f32x4 sf[2][4];
            #pragma unroll
            for (int kc = 0; kc < 4; ++kc){ sf[0][kc] = (f32x4){0.f,0.f,0.f,0.f}; sf[1][kc] = (f32x4){0.f,0.f,0.f,0.f}; }
            #pragma unroll
            for (int kc = 0; kc < 4; ++kc){
                int krow = 16 * kc + lm;
                int ksw = (krow & 7) << 4;
                #pragma unroll
                for (int df = 0; df < 4; ++df){
                    bf16x8 kf = *(const bf16x8*)(KL + krow * 256 + ((df * 64 + l4 * 16) ^ ksw));
                    sf[0][kc] = __builtin_amdgcn_mfma_f32_16x16x32_bf16(qf[0][df], kf, sf[0][kc], 0, 0, 0);
                    sf[1][kc] = __builtin_amdgcn_mfma_f32_16x16x32_bf16(qf[1][df], kf, sf[1][kc], 0, 0, 0);
                }
            }
            // R26: prefetch ks=0 V fragments so LDS pipe overlaps the exp chain
            bf16x8 vf0[8];
            #pragma unroll
            for (int dg = 0; dg < 8; ++dg){
                int vrow = 16 * dg + lm;
                vf0[dg] = *(const bf16x8*)(VL + vrow * 128 + ((l4 * 16) ^ ((vrow & 7) << 4)));
            }
            bool needmask = (64 * t + 63 > qrow0w);
            #pragma unroll
            for (int f = 0; f < 2; ++f){
                #pragma unroll
                for (int r = 0; r < 4; ++r){
                    float s0v = sf[f][0][r], s1v = sf[f][1][r],
                          s2v = sf[f][2][r], s3v = sf[f][3][r];
                    if (needmask){
                        int qr = qrow0w + 16 * f + 4 * l4 + r;
                        int j0k = 64 * t + 4 * lm;
                        s0v = (j0k     > qr) ? -1e30f : s0v;
                        s1v = (j0k + 1 > qr) ? -1e30f : s1v;
                        s2v = (j0k + 2 > qr) ? -1e30f : s2v;
                        s3v = (j0k + 3 > qr) ? -1e30f : s3v;
                    }
                    float p0 = vexp2(s0v - OFF), p1 = vexp2(s1v - OFF),
                          p2 = vexp2(s2v - OFF), p3 = vexp2(s3v - OFF);
                    lp[f][r] += p0 + p1 + p2 + p3;
                    int prow = 16 * f + 4 * l4 + r;
                    uint2 pkd = {pk2(p0, p1), pk2(p2, p3)};
                    *(uint2*)(pb + prow * 128 + ((lm * 8) ^ ((prow & 7) << 4))) = pkd;
                }
            }
            // ks = 0: use prefetched V
            {
                int pcol = (l4 * 16) ^ ((lm & 7) << 4);
                bf16x8 pa0 = *(const bf16x8*)(pb + lm * 128 + pcol);
                bf16x8 pa1 = *(const bf16x8*)(pb + (16 + lm) * 128 + pcol);
                #pragma unroll
                for (int dg = 0; dg < 8; ++dg){
                    acc[0][dg] = __builtin_amdgcn_mfma_f32_16x16x32_bf16(pa0, vf0[dg], acc[0][dg], 0, 0, 0);
                    acc[1][dg] = __builtin_amdgcn_mfma_f32_16x16x32_bf16(pa1, vf0[dg], acc[1][dg], 0, 0, 0);
                }
            }
            // ks = 1: in-loop V reads
            {
                int pcol = (64 + l4 * 16) ^ ((lm & 7) << 4);
                bf16x8 pa0 = *(const bf16x8*)(pb + lm * 128 + pcol);
                bf16x8 pa1 = *(const bf16x8*)(pb + (16 + lm) * 128 + pcol);
                #pragma unroll
                for (int dg = 0; dg < 8; ++dg){
                    int vrow = 16 * dg + lm;
                    bf16x8 vf = *(const bf16x8*)(VL + vrow * 128 + ((64 + l4 * 16) ^ ((vrow & 7) << 4)));
                    acc[0][dg] = __builtin_amdgcn_mfma_f32_16x16x32_bf16(pa0, vf, acc[0][dg], 0, 0, 0);
                    acc[1][dg] = __builtin_amdgcn_mfma_f32_16x16x32_bf16(pa1, vf, acc[1][dg], 0, 0, 0);
                }
            }
            __builtin_amdgcn_s_setprio(0);
        }
        __syncthreads();
    }
    #undef STAGE_DMA
    float lsum[2][4];
    #pragma unroll
    for (int f = 0; f < 2; ++f)
        #pragma unroll
        for (int r = 0; r < 4; ++r){
            float l_ = lp[f][r];
            l_ += __shfl_xor(l_, 1);
            l_ += __shfl_xor(l_, 2);
            l_ += __shfl_xor(l_, 4);
            l_ += __shfl_xor(l_, 8);
            lsum[f][r] = l_;
        }
    if (direct){
        #pragma unroll
        for (int f = 0; f < 2; ++f)
            #pragma unroll
            for (int r = 0; r < 4; ++r){
                float inv = 1.f / lsum[f][r];
                int row = qrow0w + 16 * f + 4 * l4 + r;
                unsigned short* yr = ybf + ((size_t)b * Sn + row) * Dn + h * HDn;
                #pragma unroll
                for (int dg = 0; dg < 8; ++dg)
                    yr[16 * dg + lm] = f2bf(acc[f][dg][r] * inv);
            }
    } else {
        unsigned short* pa_ = pab + (size_t)slice * 16384;
        #pragma unroll
        for (int f = 0; f < 2; ++f)
            #pragma unroll
            for (int r = 0; r < 4; ++r){
                int row = 32 * w + 16 * f + 4 * l4 + r;
                #pragma unroll
                for (int dg = 0; dg < 8; ++dg)
                    pa_[row * 128 + 16 * dg + lm] = f2bf(acc[f][dg][r]);
                if (lm == 0)
                    pl[slice * 128 + row] = lsum[f][r];
            }
    }
}

extern "C" void kernel_launch(void* const* d_in, const int* in_sizes, int n_in,
                              void* d_out, int out_size, void* d_ws, size_t ws_size,
                              hipStream_t stream){
    const float* x      = (const float*)d_in[0];
    const float* A      = (const float*)d_in[1];
    const float* Bm     = (const float*)d_in[2];
    const float* C_q    = (const float*)d_in[3];
    const float* C_k    = (const float*)d_in[4];
    const float* C_v    = (const float*)d_in[5];
    const float* C_o    = (const float*)d_in[6];
    const float* C_fc   = (const float*)d_in[7];
    const float* C_proj = (const float*)d_in[8];
    const float* scale1 = (const float*)d_in[9];
    const float* scale2 = (const float*)d_in[10];
    float* out = (float*)d_out;

    char* ws = (char*)d_ws;
    size_t off = 0;
    auto alloc = [&](size_t bytes)->char*{ char* p = ws + off; off += (bytes + 255) & ~(size_t)255; return p; };
    unsigned short* qb   = (unsigned short*)alloc((size_t)Mn * Dn * 2);   // 8MB
    char*           Kimg = alloc((size_t)16 * 32 * 16384);                // 8MB
    char*           Vimg = alloc((size_t)16 * 32 * 16384);                // 8MB
    unsigned short* ybf  = (unsigned short*)alloc((size_t)Mn * Dn * 2);   // 8MB
    unsigned short* pab  = (unsigned short*)alloc((size_t)256 * 16384 * 2); // 8MB
    float*          pl   = (float*)alloc((size_t)256 * 128 * 4);          // 128KB
    unsigned short* tpA  = (unsigned short*)alloc(4 * TSTRIDE * 2);       // 2MB (bf16)
    unsigned short* tpB  = (unsigned short*)alloc(4 * TSTRIDE * 2);       // 2MB (bf16)
    unsigned short* x1b  = (unsigned short*)alloc((size_t)Mn * Dn * 2);   // 8MB (bf16 x1)
    float*          sspA = (float*)alloc(4 * (size_t)Mn * 4);             // 64KB
    float*          sspB = (float*)alloc(4 * (size_t)Mn * 4);             // 64KB
    char*           AtI1c = alloc(131072);
    char*           AtI0c = alloc(131072);
    char*           AtI2u = alloc(131072);
    char*           AtI0u = alloc(131072);
    char*           BIq   = alloc(131072);
    char*           BIk   = alloc(131072);
    char*           BIv   = alloc(131072);
    char*           BIo   = alloc(131072);
    char*           BIfc  = alloc(131072);
    char*           BIpr  = alloc(131072);
    float2*         rt    = (float2*)alloc((size_t)Sn * 64 * 8);          // 1MB

    prep_g<<<3072, 256, 0, stream>>>(A, Bm, C_q, C_k, C_v, C_o, C_fc, C_proj,
                                     scale1, scale2,
                                     AtI1c, AtI0c, AtI2u, AtI0u,
                                     BIq, BIk, BIv, BIo, BIfc, BIpr, rt);
    // t1 partials = x @ At1 (s1 folded), ss = rowwise sumsq(x)
    down_g<<<dim3(Mn / 64, 4), 256, 0, stream>>>(x, AtI1c, tpA, sspA);
    // q (scaled+roped), K-image, V-image — SPLIT across z (768 blocks)
    qkv_g<<<dim3(Mn / 64, 4, 3), 256, 0, stream>>>(tpA, sspA, BIq, BIk, BIv, rt, qb, Kimg, Vimg);
    // attention (direct y for j<8; bf16 partials for j>=8)
    attn2_kernel<<<384, 256, 0, stream>>>(qb, Kimg, Vimg, ybf, pab, pl);
    // t2 partials = y @ At0 with slice-combine fused into staging
    downy_g<<<dim3(Mn / 64, 4), 256, 0, stream>>>(ybf, pab, pl, AtI0c, tpA);
    // FUSED: x1 = x + t2@Bto -> x1b (bf16); sumsq(x1) -> sspB; t3 = x1@At2 -> tpB
    updown_g<0, 1, 1, 1, 0><<<dim3(Mn / 32, 4), 256, 0, stream>>>(
        tpA, nullptr, BIo, AtI2u, x, x1b, tpB, sspB);
    // FUSED: m = silu(rms(t3)@Btfc) (never stored); t4 = m@At0 -> tpA
    updown_g<1, 0, 0, 0, 1><<<dim3(Mn / 32, 4), 256, 0, stream>>>(
        tpB, sspB, BIfc, AtI0u, nullptr, nullptr, tpA, nullptr);
    // out = x1b + t4 @ Btpr  (bf16 base, f32 out)
    up_g<0, 1, 0, 0, 1><<<dim3(Mn / 32, 4), 256, 0, stream>>>(tpA, nullptr, BIpr, x1b, out);
}